// Round 1
// baseline (1036.536 us; speedup 1.0000x reference)
//
#include <hip/hip_runtime.h>
#include <math.h>

#define EMBED 512
#define NHEAD 8
#define HD 64
#define NUM_CLS 4
#define WIN 32
#define WLEN 65          // 2*WIN+1
#define CTX 69           // NUM_CLS + WLEN
#define PATCH_LEN 8192
#define S_TOT 8196       // NUM_CLS + PATCH_LEN
#define QKV_LD 1536
#define NEGV (-1e30f)

// ---------------- GEMM: C = A * B^T + bias ----------------
// A: MxK row-major, B: NxK row-major, C: MxN row-major. K % 16 == 0.
#define BM 64
#define BN 64
#define BK 16

__global__ __launch_bounds__(256) void gemm_nt(const float* __restrict__ A,
                                               const float* __restrict__ B,
                                               const float* __restrict__ bias,
                                               float* __restrict__ C,
                                               int M, int N, int K)
{
    __shared__ float As[BK][BM + 4];   // +4 pad keeps 16B alignment, breaks store conflicts
    __shared__ float Bs[BK][BN + 4];
    const int tid = threadIdx.x;
    const int bm = blockIdx.x, bn = blockIdx.y;
    const int tx = tid & 15, ty = tid >> 4;
    const int row0 = bm * BM + ty * 4;
    const int col0 = bn * BN + tx * 4;
    const int lrow = tid >> 2;        // 0..63
    const int lk4  = (tid & 3) << 2;  // 0,4,8,12

    float acc[4][4] = {{0.f, 0.f, 0.f, 0.f}, {0.f, 0.f, 0.f, 0.f},
                       {0.f, 0.f, 0.f, 0.f}, {0.f, 0.f, 0.f, 0.f}};

    for (int k0 = 0; k0 < K; k0 += BK) {
        const int gm = bm * BM + lrow;
        float4 av = make_float4(0.f, 0.f, 0.f, 0.f);
        if (gm < M) av = *(const float4*)(A + (size_t)gm * K + k0 + lk4);
        const int gn = bn * BN + lrow;
        float4 bv = make_float4(0.f, 0.f, 0.f, 0.f);
        if (gn < N) bv = *(const float4*)(B + (size_t)gn * K + k0 + lk4);

        As[lk4 + 0][lrow] = av.x;
        As[lk4 + 1][lrow] = av.y;
        As[lk4 + 2][lrow] = av.z;
        As[lk4 + 3][lrow] = av.w;
        Bs[lk4 + 0][lrow] = bv.x;
        Bs[lk4 + 1][lrow] = bv.y;
        Bs[lk4 + 2][lrow] = bv.z;
        Bs[lk4 + 3][lrow] = bv.w;
        __syncthreads();

#pragma unroll
        for (int kk = 0; kk < BK; ++kk) {
            float4 a = *(const float4*)&As[kk][ty * 4];
            float4 b = *(const float4*)&Bs[kk][tx * 4];
            acc[0][0] += a.x * b.x; acc[0][1] += a.x * b.y; acc[0][2] += a.x * b.z; acc[0][3] += a.x * b.w;
            acc[1][0] += a.y * b.x; acc[1][1] += a.y * b.y; acc[1][2] += a.y * b.z; acc[1][3] += a.y * b.w;
            acc[2][0] += a.z * b.x; acc[2][1] += a.z * b.y; acc[2][2] += a.z * b.z; acc[2][3] += a.z * b.w;
            acc[3][0] += a.w * b.x; acc[3][1] += a.w * b.y; acc[3][2] += a.w * b.z; acc[3][3] += a.w * b.w;
        }
        __syncthreads();
    }

#pragma unroll
    for (int i = 0; i < 4; ++i) {
        const int r = row0 + i;
        if (r < M) {
#pragma unroll
            for (int j = 0; j < 4; ++j) {
                const int c = col0 + j;
                if (c < N) C[(size_t)r * N + c] = acc[i][j] + bias[c];
            }
        }
    }
}

// ---------------- RoPE 2D, in-place on q_p and k_p rows of qkv ----------------
__global__ __launch_bounds__(256) void rope_kernel(float* __restrict__ qkv,
                                                   const float* __restrict__ coords)
{
    const int idx = blockIdx.x * 256 + threadIdx.x;   // PATCH_LEN * NHEAD * 32
    const int l = idx >> 8;
    const int rem = idx & 255;
    const int h = rem >> 5;
    const int i = rem & 31;   // pair index 0..31

    const float cx = coords[l * 2 + 0] * 1e-5f;
    const float cy = coords[l * 2 + 1] * 1e-5f;
    const float basev = (i < 16) ? cx : cy;
    const int fi = (i < 16) ? i : (i - 16);
    // inv_freq = 10000^(-fi/16)
    const float inv_freq = expf(-((float)fi * (1.0f / 16.0f)) * logf(10000.0f));
    const float f = basev * inv_freq;
    const float cs = cosf(f), sn = sinf(f);

    const size_t base = (size_t)(NUM_CLS + l) * QKV_LD + h * HD + 2 * i;
    float2 q = *(float2*)(qkv + base);
    *(float2*)(qkv + base) = make_float2(q.x * cs - q.y * sn, q.y * cs + q.x * sn);
    float2 k = *(float2*)(qkv + base + EMBED);
    *(float2*)(qkv + base + EMBED) = make_float2(k.x * cs - k.y * sn, k.y * cs + k.x * sn);
}

// ---------------- cls attention: one block per (head, cls query) ----------------
__global__ __launch_bounds__(256) void cls_attn(const float* __restrict__ qkv,
                                                float* __restrict__ attn)
{
    const int h = blockIdx.x >> 2;
    const int qi = blockIdx.x & 3;
    const int tid = threadIdx.x;
    __shared__ float qs[64];
    __shared__ float red[256];
    __shared__ float probs[S_TOT];

    if (tid < 64) qs[tid] = qkv[(size_t)qi * QKV_LD + h * HD + tid];
    __syncthreads();

    // pass 1: scores + local max
    float smax = -INFINITY;
    for (int j = tid; j < S_TOT; j += 256) {
        const float* kp = qkv + (size_t)j * QKV_LD + EMBED + h * HD;
        float d0 = 0.f;
#pragma unroll
        for (int d = 0; d < 64; ++d) d0 += qs[d] * kp[d];
        d0 *= 0.125f;
        probs[j] = d0;
        smax = fmaxf(smax, d0);
    }
    red[tid] = smax;
    __syncthreads();
    for (int s2 = 128; s2 > 0; s2 >>= 1) {
        if (tid < s2) red[tid] = fmaxf(red[tid], red[tid + s2]);
        __syncthreads();
    }
    const float gmax = red[0];
    __syncthreads();

    // pass 2: exp + local sum
    float lsum = 0.f;
    for (int j = tid; j < S_TOT; j += 256) {
        float p = expf(probs[j] - gmax);
        probs[j] = p;
        lsum += p;
    }
    red[tid] = lsum;
    __syncthreads();
    for (int s2 = 128; s2 > 0; s2 >>= 1) {
        if (tid < s2) red[tid] += red[tid + s2];
        __syncthreads();
    }
    const float inv = 1.f / red[0];
    __syncthreads();

    // pass 3: out[d] = sum_j p[j] * v[j][d]  (lane = dim, 4 partial chunks)
    const int d = tid & 63, c = tid >> 6;
    float acc = 0.f;
    for (int j = c; j < S_TOT; j += 4)
        acc += probs[j] * qkv[(size_t)j * QKV_LD + 2 * EMBED + h * HD + d];
    red[tid] = acc;
    __syncthreads();
    if (tid < 64) {
        const float o = (red[tid] + red[tid + 64] + red[tid + 128] + red[tid + 192]) * inv;
        attn[(size_t)qi * EMBED + h * HD + tid] = o;
    }
}

// ---------------- patch attention: one block per (32-token tile, head) ----------------
__global__ __launch_bounds__(256) void patch_attn(const float* __restrict__ qkv,
                                                  float* __restrict__ attn)
{
    const int l0 = blockIdx.x * 32;
    const int h = blockIdx.y;
    const int tid = threadIdx.x;

    __shared__ float qt[32][68];   // +4 pad: conflict-free dot phase
    __shared__ float kw[96][68];   // window keys: pos = l0-32+r, r=0..95
    __shared__ float vw[96][68];
    __shared__ float kc[4][68];
    __shared__ float vc[4][68];
    __shared__ float sc[32][69];   // scores -> probs

    // stage q tile
    for (int idx = tid; idx < 32 * 64; idx += 256) {
        const int t = idx >> 6, d = idx & 63;
        qt[t][d] = qkv[(size_t)(NUM_CLS + l0 + t) * QKV_LD + h * HD + d];
    }
    // stage window k/v (zero-padded out of range; those scores are masked anyway)
    for (int idx = tid; idx < 96 * 64; idx += 256) {
        const int r = idx >> 6, d = idx & 63;
        const int pos = l0 - WIN + r;
        const bool ok = (pos >= 0) && (pos < PATCH_LEN);
        kw[r][d] = ok ? qkv[(size_t)(NUM_CLS + pos) * QKV_LD + EMBED + h * HD + d] : 0.f;
        vw[r][d] = ok ? qkv[(size_t)(NUM_CLS + pos) * QKV_LD + 2 * EMBED + h * HD + d] : 0.f;
    }
    // stage cls k/v (exactly 256 elements each)
    {
        const int r = tid >> 6, d = tid & 63;
        kc[r][d] = qkv[(size_t)r * QKV_LD + EMBED + h * HD + d];
        vc[r][d] = qkv[(size_t)r * QKV_LD + 2 * EMBED + h * HD + d];
    }
    __syncthreads();

    // scores: 8 lanes per token, each covers keys g, g+8, ...
    {
        const int t = tid >> 3, g = tid & 7;
        for (int key = g; key < CTX; key += 8) {
            float s;
            if (key < NUM_CLS) {
                float d0 = 0.f;
#pragma unroll
                for (int d = 0; d < 64; ++d) d0 += qt[t][d] * kc[key][d];
                s = d0 * 0.125f;
            } else {
                const int w = key - NUM_CLS;
                const int pos = l0 + t + w - WIN;
                if (pos < 0 || pos >= PATCH_LEN) {
                    s = NEGV;
                } else {
                    const int r = t + w;   // = pos - l0 + WIN
                    float d0 = 0.f;
#pragma unroll
                    for (int d = 0; d < 64; ++d) d0 += qt[t][d] * kw[r][d];
                    s = d0 * 0.125f;
                }
            }
            sc[t][key] = s;
        }
    }
    __syncthreads();

    // softmax: one thread per token (69-wide, serial — cheap)
    if (tid < 32) {
        const int t = tid;
        float m = -INFINITY;
        for (int key = 0; key < CTX; ++key) m = fmaxf(m, sc[t][key]);
        float sum = 0.f;
        for (int key = 0; key < CTX; ++key) {
            const float p = expf(sc[t][key] - m);
            sc[t][key] = p;
            sum += p;
        }
        const float inv = 1.f / sum;
        for (int key = 0; key < CTX; ++key) sc[t][key] *= inv;
    }
    __syncthreads();

    // output: lane = dim (conflict-free vw reads, broadcast sc reads)
    {
        const int d = tid & 63, tg = tid >> 6;
        for (int t = tg; t < 32; t += 4) {
            float acc = 0.f;
#pragma unroll
            for (int key = 0; key < NUM_CLS; ++key) acc += sc[t][key] * vc[key][d];
            for (int w = 0; w < WLEN; ++w) acc += sc[t][NUM_CLS + w] * vw[t + w][d];
            attn[(size_t)(NUM_CLS + l0 + t) * EMBED + h * HD + d] = acc;
        }
    }
}

extern "C" void kernel_launch(void* const* d_in, const int* in_sizes, int n_in,
                              void* d_out, int out_size, void* d_ws, size_t ws_size,
                              hipStream_t stream)
{
    const float* x      = (const float*)d_in[0];
    const float* coords = (const float*)d_in[1];
    const float* w_qkv  = (const float*)d_in[2];
    const float* b_qkv  = (const float*)d_in[3];
    const float* w_out  = (const float*)d_in[4];
    const float* b_out  = (const float*)d_in[5];
    float* out = (float*)d_out;

    // workspace layout: qkv (S_TOT x 1536 fp32) | attn (S_TOT x 512 fp32)  ~67.1 MB
    float* qkv  = (float*)d_ws;
    float* attn = qkv + (size_t)S_TOT * QKV_LD;

    // 1) qkv = x @ w_qkv^T + b_qkv
    gemm_nt<<<dim3((S_TOT + BM - 1) / BM, (3 * EMBED) / BN), 256, 0, stream>>>(
        x, w_qkv, b_qkv, qkv, S_TOT, 3 * EMBED, EMBED);

    // 2) RoPE in place on q_p, k_p
    rope_kernel<<<(PATCH_LEN * NHEAD * 32) / 256, 256, 0, stream>>>(qkv, coords);

    // 3) cls-token attention (rows 0..3 of attn)
    cls_attn<<<NHEAD * NUM_CLS, 256, 0, stream>>>(qkv, attn);

    // 4) windowed patch attention (rows 4..8195 of attn)
    patch_attn<<<dim3(PATCH_LEN / 32, NHEAD), 256, 0, stream>>>(qkv, attn);

    // 5) out = attn @ w_out^T + b_out
    gemm_nt<<<dim3((S_TOT + BM - 1) / BM, EMBED / BN), 256, 0, stream>>>(
        attn, w_out, b_out, out, S_TOT, EMBED, EMBED);
}

// Round 2
// 502.599 us; speedup vs baseline: 2.0624x; 2.0624x over previous
//
#include <hip/hip_runtime.h>
#include <math.h>

#define EMBED 512
#define NHEAD 8
#define HD 64
#define NUM_CLS 4
#define WIN 32
#define WLEN 65          // 2*WIN+1
#define CTX 69           // NUM_CLS + WLEN
#define PATCH_LEN 8192
#define S_TOT 8196       // NUM_CLS + PATCH_LEN
#define QKV_LD 1536
#define NEGV (-1e30f)

// ---------------- GEMM: C = A * B^T + bias ----------------
// A: MxK row-major, B: NxK row-major, C: MxN row-major. K % 16 == 0.
#define BM 64
#define BN 64
#define BK 16

__global__ __launch_bounds__(256) void gemm_nt(const float* __restrict__ A,
                                               const float* __restrict__ B,
                                               const float* __restrict__ bias,
                                               float* __restrict__ C,
                                               int M, int N, int K)
{
    __shared__ float As[BK][BM + 4];
    __shared__ float Bs[BK][BN + 4];
    const int tid = threadIdx.x;
    const int bm = blockIdx.x, bn = blockIdx.y;
    const int tx = tid & 15, ty = tid >> 4;
    const int row0 = bm * BM + ty * 4;
    const int col0 = bn * BN + tx * 4;
    const int lrow = tid >> 2;        // 0..63
    const int lk4  = (tid & 3) << 2;  // 0,4,8,12

    float acc[4][4] = {{0.f, 0.f, 0.f, 0.f}, {0.f, 0.f, 0.f, 0.f},
                       {0.f, 0.f, 0.f, 0.f}, {0.f, 0.f, 0.f, 0.f}};

    for (int k0 = 0; k0 < K; k0 += BK) {
        const int gm = bm * BM + lrow;
        float4 av = make_float4(0.f, 0.f, 0.f, 0.f);
        if (gm < M) av = *(const float4*)(A + (size_t)gm * K + k0 + lk4);
        const int gn = bn * BN + lrow;
        float4 bv = make_float4(0.f, 0.f, 0.f, 0.f);
        if (gn < N) bv = *(const float4*)(B + (size_t)gn * K + k0 + lk4);

        As[lk4 + 0][lrow] = av.x;
        As[lk4 + 1][lrow] = av.y;
        As[lk4 + 2][lrow] = av.z;
        As[lk4 + 3][lrow] = av.w;
        Bs[lk4 + 0][lrow] = bv.x;
        Bs[lk4 + 1][lrow] = bv.y;
        Bs[lk4 + 2][lrow] = bv.z;
        Bs[lk4 + 3][lrow] = bv.w;
        __syncthreads();

#pragma unroll
        for (int kk = 0; kk < BK; ++kk) {
            float4 a = *(const float4*)&As[kk][ty * 4];
            float4 b = *(const float4*)&Bs[kk][tx * 4];
            acc[0][0] += a.x * b.x; acc[0][1] += a.x * b.y; acc[0][2] += a.x * b.z; acc[0][3] += a.x * b.w;
            acc[1][0] += a.y * b.x; acc[1][1] += a.y * b.y; acc[1][2] += a.y * b.z; acc[1][3] += a.y * b.w;
            acc[2][0] += a.z * b.x; acc[2][1] += a.z * b.y; acc[2][2] += a.z * b.z; acc[2][3] += a.z * b.w;
            acc[3][0] += a.w * b.x; acc[3][1] += a.w * b.y; acc[3][2] += a.w * b.z; acc[3][3] += a.w * b.w;
        }
        __syncthreads();
    }

#pragma unroll
    for (int i = 0; i < 4; ++i) {
        const int r = row0 + i;
        if (r < M) {
#pragma unroll
            for (int j = 0; j < 4; ++j) {
                const int c = col0 + j;
                if (c < N) C[(size_t)r * N + c] = acc[i][j] + bias[c];
            }
        }
    }
}

// ---------------- RoPE 2D, in-place on q_p and k_p rows of qkv ----------------
__global__ __launch_bounds__(256) void rope_kernel(float* __restrict__ qkv,
                                                   const float* __restrict__ coords)
{
    const int idx = blockIdx.x * 256 + threadIdx.x;   // PATCH_LEN * NHEAD * 32
    const int l = idx >> 8;
    const int rem = idx & 255;
    const int h = rem >> 5;
    const int i = rem & 31;   // pair index 0..31

    const float cx = coords[l * 2 + 0] * 1e-5f;
    const float cy = coords[l * 2 + 1] * 1e-5f;
    const float basev = (i < 16) ? cx : cy;
    const int fi = (i < 16) ? i : (i - 16);
    const float inv_freq = expf(-((float)fi * (1.0f / 16.0f)) * logf(10000.0f));
    const float f = basev * inv_freq;
    const float cs = cosf(f), sn = sinf(f);

    const size_t base = (size_t)(NUM_CLS + l) * QKV_LD + h * HD + 2 * i;
    float2 q = *(float2*)(qkv + base);
    *(float2*)(qkv + base) = make_float2(q.x * cs - q.y * sn, q.y * cs + q.x * sn);
    float2 k = *(float2*)(qkv + base + EMBED);
    *(float2*)(qkv + base + EMBED) = make_float2(k.x * cs - k.y * sn, k.y * cs + k.x * sn);
}

// ---------------- cls attention, flash-decode split-K ----------------
// Partial pass: grid (NHEAD, NCHUNK). Each block handles ALL 4 cls queries of
// head h over a 256-key chunk: local softmax (m,l) + unnormalized PV partial.
// Partials land in d_out (dead until the final GEMM overwrites it all).
#define CCH 256
#define NCHUNK ((S_TOT + CCH - 1) / CCH)   // 33
#define PSTRIDE 68                          // 64 o + m + l + pad (16B-aligned)

__global__ __launch_bounds__(256) void cls_attn_partial(const float* __restrict__ qkv,
                                                        float* __restrict__ part)
{
    const int h = blockIdx.x;
    const int c = blockIdx.y;
    const int tid = threadIdx.x;
    const int base = c * CCH;

    __shared__ float qs[4][64];
    __shared__ float sc[4][CCH];
    __shared__ float ored[4][4][64];   // [group][qi][d]
    __shared__ float ml[4][2];

    {
        const int qi = tid >> 6, d = tid & 63;
        qs[qi][d] = qkv[(size_t)qi * QKV_LD + h * HD + d];
    }
    __syncthreads();

    // scores: thread t -> key base+t, 4 queries at once (qs reads broadcast)
    {
        const int j = base + tid;
        float s0 = -INFINITY, s1 = -INFINITY, s2 = -INFINITY, s3 = -INFINITY;
        if (j < S_TOT) {
            const float* kp = qkv + (size_t)j * QKV_LD + EMBED + h * HD;
            float a0 = 0.f, a1 = 0.f, a2 = 0.f, a3 = 0.f;
#pragma unroll
            for (int d4 = 0; d4 < 64; d4 += 4) {
                const float4 kv = *(const float4*)(kp + d4);
                a0 += qs[0][d4] * kv.x + qs[0][d4+1] * kv.y + qs[0][d4+2] * kv.z + qs[0][d4+3] * kv.w;
                a1 += qs[1][d4] * kv.x + qs[1][d4+1] * kv.y + qs[1][d4+2] * kv.z + qs[1][d4+3] * kv.w;
                a2 += qs[2][d4] * kv.x + qs[2][d4+1] * kv.y + qs[2][d4+2] * kv.z + qs[2][d4+3] * kv.w;
                a3 += qs[3][d4] * kv.x + qs[3][d4+1] * kv.y + qs[3][d4+2] * kv.z + qs[3][d4+3] * kv.w;
            }
            s0 = a0 * 0.125f; s1 = a1 * 0.125f; s2 = a2 * 0.125f; s3 = a3 * 0.125f;
        }
        sc[0][tid] = s0; sc[1][tid] = s1; sc[2][tid] = s2; sc[3][tid] = s3;
    }
    __syncthreads();

    // local softmax: wave w owns query w (no cross-wave syncs needed)
    const int w = tid >> 6, lane = tid & 63;
    {
        float m = -INFINITY;
#pragma unroll
        for (int j = lane; j < CCH; j += 64) m = fmaxf(m, sc[w][j]);
#pragma unroll
        for (int off = 32; off > 0; off >>= 1) m = fmaxf(m, __shfl_xor(m, off, 64));
        float lsum = 0.f;
#pragma unroll
        for (int j = lane; j < CCH; j += 64) {
            const float e = expf(sc[w][j] - m);   // -inf lanes -> 0
            sc[w][j] = e;
            lsum += e;
        }
#pragma unroll
        for (int off = 32; off > 0; off >>= 1) lsum += __shfl_xor(lsum, off, 64);
        if (lane == 0) { ml[w][0] = m; ml[w][1] = lsum; }
    }
    __syncthreads();

    // PV: group g covers keys g, g+4, ... (coalesced v reads, lane = dim)
    {
        const int g = w, d = lane;
        float a0 = 0.f, a1 = 0.f, a2 = 0.f, a3 = 0.f;
        for (int jj = g; jj < CCH; jj += 4) {
            const int j = base + jj;
            if (j >= S_TOT) break;
            const float vv = qkv[(size_t)j * QKV_LD + 2 * EMBED + h * HD + d];
            a0 += sc[0][jj] * vv; a1 += sc[1][jj] * vv;
            a2 += sc[2][jj] * vv; a3 += sc[3][jj] * vv;
        }
        ored[g][0][d] = a0; ored[g][1][d] = a1; ored[g][2][d] = a2; ored[g][3][d] = a3;
    }
    __syncthreads();

    // combine the 4 groups, store partial (o[64], m, l)
    {
        const int qi = tid >> 6, d = tid & 63;
        const float o = ored[0][qi][d] + ored[1][qi][d] + ored[2][qi][d] + ored[3][qi][d];
        float* pb = part + ((size_t)(h * NCHUNK + c) * 4 + qi) * PSTRIDE;
        pb[d] = o;
        if (d == 0) { pb[64] = ml[qi][0]; pb[65] = ml[qi][1]; }
    }
}

__global__ __launch_bounds__(256) void cls_attn_combine(const float* __restrict__ part,
                                                        float* __restrict__ attn)
{
    const int h = blockIdx.x;
    const int qi = threadIdx.x >> 6, d = threadIdx.x & 63;
    float M = -INFINITY;
    for (int c = 0; c < NCHUNK; ++c)
        M = fmaxf(M, part[((size_t)(h * NCHUNK + c) * 4 + qi) * PSTRIDE + 64]);
    float acc = 0.f, L = 0.f;
    for (int c = 0; c < NCHUNK; ++c) {
        const float* pb = part + ((size_t)(h * NCHUNK + c) * 4 + qi) * PSTRIDE;
        const float s = expf(pb[64] - M);
        acc += s * pb[d];
        L   += s * pb[65];
    }
    attn[(size_t)qi * EMBED + h * HD + d] = acc / L;
}

// ---------------- patch attention: one block per (32-token tile, head) ----------------
__global__ __launch_bounds__(256) void patch_attn(const float* __restrict__ qkv,
                                                  float* __restrict__ attn)
{
    const int l0 = blockIdx.x * 32;
    const int h = blockIdx.y;
    const int tid = threadIdx.x;

    __shared__ float qt[32][68];
    __shared__ float kw[96][68];
    __shared__ float vw[96][68];
    __shared__ float kc[4][68];
    __shared__ float vc[4][68];
    __shared__ float sc[32][69];

    for (int idx = tid; idx < 32 * 64; idx += 256) {
        const int t = idx >> 6, d = idx & 63;
        qt[t][d] = qkv[(size_t)(NUM_CLS + l0 + t) * QKV_LD + h * HD + d];
    }
    for (int idx = tid; idx < 96 * 64; idx += 256) {
        const int r = idx >> 6, d = idx & 63;
        const int pos = l0 - WIN + r;
        const bool ok = (pos >= 0) && (pos < PATCH_LEN);
        kw[r][d] = ok ? qkv[(size_t)(NUM_CLS + pos) * QKV_LD + EMBED + h * HD + d] : 0.f;
        vw[r][d] = ok ? qkv[(size_t)(NUM_CLS + pos) * QKV_LD + 2 * EMBED + h * HD + d] : 0.f;
    }
    {
        const int r = tid >> 6, d = tid & 63;
        kc[r][d] = qkv[(size_t)r * QKV_LD + EMBED + h * HD + d];
        vc[r][d] = qkv[(size_t)r * QKV_LD + 2 * EMBED + h * HD + d];
    }
    __syncthreads();

    {
        const int t = tid >> 3, g = tid & 7;
        for (int key = g; key < CTX; key += 8) {
            float s;
            if (key < NUM_CLS) {
                float d0 = 0.f;
#pragma unroll
                for (int d = 0; d < 64; ++d) d0 += qt[t][d] * kc[key][d];
                s = d0 * 0.125f;
            } else {
                const int w = key - NUM_CLS;
                const int pos = l0 + t + w - WIN;
                if (pos < 0 || pos >= PATCH_LEN) {
                    s = NEGV;
                } else {
                    const int r = t + w;
                    float d0 = 0.f;
#pragma unroll
                    for (int d = 0; d < 64; ++d) d0 += qt[t][d] * kw[r][d];
                    s = d0 * 0.125f;
                }
            }
            sc[t][key] = s;
        }
    }
    __syncthreads();

    if (tid < 32) {
        const int t = tid;
        float m = -INFINITY;
        for (int key = 0; key < CTX; ++key) m = fmaxf(m, sc[t][key]);
        float sum = 0.f;
        for (int key = 0; key < CTX; ++key) {
            const float p = expf(sc[t][key] - m);
            sc[t][key] = p;
            sum += p;
        }
        const float inv = 1.f / sum;
        for (int key = 0; key < CTX; ++key) sc[t][key] *= inv;
    }
    __syncthreads();

    {
        const int d = tid & 63, tg = tid >> 6;
        for (int t = tg; t < 32; t += 4) {
            float acc = 0.f;
#pragma unroll
            for (int key = 0; key < NUM_CLS; ++key) acc += sc[t][key] * vc[key][d];
            for (int w = 0; w < WLEN; ++w) acc += sc[t][NUM_CLS + w] * vw[t + w][d];
            attn[(size_t)(NUM_CLS + l0 + t) * EMBED + h * HD + d] = acc;
        }
    }
}

extern "C" void kernel_launch(void* const* d_in, const int* in_sizes, int n_in,
                              void* d_out, int out_size, void* d_ws, size_t ws_size,
                              hipStream_t stream)
{
    const float* x      = (const float*)d_in[0];
    const float* coords = (const float*)d_in[1];
    const float* w_qkv  = (const float*)d_in[2];
    const float* b_qkv  = (const float*)d_in[3];
    const float* w_out  = (const float*)d_in[4];
    const float* b_out  = (const float*)d_in[5];
    float* out = (float*)d_out;

    // workspace: qkv (S_TOT x 1536) | attn (S_TOT x 512)   ~67.1 MB
    float* qkv  = (float*)d_ws;
    float* attn = qkv + (size_t)S_TOT * QKV_LD;
    // cls partials live in d_out (287 KB; final GEMM overwrites every element)
    float* part = out;

    gemm_nt<<<dim3((S_TOT + BM - 1) / BM, (3 * EMBED) / BN), 256, 0, stream>>>(
        x, w_qkv, b_qkv, qkv, S_TOT, 3 * EMBED, EMBED);

    rope_kernel<<<(PATCH_LEN * NHEAD * 32) / 256, 256, 0, stream>>>(qkv, coords);

    cls_attn_partial<<<dim3(NHEAD, NCHUNK), 256, 0, stream>>>(qkv, part);
    cls_attn_combine<<<NHEAD, 256, 0, stream>>>(part, attn);

    patch_attn<<<dim3(PATCH_LEN / 32, NHEAD), 256, 0, stream>>>(qkv, attn);

    gemm_nt<<<dim3((S_TOT + BM - 1) / BM, EMBED / BN), 256, 0, stream>>>(
        attn, w_out, b_out, out, S_TOT, EMBED, EMBED);
}

// Round 3
// 302.016 us; speedup vs baseline: 3.4321x; 1.6642x over previous
//
#include <hip/hip_runtime.h>
#include <math.h>

#define EMBED 512
#define NHEAD 8
#define HD 64
#define NUM_CLS 4
#define WIN 32
#define WLEN 65          // 2*WIN+1
#define CTX 69           // NUM_CLS + WLEN
#define PATCH_LEN 8192
#define S_TOT 8196       // NUM_CLS + PATCH_LEN
#define QKV_LD 1536
#define NEGV (-1e30f)

typedef short bf16x8 __attribute__((ext_vector_type(8)));
typedef float f32x4 __attribute__((ext_vector_type(4)));

__device__ __forceinline__ unsigned short f2bf(float f) {
    unsigned u = __float_as_uint(f);
    return (unsigned short)((u + 0x7fffu + ((u >> 16) & 1u)) >> 16);
}

// ---------------- fp32 -> bf16 cast (n % 4 == 0) ----------------
__global__ __launch_bounds__(256) void cast_bf16(const float* __restrict__ src,
                                                 unsigned short* __restrict__ dst, int n)
{
    const int i = (blockIdx.x * 256 + threadIdx.x) * 4;
    if (i < n) {
        const float4 v = *(const float4*)(src + i);
        ushort4 o;
        o.x = f2bf(v.x); o.y = f2bf(v.y); o.z = f2bf(v.z); o.w = f2bf(v.w);
        *(ushort4*)(dst + i) = o;
    }
}

// ---------------- bf16 MFMA GEMM: C = A * B^T + bias (fp32 out) ----------------
// A: MxK bf16 row-major, B: NxK bf16 row-major. K%32==0, N%128==0, M ragged.
// 128x128 tile, BK=32, 4 waves each owning 64x64 via 4x4 mfma_16x16x32 tiles.
__global__ __launch_bounds__(256) void gemm_bf16_nt(const unsigned short* __restrict__ A,
                                                    const unsigned short* __restrict__ B,
                                                    const float* __restrict__ bias,
                                                    float* __restrict__ C,
                                                    int M, int N, int K)
{
    __shared__ unsigned short As[128 * 32];
    __shared__ unsigned short Bs[128 * 32];
    const int tid = threadIdx.x;
    const int lane = tid & 63, w = tid >> 6;
    const int bm = blockIdx.x, bn = blockIdx.y;

    // staging: thread covers 16B element-groups tid and tid+256 of the 128x32 tile
    const int ar0 = tid >> 2;            // row 0..63 (round 0); +64 for round 1
    const int col8 = (tid & 3) * 8;      // k-offset 0,8,16,24
    int gm0 = bm * 128 + ar0;       if (gm0 >= M) gm0 = M - 1;   // clamp: dup reads, rows never stored
    int gm1 = bm * 128 + ar0 + 64;  if (gm1 >= M) gm1 = M - 1;
    const int gn0 = bn * 128 + ar0;
    const int gn1 = bn * 128 + ar0 + 64;
    const unsigned short* pa0 = A + (size_t)gm0 * K + col8;
    const unsigned short* pa1 = A + (size_t)gm1 * K + col8;
    const unsigned short* pb0 = B + (size_t)gn0 * K + col8;
    const unsigned short* pb1 = B + (size_t)gn1 * K + col8;
    unsigned short* la0 = As + tid * 8;
    unsigned short* la1 = As + (tid + 256) * 8;
    unsigned short* lb0 = Bs + tid * 8;
    unsigned short* lb1 = Bs + (tid + 256) * 8;

    const int wr = (w & 1) * 64;         // wave row offset in tile
    const int wc = (w >> 1) * 64;        // wave col offset
    const int fr = lane & 15;            // fragment row (A) / col (B)
    const int fk = (lane >> 4) * 8;      // fragment k offset

    f32x4 acc[4][4];
#pragma unroll
    for (int mi = 0; mi < 4; ++mi)
#pragma unroll
        for (int ni = 0; ni < 4; ++ni) acc[mi][ni] = (f32x4)0.f;

    for (int k0 = 0; k0 < K; k0 += 32) {
        __builtin_amdgcn_global_load_lds((const __attribute__((address_space(1))) void*)(pa0 + k0),
                                         (__attribute__((address_space(3))) void*)la0, 16, 0, 0);
        __builtin_amdgcn_global_load_lds((const __attribute__((address_space(1))) void*)(pa1 + k0),
                                         (__attribute__((address_space(3))) void*)la1, 16, 0, 0);
        __builtin_amdgcn_global_load_lds((const __attribute__((address_space(1))) void*)(pb0 + k0),
                                         (__attribute__((address_space(3))) void*)lb0, 16, 0, 0);
        __builtin_amdgcn_global_load_lds((const __attribute__((address_space(1))) void*)(pb1 + k0),
                                         (__attribute__((address_space(3))) void*)lb1, 16, 0, 0);
        __syncthreads();   // compiler emits vmcnt(0) drain before s_barrier

        bf16x8 af[4], bf[4];
#pragma unroll
        for (int mi = 0; mi < 4; ++mi)
            af[mi] = *(const bf16x8*)(As + (wr + mi * 16 + fr) * 32 + fk);
#pragma unroll
        for (int ni = 0; ni < 4; ++ni)
            bf[ni] = *(const bf16x8*)(Bs + (wc + ni * 16 + fr) * 32 + fk);
#pragma unroll
        for (int mi = 0; mi < 4; ++mi)
#pragma unroll
            for (int ni = 0; ni < 4; ++ni)
                acc[mi][ni] = __builtin_amdgcn_mfma_f32_16x16x32_bf16(af[mi], bf[ni], acc[mi][ni], 0, 0, 0);
        __syncthreads();   // protect LDS from next iteration's staging
    }

    // epilogue: C/D layout col=lane&15, row=(lane>>4)*4+reg
    const int ccol = bn * 128 + wc + fr;
#pragma unroll
    for (int mi = 0; mi < 4; ++mi) {
        const int rbase = bm * 128 + wr + mi * 16 + (lane >> 4) * 4;
#pragma unroll
        for (int r = 0; r < 4; ++r) {
            const int row = rbase + r;
            if (row < M) {
#pragma unroll
                for (int ni = 0; ni < 4; ++ni)
                    C[(size_t)row * N + ccol + ni * 16] = acc[mi][ni][r] + bias[ccol + ni * 16];
            }
        }
    }
}

// ---------------- RoPE 2D, in-place on q_p and k_p rows of qkv ----------------
__global__ __launch_bounds__(256) void rope_kernel(float* __restrict__ qkv,
                                                   const float* __restrict__ coords)
{
    const int idx = blockIdx.x * 256 + threadIdx.x;
    const int l = idx >> 8;
    const int rem = idx & 255;
    const int h = rem >> 5;
    const int i = rem & 31;

    const float cx = coords[l * 2 + 0] * 1e-5f;
    const float cy = coords[l * 2 + 1] * 1e-5f;
    const float basev = (i < 16) ? cx : cy;
    const int fi = (i < 16) ? i : (i - 16);
    const float inv_freq = expf(-((float)fi * (1.0f / 16.0f)) * logf(10000.0f));
    const float f = basev * inv_freq;
    const float cs = cosf(f), sn = sinf(f);

    const size_t base = (size_t)(NUM_CLS + l) * QKV_LD + h * HD + 2 * i;
    float2 q = *(float2*)(qkv + base);
    *(float2*)(qkv + base) = make_float2(q.x * cs - q.y * sn, q.y * cs + q.x * sn);
    float2 k = *(float2*)(qkv + base + EMBED);
    *(float2*)(qkv + base + EMBED) = make_float2(k.x * cs - k.y * sn, k.y * cs + k.x * sn);
}

// ---------------- cls attention, flash-decode split-K ----------------
#define CCH 256
#define NCHUNK ((S_TOT + CCH - 1) / CCH)   // 33
#define PSTRIDE 68

__global__ __launch_bounds__(256) void cls_attn_partial(const float* __restrict__ qkv,
                                                        float* __restrict__ part)
{
    const int h = blockIdx.x;
    const int c = blockIdx.y;
    const int tid = threadIdx.x;
    const int base = c * CCH;

    __shared__ float qs[4][64];
    __shared__ float sc[4][CCH];
    __shared__ float ored[4][4][64];
    __shared__ float ml[4][2];

    {
        const int qi = tid >> 6, d = tid & 63;
        qs[qi][d] = qkv[(size_t)qi * QKV_LD + h * HD + d];
    }
    __syncthreads();

    {
        const int j = base + tid;
        float s0 = -INFINITY, s1 = -INFINITY, s2 = -INFINITY, s3 = -INFINITY;
        if (j < S_TOT) {
            const float* kp = qkv + (size_t)j * QKV_LD + EMBED + h * HD;
            float a0 = 0.f, a1 = 0.f, a2 = 0.f, a3 = 0.f;
#pragma unroll
            for (int d4 = 0; d4 < 64; d4 += 4) {
                const float4 kv = *(const float4*)(kp + d4);
                a0 += qs[0][d4] * kv.x + qs[0][d4+1] * kv.y + qs[0][d4+2] * kv.z + qs[0][d4+3] * kv.w;
                a1 += qs[1][d4] * kv.x + qs[1][d4+1] * kv.y + qs[1][d4+2] * kv.z + qs[1][d4+3] * kv.w;
                a2 += qs[2][d4] * kv.x + qs[2][d4+1] * kv.y + qs[2][d4+2] * kv.z + qs[2][d4+3] * kv.w;
                a3 += qs[3][d4] * kv.x + qs[3][d4+1] * kv.y + qs[3][d4+2] * kv.z + qs[3][d4+3] * kv.w;
            }
            s0 = a0 * 0.125f; s1 = a1 * 0.125f; s2 = a2 * 0.125f; s3 = a3 * 0.125f;
        }
        sc[0][tid] = s0; sc[1][tid] = s1; sc[2][tid] = s2; sc[3][tid] = s3;
    }
    __syncthreads();

    const int w = tid >> 6, lane = tid & 63;
    {
        float m = -INFINITY;
#pragma unroll
        for (int j = lane; j < CCH; j += 64) m = fmaxf(m, sc[w][j]);
#pragma unroll
        for (int off = 32; off > 0; off >>= 1) m = fmaxf(m, __shfl_xor(m, off, 64));
        float lsum = 0.f;
#pragma unroll
        for (int j = lane; j < CCH; j += 64) {
            const float e = expf(sc[w][j] - m);
            sc[w][j] = e;
            lsum += e;
        }
#pragma unroll
        for (int off = 32; off > 0; off >>= 1) lsum += __shfl_xor(lsum, off, 64);
        if (lane == 0) { ml[w][0] = m; ml[w][1] = lsum; }
    }
    __syncthreads();

    {
        const int g = w, d = lane;
        float a0 = 0.f, a1 = 0.f, a2 = 0.f, a3 = 0.f;
        for (int jj = g; jj < CCH; jj += 4) {
            const int j = base + jj;
            if (j >= S_TOT) break;
            const float vv = qkv[(size_t)j * QKV_LD + 2 * EMBED + h * HD + d];
            a0 += sc[0][jj] * vv; a1 += sc[1][jj] * vv;
            a2 += sc[2][jj] * vv; a3 += sc[3][jj] * vv;
        }
        ored[g][0][d] = a0; ored[g][1][d] = a1; ored[g][2][d] = a2; ored[g][3][d] = a3;
    }
    __syncthreads();

    {
        const int qi = tid >> 6, d = tid & 63;
        const float o = ored[0][qi][d] + ored[1][qi][d] + ored[2][qi][d] + ored[3][qi][d];
        float* pb = part + ((size_t)(h * NCHUNK + c) * 4 + qi) * PSTRIDE;
        pb[d] = o;
        if (d == 0) { pb[64] = ml[qi][0]; pb[65] = ml[qi][1]; }
    }
}

__global__ __launch_bounds__(256) void cls_attn_combine(const float* __restrict__ part,
                                                        unsigned short* __restrict__ attn)
{
    const int h = blockIdx.x;
    const int qi = threadIdx.x >> 6, d = threadIdx.x & 63;
    float M = -INFINITY;
    for (int c = 0; c < NCHUNK; ++c)
        M = fmaxf(M, part[((size_t)(h * NCHUNK + c) * 4 + qi) * PSTRIDE + 64]);
    float acc = 0.f, L = 0.f;
    for (int c = 0; c < NCHUNK; ++c) {
        const float* pb = part + ((size_t)(h * NCHUNK + c) * 4 + qi) * PSTRIDE;
        const float s = expf(pb[64] - M);
        acc += s * pb[d];
        L   += s * pb[65];
    }
    attn[(size_t)qi * EMBED + h * HD + d] = f2bf(acc / L);
}

// ---------------- patch attention: one block per (32-token tile, head) ----------------
__global__ __launch_bounds__(256) void patch_attn(const float* __restrict__ qkv,
                                                  unsigned short* __restrict__ attn)
{
    const int l0 = blockIdx.x * 32;
    const int h = blockIdx.y;
    const int tid = threadIdx.x;

    __shared__ float qt[32][68];
    __shared__ float kw[96][68];
    __shared__ float vw[96][68];
    __shared__ float kc[4][68];
    __shared__ float vc[4][68];
    __shared__ float sc[32][69];

    for (int idx = tid; idx < 32 * 64; idx += 256) {
        const int t = idx >> 6, d = idx & 63;
        qt[t][d] = qkv[(size_t)(NUM_CLS + l0 + t) * QKV_LD + h * HD + d];
    }
    for (int idx = tid; idx < 96 * 64; idx += 256) {
        const int r = idx >> 6, d = idx & 63;
        const int pos = l0 - WIN + r;
        const bool ok = (pos >= 0) && (pos < PATCH_LEN);
        kw[r][d] = ok ? qkv[(size_t)(NUM_CLS + pos) * QKV_LD + EMBED + h * HD + d] : 0.f;
        vw[r][d] = ok ? qkv[(size_t)(NUM_CLS + pos) * QKV_LD + 2 * EMBED + h * HD + d] : 0.f;
    }
    {
        const int r = tid >> 6, d = tid & 63;
        kc[r][d] = qkv[(size_t)r * QKV_LD + EMBED + h * HD + d];
        vc[r][d] = qkv[(size_t)r * QKV_LD + 2 * EMBED + h * HD + d];
    }
    __syncthreads();

    {
        const int t = tid >> 3, g = tid & 7;
        for (int key = g; key < CTX; key += 8) {
            float s;
            if (key < NUM_CLS) {
                float d0 = 0.f;
#pragma unroll
                for (int d = 0; d < 64; ++d) d0 += qt[t][d] * kc[key][d];
                s = d0 * 0.125f;
            } else {
                const int w = key - NUM_CLS;
                const int pos = l0 + t + w - WIN;
                if (pos < 0 || pos >= PATCH_LEN) {
                    s = NEGV;
                } else {
                    const int r = t + w;
                    float d0 = 0.f;
#pragma unroll
                    for (int d = 0; d < 64; ++d) d0 += qt[t][d] * kw[r][d];
                    s = d0 * 0.125f;
                }
            }
            sc[t][key] = s;
        }
    }
    __syncthreads();

    if (tid < 32) {
        const int t = tid;
        float m = -INFINITY;
        for (int key = 0; key < CTX; ++key) m = fmaxf(m, sc[t][key]);
        float sum = 0.f;
        for (int key = 0; key < CTX; ++key) {
            const float p = expf(sc[t][key] - m);
            sc[t][key] = p;
            sum += p;
        }
        const float inv = 1.f / sum;
        for (int key = 0; key < CTX; ++key) sc[t][key] *= inv;
    }
    __syncthreads();

    {
        const int d = tid & 63, tg = tid >> 6;
        for (int t = tg; t < 32; t += 4) {
            float acc = 0.f;
#pragma unroll
            for (int key = 0; key < NUM_CLS; ++key) acc += sc[t][key] * vc[key][d];
            for (int w = 0; w < WLEN; ++w) acc += sc[t][NUM_CLS + w] * vw[t + w][d];
            attn[(size_t)(NUM_CLS + l0 + t) * EMBED + h * HD + d] = f2bf(acc);
        }
    }
}

extern "C" void kernel_launch(void* const* d_in, const int* in_sizes, int n_in,
                              void* d_out, int out_size, void* d_ws, size_t ws_size,
                              hipStream_t stream)
{
    const float* x      = (const float*)d_in[0];
    const float* coords = (const float*)d_in[1];
    const float* w_qkv  = (const float*)d_in[2];
    const float* b_qkv  = (const float*)d_in[3];
    const float* w_out  = (const float*)d_in[4];
    const float* b_out  = (const float*)d_in[5];
    float* out = (float*)d_out;

    // ws layout: qkv fp32 (50.3 MB) | attn bf16 (8.4 MB) | w_out bf16 (0.5 MB)
    float* qkv = (float*)d_ws;
    unsigned short* attnb = (unsigned short*)(qkv + (size_t)S_TOT * QKV_LD);
    unsigned short* wob   = attnb + (size_t)S_TOT * EMBED;

    // d_out scratch (dead until final GEMM): x bf16 | w_qkv bf16 | cls partials
    unsigned short* xb  = (unsigned short*)d_out;
    unsigned short* wqb = xb + (size_t)S_TOT * EMBED;
    float* part = (float*)(wqb + (size_t)3 * EMBED * EMBED);

    cast_bf16<<<(S_TOT * EMBED / 4 + 255) / 256, 256, 0, stream>>>(x, xb, S_TOT * EMBED);
    cast_bf16<<<(3 * EMBED * EMBED / 4 + 255) / 256, 256, 0, stream>>>(w_qkv, wqb, 3 * EMBED * EMBED);
    cast_bf16<<<(EMBED * EMBED / 4 + 255) / 256, 256, 0, stream>>>(w_out, wob, EMBED * EMBED);

    // 1) qkv = x @ w_qkv^T + b_qkv   (bf16 MFMA, fp32 out)
    gemm_bf16_nt<<<dim3((S_TOT + 127) / 128, (3 * EMBED) / 128), 256, 0, stream>>>(
        xb, wqb, b_qkv, qkv, S_TOT, 3 * EMBED, EMBED);

    // 2) RoPE in place on q_p, k_p (fp32)
    rope_kernel<<<(PATCH_LEN * NHEAD * 32) / 256, 256, 0, stream>>>(qkv, coords);

    // 3) cls attention (flash-decode split-K), writes attn rows 0..3 (bf16)
    cls_attn_partial<<<dim3(NHEAD, NCHUNK), 256, 0, stream>>>(qkv, part);
    cls_attn_combine<<<NHEAD, 256, 0, stream>>>(part, attnb);

    // 4) windowed patch attention, writes attn rows 4..8195 (bf16)
    patch_attn<<<dim3(PATCH_LEN / 32, NHEAD), 256, 0, stream>>>(qkv, attnb);

    // 5) out = attn @ w_out^T + b_out   (bf16 MFMA, fp32 out)
    gemm_bf16_nt<<<dim3((S_TOT + 127) / 128, EMBED / 128), 256, 0, stream>>>(
        attnb, wob, b_out, out, S_TOT, EMBED, EMBED);
}

// Round 4
// 232.767 us; speedup vs baseline: 4.4531x; 1.2975x over previous
//
#include <hip/hip_runtime.h>
#include <math.h>

#define EMBED 512
#define NHEAD 8
#define HD 64
#define NUM_CLS 4
#define WIN 32
#define WLEN 65          // 2*WIN+1
#define PATCH_LEN 8192
#define S_TOT 8196       // NUM_CLS + PATCH_LEN
#define QKV_LD 1536
#define VT_LD 8200       // padded, multiple of 8 -> 16B-aligned rows

typedef short bf16x8 __attribute__((ext_vector_type(8)));
typedef float f32x4 __attribute__((ext_vector_type(4)));

__device__ __forceinline__ unsigned short f2bf(float f) {
    unsigned u = __float_as_uint(f);
    return (unsigned short)((u + 0x7fffu + ((u >> 16) & 1u)) >> 16);
}

// ---------------- fp32 -> bf16 cast (n % 4 == 0) ----------------
__global__ __launch_bounds__(256) void cast_bf16(const float* __restrict__ src,
                                                 unsigned short* __restrict__ dst, int n)
{
    const int i = (blockIdx.x * 256 + threadIdx.x) * 4;
    if (i < n) {
        const float4 v = *(const float4*)(src + i);
        ushort4 o;
        o.x = f2bf(v.x); o.y = f2bf(v.y); o.z = f2bf(v.z); o.w = f2bf(v.w);
        *(ushort4*)(dst + i) = o;
    }
}

// ---------------- bf16 MFMA GEMM: C = A * B^T + bias (fp32 out) ----------------
__global__ __launch_bounds__(256) void gemm_bf16_nt(const unsigned short* __restrict__ A,
                                                    const unsigned short* __restrict__ B,
                                                    const float* __restrict__ bias,
                                                    float* __restrict__ C,
                                                    int M, int N, int K)
{
    __shared__ __align__(16) unsigned short As[128 * 32];
    __shared__ __align__(16) unsigned short Bs[128 * 32];
    const int tid = threadIdx.x;
    const int lane = tid & 63, w = tid >> 6;
    const int bm = blockIdx.x, bn = blockIdx.y;

    const int ar0 = tid >> 2;
    const int col8 = (tid & 3) * 8;
    int gm0 = bm * 128 + ar0;       if (gm0 >= M) gm0 = M - 1;
    int gm1 = bm * 128 + ar0 + 64;  if (gm1 >= M) gm1 = M - 1;
    const int gn0 = bn * 128 + ar0;
    const int gn1 = bn * 128 + ar0 + 64;
    const unsigned short* pa0 = A + (size_t)gm0 * K + col8;
    const unsigned short* pa1 = A + (size_t)gm1 * K + col8;
    const unsigned short* pb0 = B + (size_t)gn0 * K + col8;
    const unsigned short* pb1 = B + (size_t)gn1 * K + col8;
    unsigned short* la0 = As + tid * 8;
    unsigned short* la1 = As + (tid + 256) * 8;
    unsigned short* lb0 = Bs + tid * 8;
    unsigned short* lb1 = Bs + (tid + 256) * 8;

    const int wr = (w & 1) * 64;
    const int wc = (w >> 1) * 64;
    const int fr = lane & 15;
    const int fk = (lane >> 4) * 8;

    f32x4 acc[4][4];
#pragma unroll
    for (int mi = 0; mi < 4; ++mi)
#pragma unroll
        for (int ni = 0; ni < 4; ++ni) acc[mi][ni] = (f32x4)0.f;

    for (int k0 = 0; k0 < K; k0 += 32) {
        __builtin_amdgcn_global_load_lds((const __attribute__((address_space(1))) void*)(pa0 + k0),
                                         (__attribute__((address_space(3))) void*)la0, 16, 0, 0);
        __builtin_amdgcn_global_load_lds((const __attribute__((address_space(1))) void*)(pa1 + k0),
                                         (__attribute__((address_space(3))) void*)la1, 16, 0, 0);
        __builtin_amdgcn_global_load_lds((const __attribute__((address_space(1))) void*)(pb0 + k0),
                                         (__attribute__((address_space(3))) void*)lb0, 16, 0, 0);
        __builtin_amdgcn_global_load_lds((const __attribute__((address_space(1))) void*)(pb1 + k0),
                                         (__attribute__((address_space(3))) void*)lb1, 16, 0, 0);
        __syncthreads();

        bf16x8 af[4], bf[4];
#pragma unroll
        for (int mi = 0; mi < 4; ++mi)
            af[mi] = *(const bf16x8*)(As + (wr + mi * 16 + fr) * 32 + fk);
#pragma unroll
        for (int ni = 0; ni < 4; ++ni)
            bf[ni] = *(const bf16x8*)(Bs + (wc + ni * 16 + fr) * 32 + fk);
#pragma unroll
        for (int mi = 0; mi < 4; ++mi)
#pragma unroll
            for (int ni = 0; ni < 4; ++ni)
                acc[mi][ni] = __builtin_amdgcn_mfma_f32_16x16x32_bf16(af[mi], bf[ni], acc[mi][ni], 0, 0, 0);
        __syncthreads();
    }

    const int ccol = bn * 128 + wc + fr;
#pragma unroll
    for (int mi = 0; mi < 4; ++mi) {
        const int rbase = bm * 128 + wr + mi * 16 + (lane >> 4) * 4;
#pragma unroll
        for (int r = 0; r < 4; ++r) {
            const int row = rbase + r;
            if (row < M) {
#pragma unroll
                for (int ni = 0; ni < 4; ++ni)
                    C[(size_t)row * N + ccol + ni * 16] = acc[mi][ni][r] + bias[ccol + ni * 16];
            }
        }
    }
}

// ---------------- RoPE 2D: fp32 in-place + bf16 copies for the MFMA attn ----------------
__global__ __launch_bounds__(256) void rope_kernel(float* __restrict__ qkv,
                                                   const float* __restrict__ coords,
                                                   unsigned short* __restrict__ qb,
                                                   unsigned short* __restrict__ kb)
{
    const int idx = blockIdx.x * 256 + threadIdx.x;
    const int l = idx >> 8;
    const int rem = idx & 255;
    const int h = rem >> 5;
    const int i = rem & 31;

    const float cx = coords[l * 2 + 0] * 1e-5f;
    const float cy = coords[l * 2 + 1] * 1e-5f;
    const float basev = (i < 16) ? cx : cy;
    const int fi = (i < 16) ? i : (i - 16);
    const float inv_freq = expf(-((float)fi * (1.0f / 16.0f)) * logf(10000.0f));
    const float f = basev * inv_freq;
    const float cs = cosf(f), sn = sinf(f);

    const size_t base = (size_t)(NUM_CLS + l) * QKV_LD + h * HD + 2 * i;
    float2 q = *(float2*)(qkv + base);
    q = make_float2(q.x * cs - q.y * sn, q.y * cs + q.x * sn);
    *(float2*)(qkv + base) = q;
    float2 k = *(float2*)(qkv + base + EMBED);
    k = make_float2(k.x * cs - k.y * sn, k.y * cs + k.x * sn);
    *(float2*)(qkv + base + EMBED) = k;

    ushort2 qo; qo.x = f2bf(q.x); qo.y = f2bf(q.y);
    *(ushort2*)(qb + (size_t)l * EMBED + h * HD + 2 * i) = qo;
    ushort2 ko; ko.x = f2bf(k.x); ko.y = f2bf(k.y);
    *(ushort2*)(kb + (size_t)(NUM_CLS + l) * EMBED + h * HD + 2 * i) = ko;
}

// cls k rows (tokens 0..3) -> kb bf16 (no rope)
__global__ __launch_bounds__(256) void cast_cls(const float* __restrict__ qkv,
                                                unsigned short* __restrict__ kb)
{
    const int i = blockIdx.x * 256 + threadIdx.x;   // 2048
    const int tok = i >> 9, e = i & 511;
    kb[(size_t)tok * EMBED + e] = f2bf(qkv[(size_t)tok * QKV_LD + EMBED + e]);
}

// ---------------- V transpose: qkv v-section fp32 -> vT bf16 [512][VT_LD] ----------------
__global__ __launch_bounds__(256) void v_transpose(const float* __restrict__ qkv,
                                                   unsigned short* __restrict__ vT)
{
    __shared__ __align__(16) unsigned short tile[32][36];
    const int tb = blockIdx.x * 32;      // token base (grid.x = 257)
    const int db = blockIdx.y * 32;      // dim base  (grid.y = 16)
    const int tid = threadIdx.x;

    {
        const int tok = tb + (tid >> 3);
        const int d4 = (tid & 7) * 4;
        float4 v = make_float4(0.f, 0.f, 0.f, 0.f);
        if (tok < S_TOT) v = *(const float4*)(qkv + (size_t)tok * QKV_LD + 2 * EMBED + db + d4);
        ushort4 o; o.x = f2bf(v.x); o.y = f2bf(v.y); o.z = f2bf(v.z); o.w = f2bf(v.w);
        *(ushort4*)(&tile[tid >> 3][d4]) = o;
    }
    __syncthreads();
    {
        const int dd = tid >> 3;
        const int tq = (tid & 7) * 4;
        if (tb + tq + 3 < VT_LD) {
            ushort4 o;
            o.x = tile[tq + 0][dd]; o.y = tile[tq + 1][dd];
            o.z = tile[tq + 2][dd]; o.w = tile[tq + 3][dd];
            *(ushort4*)(vT + (size_t)(db + dd) * VT_LD + tb + tq) = o;
        }
    }
}

// ---------------- cls attention, flash-decode split-K (fp32) ----------------
#define CCH 512
#define NCHUNK ((S_TOT + CCH - 1) / CCH)   // 17
#define PSTRIDE 68

__global__ __launch_bounds__(256) void cls_attn_partial(const float* __restrict__ qkv,
                                                        float* __restrict__ part)
{
    const int h = blockIdx.x;
    const int c = blockIdx.y;
    const int tid = threadIdx.x;
    const int base = c * CCH;

    __shared__ float qs[4][64];
    __shared__ float sc[4][CCH];
    __shared__ float ored[4][4][64];
    __shared__ float ml[4][2];

    {
        const int qi = tid >> 6, d = tid & 63;
        qs[qi][d] = qkv[(size_t)qi * QKV_LD + h * HD + d];
    }
    __syncthreads();

    for (int jj = tid; jj < CCH; jj += 256) {
        const int j = base + jj;
        float s0 = -INFINITY, s1 = -INFINITY, s2 = -INFINITY, s3 = -INFINITY;
        if (j < S_TOT) {
            const float* kp = qkv + (size_t)j * QKV_LD + EMBED + h * HD;
            float a0 = 0.f, a1 = 0.f, a2 = 0.f, a3 = 0.f;
#pragma unroll
            for (int d4 = 0; d4 < 64; d4 += 4) {
                const float4 kv = *(const float4*)(kp + d4);
                a0 += qs[0][d4] * kv.x + qs[0][d4+1] * kv.y + qs[0][d4+2] * kv.z + qs[0][d4+3] * kv.w;
                a1 += qs[1][d4] * kv.x + qs[1][d4+1] * kv.y + qs[1][d4+2] * kv.z + qs[1][d4+3] * kv.w;
                a2 += qs[2][d4] * kv.x + qs[2][d4+1] * kv.y + qs[2][d4+2] * kv.z + qs[2][d4+3] * kv.w;
                a3 += qs[3][d4] * kv.x + qs[3][d4+1] * kv.y + qs[3][d4+2] * kv.z + qs[3][d4+3] * kv.w;
            }
            s0 = a0 * 0.125f; s1 = a1 * 0.125f; s2 = a2 * 0.125f; s3 = a3 * 0.125f;
        }
        sc[0][jj] = s0; sc[1][jj] = s1; sc[2][jj] = s2; sc[3][jj] = s3;
    }
    __syncthreads();

    const int w = tid >> 6, lane = tid & 63;
    {
        float m = -INFINITY;
#pragma unroll
        for (int j = lane; j < CCH; j += 64) m = fmaxf(m, sc[w][j]);
#pragma unroll
        for (int off = 32; off > 0; off >>= 1) m = fmaxf(m, __shfl_xor(m, off, 64));
        float lsum = 0.f;
#pragma unroll
        for (int j = lane; j < CCH; j += 64) {
            const float e = expf(sc[w][j] - m);
            sc[w][j] = e;
            lsum += e;
        }
#pragma unroll
        for (int off = 32; off > 0; off >>= 1) lsum += __shfl_xor(lsum, off, 64);
        if (lane == 0) { ml[w][0] = m; ml[w][1] = lsum; }
    }
    __syncthreads();

    {
        const int g = w, d = lane;
        float a0 = 0.f, a1 = 0.f, a2 = 0.f, a3 = 0.f;
        for (int jj = g; jj < CCH; jj += 4) {
            const int j = base + jj;
            if (j >= S_TOT) break;
            const float vv = qkv[(size_t)j * QKV_LD + 2 * EMBED + h * HD + d];
            a0 += sc[0][jj] * vv; a1 += sc[1][jj] * vv;
            a2 += sc[2][jj] * vv; a3 += sc[3][jj] * vv;
        }
        ored[g][0][d] = a0; ored[g][1][d] = a1; ored[g][2][d] = a2; ored[g][3][d] = a3;
    }
    __syncthreads();

    {
        const int qi = tid >> 6, d = tid & 63;
        const float o = ored[0][qi][d] + ored[1][qi][d] + ored[2][qi][d] + ored[3][qi][d];
        float* pb = part + ((size_t)(h * NCHUNK + c) * 4 + qi) * PSTRIDE;
        pb[d] = o;
        if (d == 0) { pb[64] = ml[qi][0]; pb[65] = ml[qi][1]; }
    }
}

__global__ __launch_bounds__(256) void cls_attn_combine(const float* __restrict__ part,
                                                        unsigned short* __restrict__ attn)
{
    const int h = blockIdx.x;
    const int qi = threadIdx.x >> 6, d = threadIdx.x & 63;
    float M = -INFINITY;
    for (int c = 0; c < NCHUNK; ++c)
        M = fmaxf(M, part[((size_t)(h * NCHUNK + c) * 4 + qi) * PSTRIDE + 64]);
    float acc = 0.f, L = 0.f;
    for (int c = 0; c < NCHUNK; ++c) {
        const float* pb = part + ((size_t)(h * NCHUNK + c) * 4 + qi) * PSTRIDE;
        const float s = expf(pb[64] - M);
        acc += s * pb[d];
        L   += s * pb[65];
    }
    attn[(size_t)qi * EMBED + h * HD + d] = f2bf(acc / L);
}

// ---------------- patch attention, MFMA (dense 32x112 band) ----------------
// Key columns c: [4,100) window r=c-4 (pos=l0-32+r), [104,108) cls, rest masked.
#define SW 116   // S stride (fp32)
#define PW 136   // P stride (bf16)

__global__ __launch_bounds__(256) void patch_attn_mfma(
    const unsigned short* __restrict__ qb,    // [8192][512] roped q, bf16
    const unsigned short* __restrict__ kb,    // [8196][512] k bf16 (cls rows plain)
    const unsigned short* __restrict__ vT,    // [512][VT_LD] v^T bf16
    unsigned short* __restrict__ attnb)       // [8196][512] bf16
{
    const int l0 = blockIdx.x * 32;
    const int h = blockIdx.y;
    const int tid = threadIdx.x;
    const int lane = tid & 63, w = tid >> 6;

    __shared__ __align__(16) unsigned short Qs[32 * 64];
    __shared__ __align__(16) unsigned short Ks[112 * 64];
    __shared__ __align__(16) unsigned short Vt[64 * 128];
    __shared__ __align__(16) float Sm[32 * SW];   // P (bf16 [32][PW]) aliases this

    // ---- stage Q: 256 16B chunks, XOR-swizzled along k (chunk = 8 bf16) ----
    {
        const int i = tid;
        const int t = i >> 3;
        const int dcl = (i & 7) ^ (t & 7);
        const unsigned short* g = qb + (size_t)(l0 + t) * EMBED + h * HD + dcl * 8;
        __builtin_amdgcn_global_load_lds((const __attribute__((address_space(1))) void*)g,
                                         (__attribute__((address_space(3))) void*)(Qs + i * 8), 16, 0, 0);
    }
    // ---- stage K: 896 chunks ----
    for (int i = tid; i < 896; i += 256) {
        const int c = i >> 3;
        const int dcl = (i & 7) ^ (c & 7);
        int tok = (c >= 104 && c < 108) ? (c - 104) : (l0 - 32 + c);
        tok = tok < 0 ? 0 : (tok > S_TOT - 1 ? S_TOT - 1 : tok);
        const unsigned short* g = kb + (size_t)tok * EMBED + h * HD + dcl * 8;
        __builtin_amdgcn_global_load_lds((const __attribute__((address_space(1))) void*)g,
                                         (__attribute__((address_space(3))) void*)(Ks + i * 8), 16, 0, 0);
    }
    // ---- stage V^T: 1024 chunks (row=d, cols=keys; chunk = 8 consecutive tokens) ----
    for (int i = tid; i < 1024; i += 256) {
        const int d = i >> 4;
        const int kcl = (i & 15) ^ (d & 15);
        const int c0 = kcl * 8;
        int tokb = (c0 == 104) ? 0 : (l0 - 32 + c0);
        tokb = tokb < 0 ? 0 : (tokb > 8192 ? 8192 : tokb);
        const unsigned short* g = vT + (size_t)(h * HD + d) * VT_LD + tokb;
        __builtin_amdgcn_global_load_lds((const __attribute__((address_space(1))) void*)g,
                                         (__attribute__((address_space(3))) void*)(Vt + i * 8), 16, 0, 0);
    }
    __syncthreads();

    // ---- QK^T: 14 C-tiles (2 Mtiles x 7 Ntiles), wave w takes idx = w, w+4, ... ----
    bf16x8 qf[2][2];
#pragma unroll
    for (int mt = 0; mt < 2; ++mt)
#pragma unroll
        for (int ks = 0; ks < 2; ++ks) {
            const int row = mt * 16 + (lane & 15);
            const int dc = (ks * 4 + (lane >> 4)) ^ (row & 7);
            qf[mt][ks] = *(const bf16x8*)(Qs + row * 64 + dc * 8);
        }
    for (int idx = w; idx < 14; idx += 4) {
        const int mt = idx & 1, nt = idx >> 1;
        f32x4 acc = (f32x4)0.f;
#pragma unroll
        for (int ks = 0; ks < 2; ++ks) {
            const int kr = nt * 16 + (lane & 15);
            const int dc = (ks * 4 + (lane >> 4)) ^ (kr & 7);
            const bf16x8 kf = *(const bf16x8*)(Ks + kr * 64 + dc * 8);
            acc = __builtin_amdgcn_mfma_f32_16x16x32_bf16(qf[mt][ks], kf, acc, 0, 0, 0);
        }
        const int col = nt * 16 + (lane & 15);
        const int r0 = mt * 16 + (lane >> 4) * 4;
#pragma unroll
        for (int r = 0; r < 4; ++r) Sm[(r0 + r) * SW + col] = acc[r];
    }
    __syncthreads();

    // ---- masked softmax: 8 lanes per token, 14 cols each (kept in regs) ----
    {
        const int t = tid >> 3, lq = tid & 7;
        float e[14];
        float m = -INFINITY;
#pragma unroll
        for (int j = 0; j < 14; ++j) {
            const int c = lq + 8 * j;
            bool valid;
            if (c >= 104) valid = (c < 108);
            else {
                const int r = c - 4;
                const int pos = l0 - 32 + r;
                valid = (c >= 4) && (c < 100) && (r >= t) && (r <= t + 64) &&
                        (pos >= 0) && (pos < PATCH_LEN);
            }
            e[j] = valid ? Sm[t * SW + c] * 0.125f : -INFINITY;
            m = fmaxf(m, e[j]);
        }
#pragma unroll
        for (int off = 1; off < 8; off <<= 1) m = fmaxf(m, __shfl_xor(m, off, 64));
        float sum = 0.f;
#pragma unroll
        for (int j = 0; j < 14; ++j) { e[j] = expf(e[j] - m); sum += e[j]; }
#pragma unroll
        for (int off = 1; off < 8; off <<= 1) sum += __shfl_xor(sum, off, 64);
        const float inv = 1.f / sum;
        __syncthreads();   // all Sm reads done before P overwrites the region
        unsigned short* P = (unsigned short*)Sm;
#pragma unroll
        for (int j = 0; j < 14; ++j) P[t * PW + lq + 8 * j] = f2bf(e[j] * inv);
        // zero pad cols 112..127 (PV contracts over K=128)
        ushort2 z; z.x = 0; z.y = 0;
        *(ushort2*)(P + (tid >> 3) * PW + 112 + (tid & 7) * 2) = z;
    }
    __syncthreads();

    // ---- PV: 8 C-tiles (2 Mtiles x 4 Ntiles); wave w: M=w&1, N={w>>1, (w>>1)+2} ----
    {
        const unsigned short* P = (const unsigned short*)Sm;
        const int mt = w & 1;
        bf16x8 pf[4];
#pragma unroll
        for (int ks = 0; ks < 4; ++ks) {
            const int row = mt * 16 + (lane & 15);
            pf[ks] = *(const bf16x8*)(P + row * PW + ks * 32 + (lane >> 4) * 8);
        }
#pragma unroll
        for (int nn = 0; nn < 2; ++nn) {
            const int nt = (w >> 1) + nn * 2;
            f32x4 acc = (f32x4)0.f;
#pragma unroll
            for (int ks = 0; ks < 4; ++ks) {
                const int d = nt * 16 + (lane & 15);
                const int kc = (ks * 4 + (lane >> 4)) ^ (d & 15);
                const bf16x8 vf = *(const bf16x8*)(Vt + d * 128 + kc * 8);
                acc = __builtin_amdgcn_mfma_f32_16x16x32_bf16(pf[ks], vf, acc, 0, 0, 0);
            }
            const int dcol = nt * 16 + (lane & 15);
            const int r0 = mt * 16 + (lane >> 4) * 4;
#pragma unroll
            for (int r = 0; r < 4; ++r)
                attnb[(size_t)(NUM_CLS + l0 + r0 + r) * EMBED + h * HD + dcol] = f2bf(acc[r]);
        }
    }
}

extern "C" void kernel_launch(void* const* d_in, const int* in_sizes, int n_in,
                              void* d_out, int out_size, void* d_ws, size_t ws_size,
                              hipStream_t stream)
{
    const float* x      = (const float*)d_in[0];
    const float* coords = (const float*)d_in[1];
    const float* w_qkv  = (const float*)d_in[2];
    const float* b_qkv  = (const float*)d_in[3];
    const float* w_out  = (const float*)d_in[4];
    const float* b_out  = (const float*)d_in[5];
    float* out = (float*)d_out;

    // ---- ws layout (59.4 MB) ----
    const size_t QKV_BYTES = (size_t)S_TOT * QKV_LD * 4;            // 50,356,224
    float* qkv = (float*)d_ws;
    unsigned short* wob = (unsigned short*)((char*)d_ws + QKV_BYTES);             // 524,288
    unsigned short* vT  = (unsigned short*)((char*)wob + (size_t)EMBED * EMBED * 2); // 8,396,800
    float* part = (float*)((char*)vT + (size_t)EMBED * VT_LD * 2);                // 147,968
    // attnb aliases the qkv tail (qkv dead once cls_partial completes)
    unsigned short* attnb = (unsigned short*)((char*)d_ws + QKV_BYTES - (size_t)S_TOT * EMBED * 2);

    // ---- d_out scratch ----
    // phase 1 (pre-gemm1): xb | wqb ; phase 2 (post-gemm1, overwrites them): qb | kb
    unsigned short* xb  = (unsigned short*)d_out;
    unsigned short* wqb = xb + (size_t)S_TOT * EMBED;
    unsigned short* qb  = (unsigned short*)d_out;
    unsigned short* kb  = qb + (size_t)PATCH_LEN * EMBED;

    cast_bf16<<<(S_TOT * EMBED / 4 + 255) / 256, 256, 0, stream>>>(x, xb, S_TOT * EMBED);
    cast_bf16<<<(3 * EMBED * EMBED / 4 + 255) / 256, 256, 0, stream>>>(w_qkv, wqb, 3 * EMBED * EMBED);
    cast_bf16<<<(EMBED * EMBED / 4 + 255) / 256, 256, 0, stream>>>(w_out, wob, EMBED * EMBED);

    // 1) qkv = x @ w_qkv^T + b_qkv
    gemm_bf16_nt<<<dim3((S_TOT + 127) / 128, (3 * EMBED) / 128), 256, 0, stream>>>(
        xb, wqb, b_qkv, qkv, S_TOT, 3 * EMBED, EMBED);

    // 2) RoPE (fp32 in place + bf16 qb/kb), v transpose, cls-k cast
    rope_kernel<<<(PATCH_LEN * NHEAD * 32) / 256, 256, 0, stream>>>(qkv, coords, qb, kb);
    v_transpose<<<dim3((S_TOT + 31) / 32, EMBED / 32), 256, 0, stream>>>(qkv, vT);
    cast_cls<<<8, 256, 0, stream>>>(qkv, kb);

    // 3) cls attention (fp32 split-K); qkv dead after cls_attn_partial
    cls_attn_partial<<<dim3(NHEAD, NCHUNK), 256, 0, stream>>>(qkv, part);
    cls_attn_combine<<<NHEAD, 256, 0, stream>>>(part, attnb);

    // 4) patch attention via MFMA
    patch_attn_mfma<<<dim3(PATCH_LEN / 32, NHEAD), 256, 0, stream>>>(qb, kb, vT, attnb);

    // 5) out = attn @ w_out^T + b_out
    gemm_bf16_nt<<<dim3((S_TOT + 127) / 128, EMBED / 128), 256, 0, stream>>>(
        attnb, wob, b_out, out, S_TOT, EMBED, EMBED);
}

// Round 6
// 204.882 us; speedup vs baseline: 5.0592x; 1.1361x over previous
//
#include <hip/hip_runtime.h>
#include <math.h>

#define EMBED 512
#define NHEAD 8
#define HD 64
#define NUM_CLS 4
#define WIN 32
#define WLEN 65          // 2*WIN+1
#define PATCH_LEN 8192
#define S_TOT 8196       // NUM_CLS + PATCH_LEN
#define QKV_LD 1536
#define VT_LD 8200       // padded, multiple of 8 -> 16B-aligned rows

typedef short bf16x8 __attribute__((ext_vector_type(8)));
typedef float f32x4 __attribute__((ext_vector_type(4)));

__device__ __forceinline__ unsigned short f2bf(float f) {
    unsigned u = __float_as_uint(f);
    return (unsigned short)((u + 0x7fffu + ((u >> 16) & 1u)) >> 16);
}
__device__ __forceinline__ float bf2f(unsigned short v) {
    return __uint_as_float((unsigned)v << 16);
}

// ---------------- fp32 -> bf16 cast (n % 4 == 0) ----------------
__global__ __launch_bounds__(256) void cast_bf16(const float* __restrict__ src,
                                                 unsigned short* __restrict__ dst, int n)
{
    const int i = (blockIdx.x * 256 + threadIdx.x) * 4;
    if (i < n) {
        const float4 v = *(const float4*)(src + i);
        ushort4 o;
        o.x = f2bf(v.x); o.y = f2bf(v.y); o.z = f2bf(v.z); o.w = f2bf(v.w);
        *(ushort4*)(dst + i) = o;
    }
}

// ---------------- bf16 MFMA GEMM: C = A * B^T + bias ----------------
// OutT = float (fp32 out) or unsigned short (bf16 out).
template <typename OutT>
__global__ __launch_bounds__(256) void gemm_bf16_nt(const unsigned short* __restrict__ A,
                                                    const unsigned short* __restrict__ B,
                                                    const float* __restrict__ bias,
                                                    OutT* __restrict__ C,
                                                    int M, int N, int K)
{
    __shared__ __align__(16) unsigned short As[128 * 32];
    __shared__ __align__(16) unsigned short Bs[128 * 32];
    const int tid = threadIdx.x;
    const int lane = tid & 63, w = tid >> 6;
    const int bm = blockIdx.x, bn = blockIdx.y;

    const int ar0 = tid >> 2;
    const int col8 = (tid & 3) * 8;
    int gm0 = bm * 128 + ar0;       if (gm0 >= M) gm0 = M - 1;
    int gm1 = bm * 128 + ar0 + 64;  if (gm1 >= M) gm1 = M - 1;
    const int gn0 = bn * 128 + ar0;
    const int gn1 = bn * 128 + ar0 + 64;
    const unsigned short* pa0 = A + (size_t)gm0 * K + col8;
    const unsigned short* pa1 = A + (size_t)gm1 * K + col8;
    const unsigned short* pb0 = B + (size_t)gn0 * K + col8;
    const unsigned short* pb1 = B + (size_t)gn1 * K + col8;
    unsigned short* la0 = As + tid * 8;
    unsigned short* la1 = As + (tid + 256) * 8;
    unsigned short* lb0 = Bs + tid * 8;
    unsigned short* lb1 = Bs + (tid + 256) * 8;

    const int wr = (w & 1) * 64;
    const int wc = (w >> 1) * 64;
    const int fr = lane & 15;
    const int fk = (lane >> 4) * 8;

    f32x4 acc[4][4];
#pragma unroll
    for (int mi = 0; mi < 4; ++mi)
#pragma unroll
        for (int ni = 0; ni < 4; ++ni) acc[mi][ni] = (f32x4)0.f;

    for (int k0 = 0; k0 < K; k0 += 32) {
        __builtin_amdgcn_global_load_lds((const __attribute__((address_space(1))) void*)(pa0 + k0),
                                         (__attribute__((address_space(3))) void*)la0, 16, 0, 0);
        __builtin_amdgcn_global_load_lds((const __attribute__((address_space(1))) void*)(pa1 + k0),
                                         (__attribute__((address_space(3))) void*)la1, 16, 0, 0);
        __builtin_amdgcn_global_load_lds((const __attribute__((address_space(1))) void*)(pb0 + k0),
                                         (__attribute__((address_space(3))) void*)lb0, 16, 0, 0);
        __builtin_amdgcn_global_load_lds((const __attribute__((address_space(1))) void*)(pb1 + k0),
                                         (__attribute__((address_space(3))) void*)lb1, 16, 0, 0);
        __syncthreads();

        bf16x8 af[4], bf[4];
#pragma unroll
        for (int mi = 0; mi < 4; ++mi)
            af[mi] = *(const bf16x8*)(As + (wr + mi * 16 + fr) * 32 + fk);
#pragma unroll
        for (int ni = 0; ni < 4; ++ni)
            bf[ni] = *(const bf16x8*)(Bs + (wc + ni * 16 + fr) * 32 + fk);
#pragma unroll
        for (int mi = 0; mi < 4; ++mi)
#pragma unroll
            for (int ni = 0; ni < 4; ++ni)
                acc[mi][ni] = __builtin_amdgcn_mfma_f32_16x16x32_bf16(af[mi], bf[ni], acc[mi][ni], 0, 0, 0);
        __syncthreads();
    }

    const int ccol = bn * 128 + wc + fr;
#pragma unroll
    for (int mi = 0; mi < 4; ++mi) {
        const int rbase = bm * 128 + wr + mi * 16 + (lane >> 4) * 4;
#pragma unroll
        for (int r = 0; r < 4; ++r) {
            const int row = rbase + r;
            if (row < M) {
#pragma unroll
                for (int ni = 0; ni < 4; ++ni) {
                    const float v = acc[mi][ni][r] + bias[ccol + ni * 16];
                    if constexpr (sizeof(OutT) == 4)
                        C[(size_t)row * N + ccol + ni * 16] = v;
                    else
                        C[(size_t)row * N + ccol + ni * 16] = (OutT)f2bf(v);
                }
            }
        }
    }
}

// ---------------- RoPE 2D, in-place on bf16 qkv (q & k of patch rows) ----------------
__global__ __launch_bounds__(256) void rope_bf(unsigned short* __restrict__ qkv,
                                               const float* __restrict__ coords)
{
    const int idx = blockIdx.x * 256 + threadIdx.x;   // PATCH_LEN * NHEAD * 32
    const int l = idx >> 8;
    const int rem = idx & 255;
    const int h = rem >> 5;
    const int i = rem & 31;

    const float cx = coords[l * 2 + 0] * 1e-5f;
    const float cy = coords[l * 2 + 1] * 1e-5f;
    const float basev = (i < 16) ? cx : cy;
    const int fi = (i < 16) ? i : (i - 16);
    const float inv_freq = expf(-((float)fi * (1.0f / 16.0f)) * logf(10000.0f));
    const float f = basev * inv_freq;
    const float cs = cosf(f), sn = sinf(f);

    const size_t base = (size_t)(NUM_CLS + l) * QKV_LD + h * HD + 2 * i;
    ushort2 q2 = *(ushort2*)(qkv + base);
    const float qx = bf2f(q2.x), qy = bf2f(q2.y);
    q2.x = f2bf(qx * cs - qy * sn); q2.y = f2bf(qy * cs + qx * sn);
    *(ushort2*)(qkv + base) = q2;

    ushort2 k2 = *(ushort2*)(qkv + base + EMBED);
    const float kx = bf2f(k2.x), ky = bf2f(k2.y);
    k2.x = f2bf(kx * cs - ky * sn); k2.y = f2bf(ky * cs + kx * sn);
    *(ushort2*)(qkv + base + EMBED) = k2;
}

// ---------------- V transpose: bf16 qkv v-section -> vT bf16 [512][VT_LD] ----------------
__global__ __launch_bounds__(256) void v_transpose(const unsigned short* __restrict__ qkv,
                                                   unsigned short* __restrict__ vT)
{
    __shared__ __align__(16) unsigned short tile[32][36];
    const int tb = blockIdx.x * 32;      // token base (grid.x = 257)
    const int db = blockIdx.y * 32;      // dim base  (grid.y = 16)
    const int tid = threadIdx.x;

    {
        const int tok = tb + (tid >> 3);
        const int d4 = (tid & 7) * 4;
        ushort4 v = make_ushort4(0, 0, 0, 0);
        if (tok < S_TOT) v = *(const ushort4*)(qkv + (size_t)tok * QKV_LD + 2 * EMBED + db + d4);
        *(ushort4*)(&tile[tid >> 3][d4]) = v;
    }
    __syncthreads();
    {
        const int dd = tid >> 3;
        const int tq = (tid & 7) * 4;
        if (tb + tq + 3 < VT_LD) {
            ushort4 o;
            o.x = tile[tq + 0][dd]; o.y = tile[tq + 1][dd];
            o.z = tile[tq + 2][dd]; o.w = tile[tq + 3][dd];
            *(ushort4*)(vT + (size_t)(db + dd) * VT_LD + tb + tq) = o;
        }
    }
}

// ---------------- cls attention, flash-decode split-K (bf16 K/V) ----------------
#define CCH 128
#define NCHUNK ((S_TOT + CCH - 1) / CCH)   // 65
#define PSTRIDE 68

__global__ __launch_bounds__(256) void cls_attn_partial(const unsigned short* __restrict__ qkv,
                                                        float* __restrict__ part)
{
    const int h = blockIdx.x;
    const int c = blockIdx.y;
    const int tid = threadIdx.x;
    const int base = c * CCH;

    __shared__ float qs[4][64];
    __shared__ float sc[4][CCH];
    __shared__ float ored[4][4][64];
    __shared__ float ml[4][2];

    {
        const int qi = tid >> 6, d = tid & 63;
        qs[qi][d] = bf2f(qkv[(size_t)qi * QKV_LD + h * HD + d]);
    }
    __syncthreads();

    // scores: thread -> (key = tid&127, query-pair = tid>>7)
    {
        const int jj = tid & 127;
        const int qp = (tid >> 7) * 2;
        const int j = base + jj;
        float s0 = -INFINITY, s1 = -INFINITY;
        if (j < S_TOT) {
            const unsigned short* kp = qkv + (size_t)j * QKV_LD + EMBED + h * HD;
            float a0 = 0.f, a1 = 0.f;
#pragma unroll
            for (int d8 = 0; d8 < 64; d8 += 8) {
                const bf16x8 kv8 = *(const bf16x8*)(kp + d8);
#pragma unroll
                for (int u = 0; u < 8; ++u) {
                    const float kf = bf2f((unsigned short)kv8[u]);
                    a0 += qs[qp + 0][d8 + u] * kf;
                    a1 += qs[qp + 1][d8 + u] * kf;
                }
            }
            s0 = a0 * 0.125f; s1 = a1 * 0.125f;
        }
        sc[qp + 0][jj] = s0;
        sc[qp + 1][jj] = s1;
    }
    __syncthreads();

    // local softmax: wave w owns query w (2 elements/lane)
    const int w = tid >> 6, lane = tid & 63;
    {
        float m = fmaxf(sc[w][lane], sc[w][lane + 64]);
#pragma unroll
        for (int off = 32; off > 0; off >>= 1) m = fmaxf(m, __shfl_xor(m, off, 64));
        const float e0 = expf(sc[w][lane] - m);
        const float e1 = expf(sc[w][lane + 64] - m);
        sc[w][lane] = e0; sc[w][lane + 64] = e1;
        float lsum = e0 + e1;
#pragma unroll
        for (int off = 32; off > 0; off >>= 1) lsum += __shfl_xor(lsum, off, 64);
        if (lane == 0) { ml[w][0] = m; ml[w][1] = lsum; }
    }
    __syncthreads();

    // PV: group g covers keys g, g+4, ... (lane = dim, bf16 V)
    {
        const int g = w, d = lane;
        float a0 = 0.f, a1 = 0.f, a2 = 0.f, a3 = 0.f;
        for (int jj = g; jj < CCH; jj += 4) {
            const int j = base + jj;
            if (j >= S_TOT) break;
            const float vv = bf2f(qkv[(size_t)j * QKV_LD + 2 * EMBED + h * HD + d]);
            a0 += sc[0][jj] * vv; a1 += sc[1][jj] * vv;
            a2 += sc[2][jj] * vv; a3 += sc[3][jj] * vv;
        }
        ored[g][0][d] = a0; ored[g][1][d] = a1; ored[g][2][d] = a2; ored[g][3][d] = a3;
    }
    __syncthreads();

    {
        const int qi = tid >> 6, d = tid & 63;
        const float o = ored[0][qi][d] + ored[1][qi][d] + ored[2][qi][d] + ored[3][qi][d];
        float* pb = part + ((size_t)(h * NCHUNK + c) * 4 + qi) * PSTRIDE;
        pb[d] = o;
        if (d == 0) { pb[64] = ml[qi][0]; pb[65] = ml[qi][1]; }
    }
}

__global__ __launch_bounds__(256) void cls_attn_combine(const float* __restrict__ part,
                                                        unsigned short* __restrict__ attn)
{
    const int h = blockIdx.x;
    const int qi = threadIdx.x >> 6, d = threadIdx.x & 63;
    float M = -INFINITY;
    for (int c = 0; c < NCHUNK; ++c)
        M = fmaxf(M, part[((size_t)(h * NCHUNK + c) * 4 + qi) * PSTRIDE + 64]);
    float acc = 0.f, L = 0.f;
    for (int c = 0; c < NCHUNK; ++c) {
        const float* pb = part + ((size_t)(h * NCHUNK + c) * 4 + qi) * PSTRIDE;
        const float s = expf(pb[64] - M);
        acc += s * pb[d];
        L   += s * pb[65];
    }
    attn[(size_t)qi * EMBED + h * HD + d] = f2bf(acc / L);
}

// ---------------- patch attention, MFMA (dense 32x112 band) ----------------
// Ks row c holds: c in [104,108) -> cls token c-104; else patch pos l0-36+c
// (i.e. qkv row l0-32+c). Valid window cols c in [4,100).
#define SW 116   // S stride (fp32)
#define PW 136   // P stride (bf16)

__global__ __launch_bounds__(256) void patch_attn_mfma(
    const unsigned short* __restrict__ qkv,   // [8196][1536] bf16, rope applied
    const unsigned short* __restrict__ vT,    // [512][VT_LD] v^T bf16
    unsigned short* __restrict__ attnb)       // [8196][512] bf16
{
    const int l0 = blockIdx.x * 32;
    const int h = blockIdx.y;
    const int tid = threadIdx.x;
    const int lane = tid & 63, w = tid >> 6;

    __shared__ __align__(16) unsigned short Qs[32 * 64];
    __shared__ __align__(16) unsigned short Ks[112 * 64];
    __shared__ __align__(16) unsigned short Vt[64 * 128];
    __shared__ __align__(16) float Sm[32 * SW];   // P (bf16 [32][PW]) aliases this

    // ---- stage Q from qkv rows NUM_CLS+l0+t (q section) ----
    {
        const int i = tid;
        const int t = i >> 3;
        const int dcl = (i & 7) ^ (t & 7);
        const unsigned short* g = qkv + (size_t)(NUM_CLS + l0 + t) * QKV_LD + h * HD + dcl * 8;
        __builtin_amdgcn_global_load_lds((const __attribute__((address_space(1))) void*)g,
                                         (__attribute__((address_space(3))) void*)(Qs + i * 8), 16, 0, 0);
    }
    // ---- stage K from qkv (k section) ----
    for (int i = tid; i < 896; i += 256) {
        const int c = i >> 3;
        const int dcl = (i & 7) ^ (c & 7);
        int tok = (c >= 104 && c < 108) ? (c - 104) : (l0 - 32 + c);
        tok = tok < 0 ? 0 : (tok > S_TOT - 1 ? S_TOT - 1 : tok);
        const unsigned short* g = qkv + (size_t)tok * QKV_LD + EMBED + h * HD + dcl * 8;
        __builtin_amdgcn_global_load_lds((const __attribute__((address_space(1))) void*)g,
                                         (__attribute__((address_space(3))) void*)(Ks + i * 8), 16, 0, 0);
    }
    // ---- stage V^T (row=d, cols=keys; chunk = 8 consecutive tokens) ----
    for (int i = tid; i < 1024; i += 256) {
        const int d = i >> 4;
        const int kcl = (i & 15) ^ (d & 15);
        const int c0 = kcl * 8;
        int tokb = (c0 == 104) ? 0 : (l0 - 32 + c0);
        tokb = tokb < 0 ? 0 : (tokb > 8192 ? 8192 : tokb);
        const unsigned short* g = vT + (size_t)(h * HD + d) * VT_LD + tokb;
        __builtin_amdgcn_global_load_lds((const __attribute__((address_space(1))) void*)g,
                                         (__attribute__((address_space(3))) void*)(Vt + i * 8), 16, 0, 0);
    }
    __syncthreads();

    // ---- QK^T: 14 C-tiles (2 Mtiles x 7 Ntiles) ----
    bf16x8 qf[2][2];
#pragma unroll
    for (int mt = 0; mt < 2; ++mt)
#pragma unroll
        for (int ks = 0; ks < 2; ++ks) {
            const int row = mt * 16 + (lane & 15);
            const int dc = (ks * 4 + (lane >> 4)) ^ (row & 7);
            qf[mt][ks] = *(const bf16x8*)(Qs + row * 64 + dc * 8);
        }
    for (int idx = w; idx < 14; idx += 4) {
        const int mt = idx & 1, nt = idx >> 1;
        f32x4 acc = (f32x4)0.f;
#pragma unroll
        for (int ks = 0; ks < 2; ++ks) {
            const int kr = nt * 16 + (lane & 15);
            const int dc = (ks * 4 + (lane >> 4)) ^ (kr & 7);
            const bf16x8 kf = *(const bf16x8*)(Ks + kr * 64 + dc * 8);
            acc = __builtin_amdgcn_mfma_f32_16x16x32_bf16(qf[mt][ks], kf, acc, 0, 0, 0);
        }
        const int col = nt * 16 + (lane & 15);
        const int r0 = mt * 16 + (lane >> 4) * 4;
#pragma unroll
        for (int r = 0; r < 4; ++r) Sm[(r0 + r) * SW + col] = acc[r];
    }
    __syncthreads();

    // ---- masked softmax: 8 lanes per token, 14 cols each ----
    {
        const int t = tid >> 3, lq = tid & 7;
        float e[14];
        float m = -INFINITY;
#pragma unroll
        for (int j = 0; j < 14; ++j) {
            const int c = lq + 8 * j;
            bool valid;
            if (c >= 104) valid = (c < 108);
            else {
                const int r = c - 4;
                const int pos = l0 - 32 + r;
                valid = (c >= 4) && (c < 100) && (r >= t) && (r <= t + 64) &&
                        (pos >= 0) && (pos < PATCH_LEN);
            }
            e[j] = valid ? Sm[t * SW + c] * 0.125f : -INFINITY;
            m = fmaxf(m, e[j]);
        }
#pragma unroll
        for (int off = 1; off < 8; off <<= 1) m = fmaxf(m, __shfl_xor(m, off, 64));
        float sum = 0.f;
#pragma unroll
        for (int j = 0; j < 14; ++j) { e[j] = expf(e[j] - m); sum += e[j]; }
#pragma unroll
        for (int off = 1; off < 8; off <<= 1) sum += __shfl_xor(sum, off, 64);
        const float inv = 1.f / sum;
        __syncthreads();   // all Sm reads done before P overwrites the region
        unsigned short* P = (unsigned short*)Sm;
#pragma unroll
        for (int j = 0; j < 14; ++j) P[t * PW + lq + 8 * j] = f2bf(e[j] * inv);
        ushort2 z; z.x = 0; z.y = 0;
        *(ushort2*)(P + (tid >> 3) * PW + 112 + (tid & 7) * 2) = z;
    }
    __syncthreads();

    // ---- PV: 8 C-tiles ----
    {
        const unsigned short* P = (const unsigned short*)Sm;
        const int mt = w & 1;
        bf16x8 pf[4];
#pragma unroll
        for (int ks = 0; ks < 4; ++ks) {
            const int row = mt * 16 + (lane & 15);
            pf[ks] = *(const bf16x8*)(P + row * PW + ks * 32 + (lane >> 4) * 8);
        }
#pragma unroll
        for (int nn = 0; nn < 2; ++nn) {
            const int nt = (w >> 1) + nn * 2;
            f32x4 acc = (f32x4)0.f;
#pragma unroll
            for (int ks = 0; ks < 4; ++ks) {
                const int d = nt * 16 + (lane & 15);
                const int kc = (ks * 4 + (lane >> 4)) ^ (d & 15);
                const bf16x8 vf = *(const bf16x8*)(Vt + d * 128 + kc * 8);
                acc = __builtin_amdgcn_mfma_f32_16x16x32_bf16(pf[ks], vf, acc, 0, 0, 0);
            }
            const int dcol = nt * 16 + (lane & 15);
            const int r0 = mt * 16 + (lane >> 4) * 4;
#pragma unroll
            for (int r = 0; r < 4; ++r)
                attnb[(size_t)(NUM_CLS + l0 + r0 + r) * EMBED + h * HD + dcol] = f2bf(acc[r]);
        }
    }
}

extern "C" void kernel_launch(void* const* d_in, const int* in_sizes, int n_in,
                              void* d_out, int out_size, void* d_ws, size_t ws_size,
                              hipStream_t stream)
{
    const float* x      = (const float*)d_in[0];
    const float* coords = (const float*)d_in[1];
    const float* w_qkv  = (const float*)d_in[2];
    const float* b_qkv  = (const float*)d_in[3];
    const float* w_out  = (const float*)d_in[4];
    const float* b_out  = (const float*)d_in[5];
    float* out = (float*)d_out;

    // ---- ws layout: fully disjoint regions, 53.0 MB total (proven ws >= 67.1 MB) ----
    char* p = (char*)d_ws;
    unsigned short* qkv   = (unsigned short*)p;                 p += (size_t)S_TOT * QKV_LD * 2;   // 25,178,112
    unsigned short* vT    = (unsigned short*)p;                 p += (size_t)EMBED * VT_LD * 2;    //  8,396,800
    unsigned short* attnb = (unsigned short*)p;                 p += (size_t)S_TOT * EMBED * 2;    //  8,392,704
    float*          part  = (float*)p;                          p += (size_t)NHEAD * NCHUNK * 4 * PSTRIDE * 4; // 565,760
    unsigned short* wob   = (unsigned short*)p;                 p += (size_t)EMBED * EMBED * 2;    //    524,288
    unsigned short* xb    = (unsigned short*)p;                 p += (size_t)S_TOT * EMBED * 2;    //  8,392,704
    unsigned short* wqb   = (unsigned short*)p;                                                    //  1,572,864

    // d_out is written ONLY by the final GEMM. Output = pure function of d_in.

    cast_bf16<<<(S_TOT * EMBED / 4 + 255) / 256, 256, 0, stream>>>(x, xb, S_TOT * EMBED);
    cast_bf16<<<(3 * EMBED * EMBED / 4 + 255) / 256, 256, 0, stream>>>(w_qkv, wqb, 3 * EMBED * EMBED);
    cast_bf16<<<(EMBED * EMBED / 4 + 255) / 256, 256, 0, stream>>>(w_out, wob, EMBED * EMBED);

    // 1) qkv(bf16) = x @ w_qkv^T + b_qkv
    gemm_bf16_nt<unsigned short><<<dim3((S_TOT + 127) / 128, (3 * EMBED) / 128), 256, 0, stream>>>(
        xb, wqb, b_qkv, qkv, S_TOT, 3 * EMBED, EMBED);

    // 2) RoPE in place (bf16), then V transpose
    rope_bf<<<(PATCH_LEN * NHEAD * 32) / 256, 256, 0, stream>>>(qkv, coords);
    v_transpose<<<dim3((S_TOT + 31) / 32, EMBED / 32), 256, 0, stream>>>(qkv, vT);

    // 3) cls attention (split-K over 65 chunks, 520 blocks)
    cls_attn_partial<<<dim3(NHEAD, NCHUNK), 256, 0, stream>>>(qkv, part);
    cls_attn_combine<<<NHEAD, 256, 0, stream>>>(part, attnb);

    // 4) patch attention via MFMA
    patch_attn_mfma<<<dim3(PATCH_LEN / 32, NHEAD), 256, 0, stream>>>(qkv, vT, attnb);

    // 5) out = attn @ w_out^T + b_out (fp32 out)
    gemm_bf16_nt<float><<<dim3((S_TOT + 127) / 128, EMBED / 128), 256, 0, stream>>>(
        attnb, wob, b_out, out, S_TOT, EMBED, EMBED);
}

// Round 7
// 196.330 us; speedup vs baseline: 5.2796x; 1.0436x over previous
//
#include <hip/hip_runtime.h>
#include <math.h>

#define EMBED 512
#define NHEAD 8
#define HD 64
#define NUM_CLS 4
#define WIN 32
#define WLEN 65          // 2*WIN+1
#define PATCH_LEN 8192
#define S_TOT 8196       // NUM_CLS + PATCH_LEN
#define QKV_LD 1536
#define VT_LD 8200       // padded, multiple of 8 -> 16B-aligned rows

typedef short bf16x8 __attribute__((ext_vector_type(8)));
typedef float f32x4 __attribute__((ext_vector_type(4)));

__device__ __forceinline__ unsigned short f2bf(float f) {
    unsigned u = __float_as_uint(f);
    return (unsigned short)((u + 0x7fffu + ((u >> 16) & 1u)) >> 16);
}
__device__ __forceinline__ float bf2f(unsigned short v) {
    return __uint_as_float((unsigned)v << 16);
}

// ---------------- fused fp32 -> bf16 cast of x | w_qkv | w_out ----------------
__global__ __launch_bounds__(256) void cast_all(const float* __restrict__ x,
                                                const float* __restrict__ wq,
                                                const float* __restrict__ wo,
                                                unsigned short* __restrict__ xb,
                                                unsigned short* __restrict__ wqb,
                                                unsigned short* __restrict__ wob)
{
    const int n1 = S_TOT * EMBED;          // 4,196,352
    const int n2 = 3 * EMBED * EMBED;      //   786,432
    const int n3 = EMBED * EMBED;          //   262,144
    const int i = (blockIdx.x * 256 + threadIdx.x) * 4;
    const float* src;
    unsigned short* dst;
    int j;
    if (i < n1)           { src = x;  dst = xb;  j = i; }
    else if (i < n1 + n2) { src = wq; dst = wqb; j = i - n1; }
    else if (i < n1 + n2 + n3) { src = wo; dst = wob; j = i - n1 - n2; }
    else return;
    const float4 v = *(const float4*)(src + j);
    ushort4 o;
    o.x = f2bf(v.x); o.y = f2bf(v.y); o.z = f2bf(v.z); o.w = f2bf(v.w);
    *(ushort4*)(dst + j) = o;
}

// ---------------- bf16 MFMA GEMM: C = A * B^T + bias ----------------
// MODE 0: plain fp32 output (out-projection).
// MODE 1: fused QKV epilogue — bf16 output into qkv layout, RoPE applied to
//         q/k sections (patch rows), v section dual-written (row-major + vT).
template <int MODE, typename OutT>
__global__ __launch_bounds__(256) void gemm_bf16_nt(const unsigned short* __restrict__ A,
                                                    const unsigned short* __restrict__ B,
                                                    const float* __restrict__ bias,
                                                    OutT* __restrict__ C,
                                                    int M, int N, int K,
                                                    const float* __restrict__ coords,
                                                    unsigned short* __restrict__ vT)
{
    __shared__ __align__(16) unsigned short As[128 * 32];
    __shared__ __align__(16) unsigned short Bs[128 * 32];
    const int tid = threadIdx.x;
    const int lane = tid & 63, w = tid >> 6;
    const int bm = blockIdx.x, bn = blockIdx.y;

    const int ar0 = tid >> 2;
    const int col8 = (tid & 3) * 8;
    int gm0 = bm * 128 + ar0;       if (gm0 >= M) gm0 = M - 1;
    int gm1 = bm * 128 + ar0 + 64;  if (gm1 >= M) gm1 = M - 1;
    const int gn0 = bn * 128 + ar0;
    const int gn1 = bn * 128 + ar0 + 64;
    const unsigned short* pa0 = A + (size_t)gm0 * K + col8;
    const unsigned short* pa1 = A + (size_t)gm1 * K + col8;
    const unsigned short* pb0 = B + (size_t)gn0 * K + col8;
    const unsigned short* pb1 = B + (size_t)gn1 * K + col8;
    unsigned short* la0 = As + tid * 8;
    unsigned short* la1 = As + (tid + 256) * 8;
    unsigned short* lb0 = Bs + tid * 8;
    unsigned short* lb1 = Bs + (tid + 256) * 8;

    const int wr = (w & 1) * 64;
    const int wc = (w >> 1) * 64;
    const int fr = lane & 15;
    const int fk = (lane >> 4) * 8;

    f32x4 acc[4][4];
#pragma unroll
    for (int mi = 0; mi < 4; ++mi)
#pragma unroll
        for (int ni = 0; ni < 4; ++ni) acc[mi][ni] = (f32x4)0.f;

    for (int k0 = 0; k0 < K; k0 += 32) {
        __builtin_amdgcn_global_load_lds((const __attribute__((address_space(1))) void*)(pa0 + k0),
                                         (__attribute__((address_space(3))) void*)la0, 16, 0, 0);
        __builtin_amdgcn_global_load_lds((const __attribute__((address_space(1))) void*)(pa1 + k0),
                                         (__attribute__((address_space(3))) void*)la1, 16, 0, 0);
        __builtin_amdgcn_global_load_lds((const __attribute__((address_space(1))) void*)(pb0 + k0),
                                         (__attribute__((address_space(3))) void*)lb0, 16, 0, 0);
        __builtin_amdgcn_global_load_lds((const __attribute__((address_space(1))) void*)(pb1 + k0),
                                         (__attribute__((address_space(3))) void*)lb1, 16, 0, 0);
        __syncthreads();

        bf16x8 af[4], bf[4];
#pragma unroll
        for (int mi = 0; mi < 4; ++mi)
            af[mi] = *(const bf16x8*)(As + (wr + mi * 16 + fr) * 32 + fk);
#pragma unroll
        for (int ni = 0; ni < 4; ++ni)
            bf[ni] = *(const bf16x8*)(Bs + (wc + ni * 16 + fr) * 32 + fk);
#pragma unroll
        for (int mi = 0; mi < 4; ++mi)
#pragma unroll
            for (int ni = 0; ni < 4; ++ni)
                acc[mi][ni] = __builtin_amdgcn_mfma_f32_16x16x32_bf16(af[mi], bf[ni], acc[mi][ni], 0, 0, 0);
        __syncthreads();
    }

    const int ccol = bn * 128 + wc + fr;

    if constexpr (MODE == 0) {
#pragma unroll
        for (int mi = 0; mi < 4; ++mi) {
            const int rbase = bm * 128 + wr + mi * 16 + (lane >> 4) * 4;
#pragma unroll
            for (int r = 0; r < 4; ++r) {
                const int row = rbase + r;
                if (row < M) {
#pragma unroll
                    for (int ni = 0; ni < 4; ++ni)
                        C[(size_t)row * N + ccol + ni * 16] = acc[mi][ni][r] + bias[ccol + ni * 16];
                }
            }
        }
    } else {
        if (bn < 8) {
            // ---- q/k sections: RoPE on patch rows (pair partner in lane^1) ----
#pragma unroll
            for (int mi = 0; mi < 4; ++mi) {
                const int rbase = bm * 128 + wr + mi * 16 + (lane >> 4) * 4;
#pragma unroll
                for (int r = 0; r < 4; ++r) {
                    const int row = rbase + r;
                    const bool patch = (row >= NUM_CLS) && (row < M);
                    float cx = 0.f, cy = 0.f;
                    if (patch) {
                        const int l = row - NUM_CLS;
                        cx = coords[l * 2 + 0] * 1e-5f;
                        cy = coords[l * 2 + 1] * 1e-5f;
                    }
#pragma unroll
                    for (int ni = 0; ni < 4; ++ni) {
                        const int col = ccol + ni * 16;
                        const float biased = acc[mi][ni][r] + bias[col];
                        const float part = __shfl_xor(biased, 1);   // uniform ctrl flow
                        float outv = biased;
                        if (patch) {
                            const int dh = col & 63;
                            const int pr = dh >> 1;
                            // inv_freq = 10000^(-(pr&15)/16); ln(10000)/16 = 0.57564627
                            const float invf = __expf(-(float)(pr & 15) * 0.5756462732485114f);
                            const float f = ((pr < 16) ? cx : cy) * invf;
                            float sn, cs;
                            __sincosf(f, &sn, &cs);
                            outv = (dh & 1) ? (biased * cs + part * sn)
                                            : (biased * cs - part * sn);
                        }
                        if (row < M) C[(size_t)row * N + col] = (OutT)f2bf(outv);
                    }
                }
            }
        } else {
            // ---- v section: row-major qkv store + transposed vT store ----
#pragma unroll
            for (int mi = 0; mi < 4; ++mi) {
                const int rbase = bm * 128 + wr + mi * 16 + (lane >> 4) * 4;
#pragma unroll
                for (int ni = 0; ni < 4; ++ni) {
                    const int col = ccol + ni * 16;
                    const int dv = col - 1024;
                    unsigned short b[4];
#pragma unroll
                    for (int r = 0; r < 4; ++r)
                        b[r] = f2bf(acc[mi][ni][r] + bias[col]);
#pragma unroll
                    for (int r = 0; r < 4; ++r)
                        if (rbase + r < M) C[(size_t)(rbase + r) * N + col] = (OutT)b[r];
                    if (rbase + 3 < M) {
                        ushort4 o; o.x = b[0]; o.y = b[1]; o.z = b[2]; o.w = b[3];
                        *(ushort4*)(vT + (size_t)dv * VT_LD + rbase) = o;
                    } else {
#pragma unroll
                        for (int r = 0; r < 4; ++r) {
                            const int row = rbase + r;
                            if (row < VT_LD)
                                vT[(size_t)dv * VT_LD + row] = (row < M) ? b[r] : (unsigned short)0;
                        }
                    }
                }
            }
        }
    }
}

// ---------------- cls attention, flash-decode split-K (bf16 K/V) ----------------
#define CCH 128
#define NCHUNK ((S_TOT + CCH - 1) / CCH)   // 65
#define PSTRIDE 68

__global__ __launch_bounds__(256) void cls_attn_partial(const unsigned short* __restrict__ qkv,
                                                        float* __restrict__ part)
{
    const int h = blockIdx.x;
    const int c = blockIdx.y;
    const int tid = threadIdx.x;
    const int base = c * CCH;

    __shared__ float qs[4][64];
    __shared__ float sc[4][CCH];
    __shared__ float ored[4][4][64];
    __shared__ float ml[4][2];

    {
        const int qi = tid >> 6, d = tid & 63;
        qs[qi][d] = bf2f(qkv[(size_t)qi * QKV_LD + h * HD + d]);
    }
    __syncthreads();

    {
        const int jj = tid & 127;
        const int qp = (tid >> 7) * 2;
        const int j = base + jj;
        float s0 = -INFINITY, s1 = -INFINITY;
        if (j < S_TOT) {
            const unsigned short* kp = qkv + (size_t)j * QKV_LD + EMBED + h * HD;
            float a0 = 0.f, a1 = 0.f;
#pragma unroll
            for (int d8 = 0; d8 < 64; d8 += 8) {
                const bf16x8 kv8 = *(const bf16x8*)(kp + d8);
#pragma unroll
                for (int u = 0; u < 8; ++u) {
                    const float kf = bf2f((unsigned short)kv8[u]);
                    a0 += qs[qp + 0][d8 + u] * kf;
                    a1 += qs[qp + 1][d8 + u] * kf;
                }
            }
            s0 = a0 * 0.125f; s1 = a1 * 0.125f;
        }
        sc[qp + 0][jj] = s0;
        sc[qp + 1][jj] = s1;
    }
    __syncthreads();

    const int w = tid >> 6, lane = tid & 63;
    {
        float m = fmaxf(sc[w][lane], sc[w][lane + 64]);
#pragma unroll
        for (int off = 32; off > 0; off >>= 1) m = fmaxf(m, __shfl_xor(m, off, 64));
        const float e0 = expf(sc[w][lane] - m);
        const float e1 = expf(sc[w][lane + 64] - m);
        sc[w][lane] = e0; sc[w][lane + 64] = e1;
        float lsum = e0 + e1;
#pragma unroll
        for (int off = 32; off > 0; off >>= 1) lsum += __shfl_xor(lsum, off, 64);
        if (lane == 0) { ml[w][0] = m; ml[w][1] = lsum; }
    }
    __syncthreads();

    {
        const int g = w, d = lane;
        float a0 = 0.f, a1 = 0.f, a2 = 0.f, a3 = 0.f;
        for (int jj = g; jj < CCH; jj += 4) {
            const int j = base + jj;
            if (j >= S_TOT) break;
            const float vv = bf2f(qkv[(size_t)j * QKV_LD + 2 * EMBED + h * HD + d]);
            a0 += sc[0][jj] * vv; a1 += sc[1][jj] * vv;
            a2 += sc[2][jj] * vv; a3 += sc[3][jj] * vv;
        }
        ored[g][0][d] = a0; ored[g][1][d] = a1; ored[g][2][d] = a2; ored[g][3][d] = a3;
    }
    __syncthreads();

    {
        const int qi = tid >> 6, d = tid & 63;
        const float o = ored[0][qi][d] + ored[1][qi][d] + ored[2][qi][d] + ored[3][qi][d];
        float* pb = part + ((size_t)(h * NCHUNK + c) * 4 + qi) * PSTRIDE;
        pb[d] = o;
        if (d == 0) { pb[64] = ml[qi][0]; pb[65] = ml[qi][1]; }
    }
}

__global__ __launch_bounds__(256) void cls_attn_combine(const float* __restrict__ part,
                                                        unsigned short* __restrict__ attn)
{
    const int h = blockIdx.x;
    const int qi = threadIdx.x >> 6, d = threadIdx.x & 63;
    float M = -INFINITY;
    for (int c = 0; c < NCHUNK; ++c)
        M = fmaxf(M, part[((size_t)(h * NCHUNK + c) * 4 + qi) * PSTRIDE + 64]);
    float acc = 0.f, L = 0.f;
    for (int c = 0; c < NCHUNK; ++c) {
        const float* pb = part + ((size_t)(h * NCHUNK + c) * 4 + qi) * PSTRIDE;
        const float s = expf(pb[64] - M);
        acc += s * pb[d];
        L   += s * pb[65];
    }
    attn[(size_t)qi * EMBED + h * HD + d] = f2bf(acc / L);
}

// ---------------- patch attention, MFMA (dense 32x112 band) ----------------
#define SW 116   // S stride (fp32)
#define PW 136   // P stride (bf16)

__global__ __launch_bounds__(256) void patch_attn_mfma(
    const unsigned short* __restrict__ qkv,   // [8196][1536] bf16, rope applied
    const unsigned short* __restrict__ vT,    // [512][VT_LD] v^T bf16
    unsigned short* __restrict__ attnb)       // [8196][512] bf16
{
    const int l0 = blockIdx.x * 32;
    const int h = blockIdx.y;
    const int tid = threadIdx.x;
    const int lane = tid & 63, w = tid >> 6;

    __shared__ __align__(16) unsigned short Qs[32 * 64];
    __shared__ __align__(16) unsigned short Ks[112 * 64];
    __shared__ __align__(16) unsigned short Vt[64 * 128];
    __shared__ __align__(16) float Sm[32 * SW];   // P (bf16 [32][PW]) aliases this

    {
        const int i = tid;
        const int t = i >> 3;
        const int dcl = (i & 7) ^ (t & 7);
        const unsigned short* g = qkv + (size_t)(NUM_CLS + l0 + t) * QKV_LD + h * HD + dcl * 8;
        __builtin_amdgcn_global_load_lds((const __attribute__((address_space(1))) void*)g,
                                         (__attribute__((address_space(3))) void*)(Qs + i * 8), 16, 0, 0);
    }
    for (int i = tid; i < 896; i += 256) {
        const int c = i >> 3;
        const int dcl = (i & 7) ^ (c & 7);
        int tok = (c >= 104 && c < 108) ? (c - 104) : (l0 - 32 + c);
        tok = tok < 0 ? 0 : (tok > S_TOT - 1 ? S_TOT - 1 : tok);
        const unsigned short* g = qkv + (size_t)tok * QKV_LD + EMBED + h * HD + dcl * 8;
        __builtin_amdgcn_global_load_lds((const __attribute__((address_space(1))) void*)g,
                                         (__attribute__((address_space(3))) void*)(Ks + i * 8), 16, 0, 0);
    }
    for (int i = tid; i < 1024; i += 256) {
        const int d = i >> 4;
        const int kcl = (i & 15) ^ (d & 15);
        const int c0 = kcl * 8;
        int tokb = (c0 == 104) ? 0 : (l0 - 32 + c0);
        tokb = tokb < 0 ? 0 : (tokb > 8192 ? 8192 : tokb);
        const unsigned short* g = vT + (size_t)(h * HD + d) * VT_LD + tokb;
        __builtin_amdgcn_global_load_lds((const __attribute__((address_space(1))) void*)g,
                                         (__attribute__((address_space(3))) void*)(Vt + i * 8), 16, 0, 0);
    }
    __syncthreads();

    bf16x8 qf[2][2];
#pragma unroll
    for (int mt = 0; mt < 2; ++mt)
#pragma unroll
        for (int ks = 0; ks < 2; ++ks) {
            const int row = mt * 16 + (lane & 15);
            const int dc = (ks * 4 + (lane >> 4)) ^ (row & 7);
            qf[mt][ks] = *(const bf16x8*)(Qs + row * 64 + dc * 8);
        }
    for (int idx = w; idx < 14; idx += 4) {
        const int mt = idx & 1, nt = idx >> 1;
        f32x4 acc = (f32x4)0.f;
#pragma unroll
        for (int ks = 0; ks < 2; ++ks) {
            const int kr = nt * 16 + (lane & 15);
            const int dc = (ks * 4 + (lane >> 4)) ^ (kr & 7);
            const bf16x8 kf = *(const bf16x8*)(Ks + kr * 64 + dc * 8);
            acc = __builtin_amdgcn_mfma_f32_16x16x32_bf16(qf[mt][ks], kf, acc, 0, 0, 0);
        }
        const int col = nt * 16 + (lane & 15);
        const int r0 = mt * 16 + (lane >> 4) * 4;
#pragma unroll
        for (int r = 0; r < 4; ++r) Sm[(r0 + r) * SW + col] = acc[r];
    }
    __syncthreads();

    {
        const int t = tid >> 3, lq = tid & 7;
        float e[14];
        float m = -INFINITY;
#pragma unroll
        for (int j = 0; j < 14; ++j) {
            const int c = lq + 8 * j;
            bool valid;
            if (c >= 104) valid = (c < 108);
            else {
                const int r = c - 4;
                const int pos = l0 - 32 + r;
                valid = (c >= 4) && (c < 100) && (r >= t) && (r <= t + 64) &&
                        (pos >= 0) && (pos < PATCH_LEN);
            }
            e[j] = valid ? Sm[t * SW + c] * 0.125f : -INFINITY;
            m = fmaxf(m, e[j]);
        }
#pragma unroll
        for (int off = 1; off < 8; off <<= 1) m = fmaxf(m, __shfl_xor(m, off, 64));
        float sum = 0.f;
#pragma unroll
        for (int j = 0; j < 14; ++j) { e[j] = expf(e[j] - m); sum += e[j]; }
#pragma unroll
        for (int off = 1; off < 8; off <<= 1) sum += __shfl_xor(sum, off, 64);
        const float inv = 1.f / sum;
        __syncthreads();
        unsigned short* P = (unsigned short*)Sm;
#pragma unroll
        for (int j = 0; j < 14; ++j) P[t * PW + lq + 8 * j] = f2bf(e[j] * inv);
        ushort2 z; z.x = 0; z.y = 0;
        *(ushort2*)(P + (tid >> 3) * PW + 112 + (tid & 7) * 2) = z;
    }
    __syncthreads();

    {
        const unsigned short* P = (const unsigned short*)Sm;
        const int mt = w & 1;
        bf16x8 pf[4];
#pragma unroll
        for (int ks = 0; ks < 4; ++ks) {
            const int row = mt * 16 + (lane & 15);
            pf[ks] = *(const bf16x8*)(P + row * PW + ks * 32 + (lane >> 4) * 8);
        }
#pragma unroll
        for (int nn = 0; nn < 2; ++nn) {
            const int nt = (w >> 1) + nn * 2;
            f32x4 acc = (f32x4)0.f;
#pragma unroll
            for (int ks = 0; ks < 4; ++ks) {
                const int d = nt * 16 + (lane & 15);
                const int kc = (ks * 4 + (lane >> 4)) ^ (d & 15);
                const bf16x8 vf = *(const bf16x8*)(Vt + d * 128 + kc * 8);
                acc = __builtin_amdgcn_mfma_f32_16x16x32_bf16(pf[ks], vf, acc, 0, 0, 0);
            }
            const int dcol = nt * 16 + (lane & 15);
            const int r0 = mt * 16 + (lane >> 4) * 4;
#pragma unroll
            for (int r = 0; r < 4; ++r)
                attnb[(size_t)(NUM_CLS + l0 + r0 + r) * EMBED + h * HD + dcol] = f2bf(acc[r]);
        }
    }
}

extern "C" void kernel_launch(void* const* d_in, const int* in_sizes, int n_in,
                              void* d_out, int out_size, void* d_ws, size_t ws_size,
                              hipStream_t stream)
{
    const float* x      = (const float*)d_in[0];
    const float* coords = (const float*)d_in[1];
    const float* w_qkv  = (const float*)d_in[2];
    const float* b_qkv  = (const float*)d_in[3];
    const float* w_out  = (const float*)d_in[4];
    const float* b_out  = (const float*)d_in[5];
    float* out = (float*)d_out;

    // ---- ws layout: fully disjoint regions (~53 MB) ----
    char* p = (char*)d_ws;
    unsigned short* qkv   = (unsigned short*)p;  p += (size_t)S_TOT * QKV_LD * 2;
    unsigned short* vT    = (unsigned short*)p;  p += (size_t)EMBED * VT_LD * 2;
    unsigned short* attnb = (unsigned short*)p;  p += (size_t)S_TOT * EMBED * 2;
    float*          part  = (float*)p;           p += (size_t)NHEAD * NCHUNK * 4 * PSTRIDE * 4;
    unsigned short* wob   = (unsigned short*)p;  p += (size_t)EMBED * EMBED * 2;
    unsigned short* xb    = (unsigned short*)p;  p += (size_t)S_TOT * EMBED * 2;
    unsigned short* wqb   = (unsigned short*)p;

    // d_out is written ONLY by the final GEMM. Output = pure function of d_in.

    // 1) fused casts
    {
        const int total = S_TOT * EMBED + 3 * EMBED * EMBED + EMBED * EMBED;
        cast_all<<<(total / 4 + 255) / 256, 256, 0, stream>>>(x, w_qkv, w_out, xb, wqb, wob);
    }

    // 2) qkv(bf16, rope fused, vT fused) = x @ w_qkv^T + b_qkv
    gemm_bf16_nt<1, unsigned short><<<dim3((S_TOT + 127) / 128, (3 * EMBED) / 128), 256, 0, stream>>>(
        xb, wqb, b_qkv, qkv, S_TOT, 3 * EMBED, EMBED, coords, vT);

    // 3) cls attention (split-K over 65 chunks, 520 blocks)
    cls_attn_partial<<<dim3(NHEAD, NCHUNK), 256, 0, stream>>>(qkv, part);
    cls_attn_combine<<<NHEAD, 256, 0, stream>>>(part, attnb);

    // 4) patch attention via MFMA
    patch_attn_mfma<<<dim3(PATCH_LEN / 32, NHEAD), 256, 0, stream>>>(qkv, vT, attnb);

    // 5) out = attn @ w_out^T + b_out (fp32 out)
    gemm_bf16_nt<0, float><<<dim3((S_TOT + 127) / 128, EMBED / 128), 256, 0, stream>>>(
        attnb, wob, b_out, out, S_TOT, EMBED, EMBED, nullptr, nullptr);
}

// Round 9
// 195.583 us; speedup vs baseline: 5.2997x; 1.0038x over previous
//
#include <hip/hip_runtime.h>
#include <math.h>

#define EMBED 512
#define NHEAD 8
#define HD 64
#define NUM_CLS 4
#define WIN 32
#define WLEN 65          // 2*WIN+1
#define PATCH_LEN 8192
#define S_TOT 8196       // NUM_CLS + PATCH_LEN
#define QKV_LD 1536
#define VT_LD 8200       // padded, multiple of 8 -> 16B-aligned rows

typedef short bf16x8 __attribute__((ext_vector_type(8)));
typedef float f32x4 __attribute__((ext_vector_type(4)));

__device__ __forceinline__ unsigned short f2bf(float f) {
    unsigned u = __float_as_uint(f);
    return (unsigned short)((u + 0x7fffu + ((u >> 16) & 1u)) >> 16);
}
__device__ __forceinline__ float bf2f(unsigned short v) {
    return __uint_as_float((unsigned)v << 16);
}

// ---------------- fused fp32 -> bf16 cast of x | w_qkv | w_out ----------------
__global__ __launch_bounds__(256) void cast_all(const float* __restrict__ x,
                                                const float* __restrict__ wq,
                                                const float* __restrict__ wo,
                                                unsigned short* __restrict__ xb,
                                                unsigned short* __restrict__ wqb,
                                                unsigned short* __restrict__ wob)
{
    const int n1 = S_TOT * EMBED;
    const int n2 = 3 * EMBED * EMBED;
    const int n3 = EMBED * EMBED;
    const int i = (blockIdx.x * 256 + threadIdx.x) * 4;
    const float* src;
    unsigned short* dst;
    int j;
    if (i < n1)           { src = x;  dst = xb;  j = i; }
    else if (i < n1 + n2) { src = wq; dst = wqb; j = i - n1; }
    else if (i < n1 + n2 + n3) { src = wo; dst = wob; j = i - n1 - n2; }
    else return;
    const float4 v = *(const float4*)(src + j);
    ushort4 o;
    o.x = f2bf(v.x); o.y = f2bf(v.y); o.z = f2bf(v.z); o.w = f2bf(v.w);
    *(ushort4*)(dst + j) = o;
}

// ---------------- bf16 MFMA GEMM: C = A * B^T + bias ----------------
// Grid: (bn fastest, bm) so consecutive blocks share the A-stripe (L2 reuse).
// MODE 0: plain fp32 output. MODE 1: fused QKV epilogue (rope via LDS table,
// vT via LDS-transposed coalesced stores).
template <int MODE, typename OutT>
__global__ __launch_bounds__(256) void gemm_bf16_nt(const unsigned short* __restrict__ A,
                                                    const unsigned short* __restrict__ B,
                                                    const float* __restrict__ bias,
                                                    OutT* __restrict__ C,
                                                    int M, int N, int K,
                                                    const float* __restrict__ coords,
                                                    unsigned short* __restrict__ vT)
{
    __shared__ __align__(16) unsigned short As[128 * 32];
    __shared__ __align__(16) unsigned short Bs[128 * 32];
    const int tid = threadIdx.x;
    const int lane = tid & 63, w = tid >> 6;
    const int bn = blockIdx.x, bm = blockIdx.y;   // bn fastest -> A-stripe reuse

    const int ar0 = tid >> 2;
    const int col8 = (tid & 3) * 8;
    int gm0 = bm * 128 + ar0;       if (gm0 >= M) gm0 = M - 1;
    int gm1 = bm * 128 + ar0 + 64;  if (gm1 >= M) gm1 = M - 1;
    const int gn0 = bn * 128 + ar0;
    const int gn1 = bn * 128 + ar0 + 64;
    const unsigned short* pa0 = A + (size_t)gm0 * K + col8;
    const unsigned short* pa1 = A + (size_t)gm1 * K + col8;
    const unsigned short* pb0 = B + (size_t)gn0 * K + col8;
    const unsigned short* pb1 = B + (size_t)gn1 * K + col8;
    unsigned short* la0 = As + tid * 8;
    unsigned short* la1 = As + (tid + 256) * 8;
    unsigned short* lb0 = Bs + tid * 8;
    unsigned short* lb1 = Bs + (tid + 256) * 8;

    const int wr = (w & 1) * 64;
    const int wc = (w >> 1) * 64;
    const int fr = lane & 15;
    const int fk = (lane >> 4) * 8;

    f32x4 acc[4][4];
#pragma unroll
    for (int mi = 0; mi < 4; ++mi)
#pragma unroll
        for (int ni = 0; ni < 4; ++ni) acc[mi][ni] = (f32x4)0.f;

    for (int k0 = 0; k0 < K; k0 += 32) {
        __builtin_amdgcn_global_load_lds((const __attribute__((address_space(1))) void*)(pa0 + k0),
                                         (__attribute__((address_space(3))) void*)la0, 16, 0, 0);
        __builtin_amdgcn_global_load_lds((const __attribute__((address_space(1))) void*)(pa1 + k0),
                                         (__attribute__((address_space(3))) void*)la1, 16, 0, 0);
        __builtin_amdgcn_global_load_lds((const __attribute__((address_space(1))) void*)(pb0 + k0),
                                         (__attribute__((address_space(3))) void*)lb0, 16, 0, 0);
        __builtin_amdgcn_global_load_lds((const __attribute__((address_space(1))) void*)(pb1 + k0),
                                         (__attribute__((address_space(3))) void*)lb1, 16, 0, 0);
        __syncthreads();

        bf16x8 af[4], bf[4];
#pragma unroll
        for (int mi = 0; mi < 4; ++mi)
            af[mi] = *(const bf16x8*)(As + (wr + mi * 16 + fr) * 32 + fk);
#pragma unroll
        for (int ni = 0; ni < 4; ++ni)
            bf[ni] = *(const bf16x8*)(Bs + (wc + ni * 16 + fr) * 32 + fk);
#pragma unroll
        for (int mi = 0; mi < 4; ++mi)
#pragma unroll
            for (int ni = 0; ni < 4; ++ni)
                acc[mi][ni] = __builtin_amdgcn_mfma_f32_16x16x32_bf16(af[mi], bf[ni], acc[mi][ni], 0, 0, 0);
        __syncthreads();
    }

    const int ccol = bn * 128 + wc + fr;

    if constexpr (MODE == 0) {
#pragma unroll
        for (int mi = 0; mi < 4; ++mi) {
            const int rbase = bm * 128 + wr + mi * 16 + (lane >> 4) * 4;
#pragma unroll
            for (int r = 0; r < 4; ++r) {
                const int row = rbase + r;
                if (row < M) {
#pragma unroll
                    for (int ni = 0; ni < 4; ++ni)
                        C[(size_t)row * N + ccol + ni * 16] = acc[mi][ni][r] + bias[ccol + ni * 16];
                }
            }
        }
    } else {
        // union buffer: rope table ushort2[128][32] (16 KB) OR v-transpose [64][136] (17.4 KB)
        __shared__ __align__(16) unsigned short EX[64 * 136];
        if (bn < 8) {
            // ---- build (cs,sn) table: 4096 entries, 16 sincos/thread ----
            ushort2* rt = (ushort2*)EX;
            for (int idx = tid; idx < 4096; idx += 256) {
                const int rr = idx >> 5, pr = idx & 31;
                int l = bm * 128 + rr - NUM_CLS;
                l = l < 0 ? 0 : (l > PATCH_LEN - 1 ? PATCH_LEN - 1 : l);
                const float cxy = coords[l * 2 + (pr >> 4)] * 1e-5f;
                // inv_freq = 10000^(-(pr&15)/16); ln(10000)/16 = 0.5756462732485114
                const float f = cxy * __expf(-(float)(pr & 15) * 0.5756462732485114f);
                float sn, cs;
                __sincosf(f, &sn, &cs);
                ushort2 e; e.x = f2bf(cs); e.y = f2bf(sn);
                rt[idx] = e;
            }
            __syncthreads();
#pragma unroll
            for (int mi = 0; mi < 4; ++mi) {
                const int rloc0 = wr + mi * 16 + (lane >> 4) * 4;
#pragma unroll
                for (int r = 0; r < 4; ++r) {
                    const int rloc = rloc0 + r;
                    const int row = bm * 128 + rloc;
                    const bool patch = (row >= NUM_CLS) && (row < M);
#pragma unroll
                    for (int ni = 0; ni < 4; ++ni) {
                        const int col = ccol + ni * 16;
                        const float biased = acc[mi][ni][r] + bias[col];
                        const float prt = __shfl_xor(biased, 1);   // pair partner (uniform flow)
                        float outv = biased;
                        if (patch) {
                            const ushort2 e = rt[rloc * 32 + ((col & 63) >> 1)];
                            const float cs = bf2f(e.x), sn = bf2f(e.y);
                            outv = (col & 1) ? (biased * cs + prt * sn)
                                             : (biased * cs - prt * sn);
                        }
                        if (row < M) C[(size_t)row * N + col] = (OutT)f2bf(outv);
                    }
                }
            }
        } else {
            const int dbase = (bn - 8) * 128;
            // row-major qkv v store
#pragma unroll
            for (int mi = 0; mi < 4; ++mi) {
                const int rbase = bm * 128 + wr + mi * 16 + (lane >> 4) * 4;
#pragma unroll
                for (int ni = 0; ni < 4; ++ni) {
                    const int col = ccol + ni * 16;
#pragma unroll
                    for (int r = 0; r < 4; ++r) {
                        const int row = rbase + r;
                        if (row < M)
                            C[(size_t)row * N + col] = (OutT)f2bf(acc[mi][ni][r] + bias[col]);
                    }
                }
            }
            // transposed vT store via LDS, 2 passes of 64 dims -> coalesced 256B rows
            for (int p = 0; p < 2; ++p) {
                __syncthreads();
                if ((w >> 1) == p) {   // waves whose wc == p*64 own these dims
#pragma unroll
                    for (int mi = 0; mi < 4; ++mi) {
                        const int tok0 = wr + mi * 16 + (lane >> 4) * 4;   // local token 0..127
                        const int rw = bm * 128 + tok0;
#pragma unroll
                        for (int ni = 0; ni < 4; ++ni) {
                            const int col = ccol + ni * 16;
                            const int dloc = fr + 16 * ni;                 // dim-in-pass 0..63
                            ushort4 o;
                            o.x = (rw + 0 < M) ? f2bf(acc[mi][ni][0] + bias[col]) : (unsigned short)0;
                            o.y = (rw + 1 < M) ? f2bf(acc[mi][ni][1] + bias[col]) : (unsigned short)0;
                            o.z = (rw + 2 < M) ? f2bf(acc[mi][ni][2] + bias[col]) : (unsigned short)0;
                            o.w = (rw + 3 < M) ? f2bf(acc[mi][ni][3] + bias[col]) : (unsigned short)0;
                            *(ushort4*)(EX + dloc * 136 + tok0) = o;
                        }
                    }
                }
                __syncthreads();
                const int d = tid >> 2;
                const int tch = (tid & 3) * 32;
                const int gtok = bm * 128 + tch;
                unsigned short* dst = vT + (size_t)(dbase + p * 64 + d) * VT_LD + gtok;
                const unsigned short* srcl = EX + d * 136 + tch;
                if (gtok + 32 <= VT_LD) {
#pragma unroll
                    for (int c2 = 0; c2 < 32; c2 += 8)
                        *(bf16x8*)(dst + c2) = *(const bf16x8*)(srcl + c2);
                } else {
                    for (int c2 = 0; c2 < 32; ++c2)
                        if (gtok + c2 < VT_LD) dst[c2] = srcl[c2];
                }
            }
        }
    }
}

// ---------------- cls attention, flash-decode split-K (bf16 K/V) ----------------
#define CCH 128
#define NCHUNK ((S_TOT + CCH - 1) / CCH)   // 65
#define PSTRIDE 68

__global__ __launch_bounds__(256) void cls_attn_partial(const unsigned short* __restrict__ qkv,
                                                        float* __restrict__ part)
{
    const int h = blockIdx.x;
    const int c = blockIdx.y;
    const int tid = threadIdx.x;
    const int base = c * CCH;

    __shared__ float qs[4][64];
    __shared__ __align__(16) unsigned short Kl[128 * 64];   // staged K chunk, swizzled
    __shared__ float sc[4][CCH];
    __shared__ float ored[4][4][64];
    __shared__ float ml[4][2];

    {
        const int qi = tid >> 6, d = tid & 63;
        qs[qi][d] = bf2f(qkv[(size_t)qi * QKV_LD + h * HD + d]);
    }
    // stage K rows via global_load_lds (wave-contiguous LDS, XOR-swizzled chunks)
    for (int i = tid; i < 1024; i += 256) {
        const int kr = i >> 3;
        const int dc = (i & 7) ^ (kr & 7);
        int j = base + kr; if (j > S_TOT - 1) j = S_TOT - 1;
        const unsigned short* g = qkv + (size_t)j * QKV_LD + EMBED + h * HD + dc * 8;
        __builtin_amdgcn_global_load_lds((const __attribute__((address_space(1))) void*)g,
                                         (__attribute__((address_space(3))) void*)(Kl + i * 8), 16, 0, 0);
    }
    __syncthreads();

    // scores: thread -> (key = tid&127, query-pair = tid>>7); K from LDS
    {
        const int jj = tid & 127;
        const int qp = (tid >> 7) * 2;
        const int j = base + jj;
        float s0 = -INFINITY, s1 = -INFINITY;
        if (j < S_TOT) {
            float a0 = 0.f, a1 = 0.f;
#pragma unroll
            for (int cch = 0; cch < 8; ++cch) {
                const int slot = cch ^ (jj & 7);
                const bf16x8 kv8 = *(const bf16x8*)(Kl + jj * 64 + slot * 8);
#pragma unroll
                for (int u = 0; u < 8; ++u) {
                    const float kf = bf2f((unsigned short)kv8[u]);
                    a0 += qs[qp + 0][cch * 8 + u] * kf;
                    a1 += qs[qp + 1][cch * 8 + u] * kf;
                }
            }
            s0 = a0 * 0.125f; s1 = a1 * 0.125f;
        }
        sc[qp + 0][jj] = s0;
        sc[qp + 1][jj] = s1;
    }
    __syncthreads();

    const int w = tid >> 6, lane = tid & 63;
    {
        float m = fmaxf(sc[w][lane], sc[w][lane + 64]);
#pragma unroll
        for (int off = 32; off > 0; off >>= 1) m = fmaxf(m, __shfl_xor(m, off, 64));
        const float e0 = expf(sc[w][lane] - m);
        const float e1 = expf(sc[w][lane + 64] - m);
        sc[w][lane] = e0; sc[w][lane + 64] = e1;
        float lsum = e0 + e1;
#pragma unroll
        for (int off = 32; off > 0; off >>= 1) lsum += __shfl_xor(lsum, off, 64);
        if (lane == 0) { ml[w][0] = m; ml[w][1] = lsum; }
    }
    __syncthreads();

    {
        const int g = w, d = lane;
        float a0 = 0.f, a1 = 0.f, a2 = 0.f, a3 = 0.f;
        for (int jj = g; jj < CCH; jj += 4) {
            const int j = base + jj;
            if (j >= S_TOT) break;
            const float vv = bf2f(qkv[(size_t)j * QKV_LD + 2 * EMBED + h * HD + d]);
            a0 += sc[0][jj] * vv; a1 += sc[1][jj] * vv;
            a2 += sc[2][jj] * vv; a3 += sc[3][jj] * vv;
        }
        ored[g][0][d] = a0; ored[g][1][d] = a1; ored[g][2][d] = a2; ored[g][3][d] = a3;
    }
    __syncthreads();

    {
        const int qi = tid >> 6, d = tid & 63;
        const float o = ored[0][qi][d] + ored[1][qi][d] + ored[2][qi][d] + ored[3][qi][d];
        float* pb = part + ((size_t)(h * NCHUNK + c) * 4 + qi) * PSTRIDE;
        pb[d] = o;
        if (d == 0) { pb[64] = ml[qi][0]; pb[65] = ml[qi][1]; }
    }
}

__global__ __launch_bounds__(256) void cls_attn_combine(const float* __restrict__ part,
                                                        unsigned short* __restrict__ attn)
{
    const int h = blockIdx.x;
    const int qi = threadIdx.x >> 6, d = threadIdx.x & 63;
    float M = -INFINITY;
    for (int c = 0; c < NCHUNK; ++c)
        M = fmaxf(M, part[((size_t)(h * NCHUNK + c) * 4 + qi) * PSTRIDE + 64]);
    float acc = 0.f, L = 0.f;
    for (int c = 0; c < NCHUNK; ++c) {
        const float* pb = part + ((size_t)(h * NCHUNK + c) * 4 + qi) * PSTRIDE;
        const float s = expf(pb[64] - M);
        acc += s * pb[d];
        L   += s * pb[65];
    }
    attn[(size_t)qi * EMBED + h * HD + d] = f2bf(acc / L);
}

// ---------------- patch attention, MFMA (dense 32x112 band) ----------------
#define SW 116   // S stride (fp32)
#define PW 136   // P stride (bf16)

__global__ __launch_bounds__(256) void patch_attn_mfma(
    const unsigned short* __restrict__ qkv,   // [8196][1536] bf16, rope applied
    const unsigned short* __restrict__ vT,    // [512][VT_LD] v^T bf16
    unsigned short* __restrict__ attnb)       // [8196][512] bf16
{
    const int l0 = blockIdx.x * 32;
    const int h = blockIdx.y;
    const int tid = threadIdx.x;
    const int lane = tid & 63, w = tid >> 6;

    __shared__ __align__(16) unsigned short Qs[32 * 64];
    __shared__ __align__(16) unsigned short Ks[112 * 64];
    __shared__ __align__(16) unsigned short Vt[64 * 128];
    __shared__ __align__(16) float Sm[32 * SW];   // P (bf16 [32][PW]) aliases this

    {
        const int i = tid;
        const int t = i >> 3;
        const int dcl = (i & 7) ^ (t & 7);
        const unsigned short* g = qkv + (size_t)(NUM_CLS + l0 + t) * QKV_LD + h * HD + dcl * 8;
        __builtin_amdgcn_global_load_lds((const __attribute__((address_space(1))) void*)g,
                                         (__attribute__((address_space(3))) void*)(Qs + i * 8), 16, 0, 0);
    }
    for (int i = tid; i < 896; i += 256) {
        const int c = i >> 3;
        const int dcl = (i & 7) ^ (c & 7);
        int tok = (c >= 104 && c < 108) ? (c - 104) : (l0 - 32 + c);
        tok = tok < 0 ? 0 : (tok > S_TOT - 1 ? S_TOT - 1 : tok);
        const unsigned short* g = qkv + (size_t)tok * QKV_LD + EMBED + h * HD + dcl * 8;
        __builtin_amdgcn_global_load_lds((const __attribute__((address_space(1))) void*)g,
                                         (__attribute__((address_space(3))) void*)(Ks + i * 8), 16, 0, 0);
    }
    for (int i = tid; i < 1024; i += 256) {
        const int d = i >> 4;
        const int kcl = (i & 15) ^ (d & 15);
        const int c0 = kcl * 8;
        int tokb = (c0 == 104) ? 0 : (l0 - 32 + c0);
        tokb = tokb < 0 ? 0 : (tokb > 8192 ? 8192 : tokb);
        const unsigned short* g = vT + (size_t)(h * HD + d) * VT_LD + tokb;
        __builtin_amdgcn_global_load_lds((const __attribute__((address_space(1))) void*)g,
                                         (__attribute__((address_space(3))) void*)(Vt + i * 8), 16, 0, 0);
    }
    __syncthreads();

    bf16x8 qf[2][2];
#pragma unroll
    for (int mt = 0; mt < 2; ++mt)
#pragma unroll
        for (int ks = 0; ks < 2; ++ks) {
            const int row = mt * 16 + (lane & 15);
            const int dc = (ks * 4 + (lane >> 4)) ^ (row & 7);
            qf[mt][ks] = *(const bf16x8*)(Qs + row * 64 + dc * 8);
        }
    for (int idx = w; idx < 14; idx += 4) {
        const int mt = idx & 1, nt = idx >> 1;
        f32x4 acc = (f32x4)0.f;
#pragma unroll
        for (int ks = 0; ks < 2; ++ks) {
            const int kr = nt * 16 + (lane & 15);
            const int dc = (ks * 4 + (lane >> 4)) ^ (kr & 7);
            const bf16x8 kf = *(const bf16x8*)(Ks + kr * 64 + dc * 8);
            acc = __builtin_amdgcn_mfma_f32_16x16x32_bf16(qf[mt][ks], kf, acc, 0, 0, 0);
        }
        const int col = nt * 16 + (lane & 15);
        const int r0 = mt * 16 + (lane >> 4) * 4;
#pragma unroll
        for (int r = 0; r < 4; ++r) Sm[(r0 + r) * SW + col] = acc[r];
    }
    __syncthreads();

    {
        const int t = tid >> 3, lq = tid & 7;
        float e[14];
        float m = -INFINITY;
#pragma unroll
        for (int j = 0; j < 14; ++j) {
            const int c = lq + 8 * j;
            bool valid;
            if (c >= 104) valid = (c < 108);
            else {
                const int r = c - 4;
                const int pos = l0 - 32 + r;
                valid = (c >= 4) && (c < 100) && (r >= t) && (r <= t + 64) &&
                        (pos >= 0) && (pos < PATCH_LEN);
            }
            e[j] = valid ? Sm[t * SW + c] * 0.125f : -INFINITY;
            m = fmaxf(m, e[j]);
        }
#pragma unroll
        for (int off = 1; off < 8; off <<= 1) m = fmaxf(m, __shfl_xor(m, off, 64));
        float sum = 0.f;
#pragma unroll
        for (int j = 0; j < 14; ++j) { e[j] = expf(e[j] - m); sum += e[j]; }
#pragma unroll
        for (int off = 1; off < 8; off <<= 1) sum += __shfl_xor(sum, off, 64);
        const float inv = 1.f / sum;
        __syncthreads();
        unsigned short* P = (unsigned short*)Sm;
#pragma unroll
        for (int j = 0; j < 14; ++j) P[t * PW + lq + 8 * j] = f2bf(e[j] * inv);
        ushort2 z; z.x = 0; z.y = 0;
        *(ushort2*)(P + (tid >> 3) * PW + 112 + (tid & 7) * 2) = z;
    }
    __syncthreads();

    {
        const unsigned short* P = (const unsigned short*)Sm;
        const int mt = w & 1;
        bf16x8 pf[4];
#pragma unroll
        for (int ks = 0; ks < 4; ++ks) {
            const int row = mt * 16 + (lane & 15);
            pf[ks] = *(const bf16x8*)(P + row * PW + ks * 32 + (lane >> 4) * 8);
        }
#pragma unroll
        for (int nn = 0; nn < 2; ++nn) {
            const int nt = (w >> 1) + nn * 2;
            f32x4 acc = (f32x4)0.f;
#pragma unroll
            for (int ks = 0; ks < 4; ++ks) {
                const int d = nt * 16 + (lane & 15);
                const int kc = (ks * 4 + (lane >> 4)) ^ (d & 15);
                const bf16x8 vf = *(const bf16x8*)(Vt + d * 128 + kc * 8);
                acc = __builtin_amdgcn_mfma_f32_16x16x32_bf16(pf[ks], vf, acc, 0, 0, 0);
            }
            const int dcol = nt * 16 + (lane & 15);
            const int r0 = mt * 16 + (lane >> 4) * 4;
#pragma unroll
            for (int r = 0; r < 4; ++r)
                attnb[(size_t)(NUM_CLS + l0 + r0 + r) * EMBED + h * HD + dcol] = f2bf(acc[r]);
        }
    }
}

extern "C" void kernel_launch(void* const* d_in, const int* in_sizes, int n_in,
                              void* d_out, int out_size, void* d_ws, size_t ws_size,
                              hipStream_t stream)
{
    const float* x      = (const float*)d_in[0];
    const float* coords = (const float*)d_in[1];
    const float* w_qkv  = (const float*)d_in[2];
    const float* b_qkv  = (const float*)d_in[3];
    const float* w_out  = (const float*)d_in[4];
    const float* b_out  = (const float*)d_in[5];
    float* out = (float*)d_out;

    // ---- ws layout: fully disjoint regions (~53 MB) ----
    char* p = (char*)d_ws;
    unsigned short* qkv   = (unsigned short*)p;  p += (size_t)S_TOT * QKV_LD * 2;
    unsigned short* vT    = (unsigned short*)p;  p += (size_t)EMBED * VT_LD * 2;
    unsigned short* attnb = (unsigned short*)p;  p += (size_t)S_TOT * EMBED * 2;
    float*          part  = (float*)p;           p += (size_t)NHEAD * NCHUNK * 4 * PSTRIDE * 4;
    unsigned short* wob   = (unsigned short*)p;  p += (size_t)EMBED * EMBED * 2;
    unsigned short* xb    = (unsigned short*)p;  p += (size_t)S_TOT * EMBED * 2;
    unsigned short* wqb   = (unsigned short*)p;

    // d_out is written ONLY by the final GEMM. Output = pure function of d_in.

    {
        const int total = S_TOT * EMBED + 3 * EMBED * EMBED + EMBED * EMBED;
        cast_all<<<(total / 4 + 255) / 256, 256, 0, stream>>>(x, w_qkv, w_out, xb, wqb, wob);
    }

    // 1) qkv(bf16, rope fused, vT fused) = x @ w_qkv^T + b_qkv   [bn fastest]
    gemm_bf16_nt<1, unsigned short><<<dim3((3 * EMBED) / 128, (S_TOT + 127) / 128), 256, 0, stream>>>(
        xb, wqb, b_qkv, qkv, S_TOT, 3 * EMBED, EMBED, coords, vT);

    // 2) cls attention (split-K over 65 chunks, 520 blocks)
    cls_attn_partial<<<dim3(NHEAD, NCHUNK), 256, 0, stream>>>(qkv, part);
    cls_attn_combine<<<NHEAD, 256, 0, stream>>>(part, attnb);

    // 3) patch attention via MFMA
    patch_attn_mfma<<<dim3(PATCH_LEN / 32, NHEAD), 256, 0, stream>>>(qkv, vT, attnb);

    // 4) out = attn @ w_out^T + b_out (fp32 out)   [bn fastest]
    gemm_bf16_nt<0, float><<<dim3(EMBED / 128, (S_TOT + 127) / 128), 256, 0, stream>>>(
        attnb, wob, b_out, out, S_TOT, EMBED, EMBED, nullptr, nullptr);
}

// Round 10
// 194.009 us; speedup vs baseline: 5.3427x; 1.0081x over previous
//
#include <hip/hip_runtime.h>
#include <math.h>

#define EMBED 512
#define NHEAD 8
#define HD 64
#define NUM_CLS 4
#define WIN 32
#define WLEN 65          // 2*WIN+1
#define PATCH_LEN 8192
#define S_TOT 8196       // NUM_CLS + PATCH_LEN
#define QKV_LD 1536
#define VT_LD 8200       // padded, multiple of 8 -> 16B-aligned rows

typedef short bf16x8 __attribute__((ext_vector_type(8)));
typedef float f32x4 __attribute__((ext_vector_type(4)));

__device__ __forceinline__ unsigned short f2bf(float f) {
    unsigned u = __float_as_uint(f);
    return (unsigned short)((u + 0x7fffu + ((u >> 16) & 1u)) >> 16);
}
__device__ __forceinline__ float bf2f(unsigned short v) {
    return __uint_as_float((unsigned)v << 16);
}
__device__ __forceinline__ void gll16(const unsigned short* g, unsigned short* l) {
    __builtin_amdgcn_global_load_lds((const __attribute__((address_space(1))) void*)g,
                                     (__attribute__((address_space(3))) void*)l, 16, 0, 0);
}

// ---------------- fused fp32 -> bf16 cast of x | w_qkv | w_out ----------------
__global__ __launch_bounds__(256) void cast_all(const float* __restrict__ x,
                                                const float* __restrict__ wq,
                                                const float* __restrict__ wo,
                                                unsigned short* __restrict__ xb,
                                                unsigned short* __restrict__ wqb,
                                                unsigned short* __restrict__ wob)
{
    const int n1 = S_TOT * EMBED;
    const int n2 = 3 * EMBED * EMBED;
    const int n3 = EMBED * EMBED;
    const int i = (blockIdx.x * 256 + threadIdx.x) * 4;
    const float* src;
    unsigned short* dst;
    int j;
    if (i < n1)           { src = x;  dst = xb;  j = i; }
    else if (i < n1 + n2) { src = wq; dst = wqb; j = i - n1; }
    else if (i < n1 + n2 + n3) { src = wo; dst = wob; j = i - n1 - n2; }
    else return;
    const float4 v = *(const float4*)(src + j);
    ushort4 o;
    o.x = f2bf(v.x); o.y = f2bf(v.y); o.z = f2bf(v.z); o.w = f2bf(v.w);
    *(ushort4*)(dst + j) = o;
}

// ---------------- QKV GEMM: qkv = x @ w_qkv^T + b, rope + vT fused ----------------
// 128x128 tile, BK=32, double-buffered LDS (1 barrier/iter). Grid (bn=12, bm=65).
#define EXW 136   // EX row stride (ushorts); 272B, 16B-aligned
__global__ __launch_bounds__(256) void gemm_qkv(const unsigned short* __restrict__ A,
                                                const unsigned short* __restrict__ B,
                                                const float* __restrict__ bias,
                                                unsigned short* __restrict__ C,
                                                const float* __restrict__ coords,
                                                unsigned short* __restrict__ vT)
{
    const int M = S_TOT, N = 3 * EMBED, K = EMBED;
    __shared__ __align__(16) unsigned short As[2][128 * 32];
    __shared__ __align__(16) unsigned short Bs[2][128 * 32];
    __shared__ __align__(16) unsigned short EX[64 * EXW];   // rt table / store staging
    const int tid = threadIdx.x;
    const int lane = tid & 63, w = tid >> 6;
    const int bn = blockIdx.x, bm = blockIdx.y;   // bn fastest -> A-stripe L2 reuse

    const int ar0 = tid >> 2;
    const int col8 = (tid & 3) * 8;
    int gm0 = bm * 128 + ar0;       if (gm0 >= M) gm0 = M - 1;
    int gm1 = bm * 128 + ar0 + 64;  if (gm1 >= M) gm1 = M - 1;
    const unsigned short* pa0 = A + (size_t)gm0 * K + col8;
    const unsigned short* pa1 = A + (size_t)gm1 * K + col8;
    const unsigned short* pb0 = B + (size_t)(bn * 128 + ar0) * K + col8;
    const unsigned short* pb1 = B + (size_t)(bn * 128 + ar0 + 64) * K + col8;

    const int wr = (w & 1) * 64;
    const int wc = (w >> 1) * 64;
    const int fr = lane & 15;
    const int fk = (lane >> 4) * 8;

    f32x4 acc[4][4];
#pragma unroll
    for (int mi = 0; mi < 4; ++mi)
#pragma unroll
        for (int ni = 0; ni < 4; ++ni) acc[mi][ni] = (f32x4)0.f;

    // prefetch iter 0
    gll16(pa0, As[0] + tid * 8);
    gll16(pa1, As[0] + (tid + 256) * 8);
    gll16(pb0, Bs[0] + tid * 8);
    gll16(pb1, Bs[0] + (tid + 256) * 8);

    for (int it = 0; it < 16; ++it) {
        __syncthreads();            // drains prefetch issued one iteration ago
        if (it + 1 < 16) {
            const int k0 = (it + 1) * 32;
            const int nb = (it + 1) & 1;
            gll16(pa0 + k0, As[nb] + tid * 8);
            gll16(pa1 + k0, As[nb] + (tid + 256) * 8);
            gll16(pb0 + k0, Bs[nb] + tid * 8);
            gll16(pb1 + k0, Bs[nb] + (tid + 256) * 8);
        }
        const int cb = it & 1;
        bf16x8 af[4], bf[4];
#pragma unroll
        for (int mi = 0; mi < 4; ++mi)
            af[mi] = *(const bf16x8*)(As[cb] + (wr + mi * 16 + fr) * 32 + fk);
#pragma unroll
        for (int ni = 0; ni < 4; ++ni)
            bf[ni] = *(const bf16x8*)(Bs[cb] + (wc + ni * 16 + fr) * 32 + fk);
#pragma unroll
        for (int mi = 0; mi < 4; ++mi)
#pragma unroll
            for (int ni = 0; ni < 4; ++ni)
                acc[mi][ni] = __builtin_amdgcn_mfma_f32_16x16x32_bf16(af[mi], bf[ni], acc[mi][ni], 0, 0, 0);
    }

    const int ccol = bn * 128 + wc + fr;

    if (bn < 8) {
        // ---- q/k sections: rope table, pack to regs, coalesced stores via EX ----
        ushort2* rt = (ushort2*)EX;
        for (int idx = tid; idx < 4096; idx += 256) {
            const int rr = idx >> 5, pr = idx & 31;
            int l = bm * 128 + rr - NUM_CLS;
            l = l < 0 ? 0 : (l > PATCH_LEN - 1 ? PATCH_LEN - 1 : l);
            const float cxy = coords[l * 2 + (pr >> 4)] * 1e-5f;
            const float f = cxy * __expf(-(float)(pr & 15) * 0.5756462732485114f);
            float sn, cs;
            __sincosf(f, &sn, &cs);
            ushort2 e; e.x = f2bf(cs); e.y = f2bf(sn);
            rt[idx] = e;
        }
        __syncthreads();

        unsigned pv[4][4][2];   // packed bf16 pairs (r0r1, r2r3)
#pragma unroll
        for (int mi = 0; mi < 4; ++mi) {
#pragma unroll
            for (int r = 0; r < 4; ++r) {
                const int rloc = wr + mi * 16 + (lane >> 4) * 4 + r;
                const int row = bm * 128 + rloc;
                const bool patch = (row >= NUM_CLS) && (row < M);
#pragma unroll
                for (int ni = 0; ni < 4; ++ni) {
                    const int col = ccol + ni * 16;
                    const float biased = acc[mi][ni][r] + bias[col];
                    const float prt = __shfl_xor(biased, 1);   // uniform flow
                    float outv = biased;
                    if (patch) {
                        const ushort2 e = rt[rloc * 32 + ((col & 63) >> 1)];
                        const float cs = bf2f(e.x), sn = bf2f(e.y);
                        outv = (col & 1) ? (biased * cs + prt * sn)
                                         : (biased * cs - prt * sn);
                    }
                    const unsigned us = f2bf(outv);
                    if (r & 1) pv[mi][ni][r >> 1] |= us << 16;
                    else       pv[mi][ni][r >> 1] = us;
                }
            }
        }
        // two passes of 64 rows: half-waves stage, all threads store coalesced
        for (int p = 0; p < 2; ++p) {
            __syncthreads();
            if ((w & 1) == p) {
#pragma unroll
                for (int mi = 0; mi < 4; ++mi) {
#pragma unroll
                    for (int r = 0; r < 4; ++r) {
                        const int rl = mi * 16 + (lane >> 4) * 4 + r;   // 0..63
#pragma unroll
                        for (int ni = 0; ni < 4; ++ni) {
                            const unsigned pw = pv[mi][ni][r >> 1];
                            EX[rl * EXW + wc + fr + ni * 16] =
                                (unsigned short)((r & 1) ? (pw >> 16) : (pw & 0xffff));
                        }
                    }
                }
            }
            __syncthreads();
#pragma unroll
            for (int i = 0; i < 4; ++i) {
                const int idx = tid + 256 * i;
                const int rowl = idx >> 4, ch = idx & 15;
                const int grow = bm * 128 + p * 64 + rowl;
                if (grow < M)
                    *(bf16x8*)(C + (size_t)grow * N + bn * 128 + ch * 8) =
                        *(const bf16x8*)(EX + rowl * EXW + ch * 8);
            }
        }
    } else {
        const int dbase = (bn - 8) * 128;
        // row-major qkv v store (read by cls PV only)
#pragma unroll
        for (int mi = 0; mi < 4; ++mi) {
            const int rbase = bm * 128 + wr + mi * 16 + (lane >> 4) * 4;
#pragma unroll
            for (int ni = 0; ni < 4; ++ni) {
                const int col = ccol + ni * 16;
#pragma unroll
                for (int r = 0; r < 4; ++r) {
                    const int row = rbase + r;
                    if (row < M)
                        C[(size_t)row * N + col] = f2bf(acc[mi][ni][r] + bias[col]);
                }
            }
        }
        // transposed vT store via EX, 2 passes of 64 dims -> coalesced rows
        for (int p = 0; p < 2; ++p) {
            __syncthreads();
            if ((w >> 1) == p) {   // waves whose wc == p*64 own these dims
#pragma unroll
                for (int mi = 0; mi < 4; ++mi) {
                    const int tok0 = wr + mi * 16 + (lane >> 4) * 4;
                    const int rw = bm * 128 + tok0;
#pragma unroll
                    for (int ni = 0; ni < 4; ++ni) {
                        const int col = ccol + ni * 16;
                        const int dloc = fr + 16 * ni;
                        ushort4 o;
                        o.x = (rw + 0 < M) ? f2bf(acc[mi][ni][0] + bias[col]) : (unsigned short)0;
                        o.y = (rw + 1 < M) ? f2bf(acc[mi][ni][1] + bias[col]) : (unsigned short)0;
                        o.z = (rw + 2 < M) ? f2bf(acc[mi][ni][2] + bias[col]) : (unsigned short)0;
                        o.w = (rw + 3 < M) ? f2bf(acc[mi][ni][3] + bias[col]) : (unsigned short)0;
                        *(ushort4*)(EX + dloc * EXW + tok0) = o;
                    }
                }
            }
            __syncthreads();
            const int d = tid >> 2;
            const int tch = (tid & 3) * 32;
            const int gtok = bm * 128 + tch;
            unsigned short* dst = vT + (size_t)(dbase + p * 64 + d) * VT_LD + gtok;
            const unsigned short* srcl = EX + d * EXW + tch;
            if (gtok + 32 <= VT_LD) {
#pragma unroll
                for (int c2 = 0; c2 < 32; c2 += 8)
                    *(bf16x8*)(dst + c2) = *(const bf16x8*)(srcl + c2);
            } else {
                for (int c2 = 0; c2 < 32; ++c2)
                    if (gtok + c2 < VT_LD) dst[c2] = srcl[c2];
            }
        }
    }
}

// ---------------- out GEMM: out = attn @ w_out^T + b (fp32) ----------------
// 64x128 tile (M x N), BK=32, double-buffered, grid (4, 129) = 516 blocks.
__global__ __launch_bounds__(256) void gemm_out(const unsigned short* __restrict__ A,
                                                const unsigned short* __restrict__ B,
                                                const float* __restrict__ bias,
                                                float* __restrict__ C)
{
    const int M = S_TOT, N = EMBED, K = EMBED;
    __shared__ __align__(16) unsigned short As[2][64 * 32];
    __shared__ __align__(16) unsigned short Bs[2][128 * 32];
    const int tid = threadIdx.x;
    const int lane = tid & 63, w = tid >> 6;
    const int bn = blockIdx.x, bm = blockIdx.y;

    const int ar0 = tid >> 2;
    const int col8 = (tid & 3) * 8;
    int gm0 = bm * 64 + ar0;  if (gm0 >= M) gm0 = M - 1;
    const unsigned short* pa0 = A + (size_t)gm0 * K + col8;
    const unsigned short* pb0 = B + (size_t)(bn * 128 + ar0) * K + col8;
    const unsigned short* pb1 = B + (size_t)(bn * 128 + ar0 + 64) * K + col8;

    const int wr = (w & 1) * 32;
    const int wc = (w >> 1) * 64;
    const int fr = lane & 15;
    const int fk = (lane >> 4) * 8;

    f32x4 acc[2][4];
#pragma unroll
    for (int mi = 0; mi < 2; ++mi)
#pragma unroll
        for (int ni = 0; ni < 4; ++ni) acc[mi][ni] = (f32x4)0.f;

    gll16(pa0, As[0] + tid * 8);
    gll16(pb0, Bs[0] + tid * 8);
    gll16(pb1, Bs[0] + (tid + 256) * 8);

    for (int it = 0; it < 16; ++it) {
        __syncthreads();
        if (it + 1 < 16) {
            const int k0 = (it + 1) * 32;
            const int nb = (it + 1) & 1;
            gll16(pa0 + k0, As[nb] + tid * 8);
            gll16(pb0 + k0, Bs[nb] + tid * 8);
            gll16(pb1 + k0, Bs[nb] + (tid + 256) * 8);
        }
        const int cb = it & 1;
        bf16x8 af[2], bf[4];
#pragma unroll
        for (int mi = 0; mi < 2; ++mi)
            af[mi] = *(const bf16x8*)(As[cb] + (wr + mi * 16 + fr) * 32 + fk);
#pragma unroll
        for (int ni = 0; ni < 4; ++ni)
            bf[ni] = *(const bf16x8*)(Bs[cb] + (wc + ni * 16 + fr) * 32 + fk);
#pragma unroll
        for (int mi = 0; mi < 2; ++mi)
#pragma unroll
            for (int ni = 0; ni < 4; ++ni)
                acc[mi][ni] = __builtin_amdgcn_mfma_f32_16x16x32_bf16(af[mi], bf[ni], acc[mi][ni], 0, 0, 0);
    }

    const int ccol = bn * 128 + wc + fr;
#pragma unroll
    for (int mi = 0; mi < 2; ++mi) {
        const int rbase = bm * 64 + wr + mi * 16 + (lane >> 4) * 4;
#pragma unroll
        for (int r = 0; r < 4; ++r) {
            const int row = rbase + r;
            if (row < M) {
#pragma unroll
                for (int ni = 0; ni < 4; ++ni)
                    C[(size_t)row * N + ccol + ni * 16] = acc[mi][ni][r] + bias[ccol + ni * 16];
            }
        }
    }
}

// ---------------- cls attention, flash-decode split-K (bf16 K/V) ----------------
#define CCH 128
#define NCHUNK ((S_TOT + CCH - 1) / CCH)   // 65
#define PSTRIDE 68

__global__ __launch_bounds__(256) void cls_attn_partial(const unsigned short* __restrict__ qkv,
                                                        float* __restrict__ part)
{
    const int h = blockIdx.x;
    const int c = blockIdx.y;
    const int tid = threadIdx.x;
    const int base = c * CCH;

    __shared__ float qs[4][64];
    __shared__ __align__(16) unsigned short Kl[128 * 64];   // staged K chunk, swizzled
    __shared__ float sc[4][CCH];
    __shared__ float ored[4][4][64];
    __shared__ float ml[4][2];

    {
        const int qi = tid >> 6, d = tid & 63;
        qs[qi][d] = bf2f(qkv[(size_t)qi * QKV_LD + h * HD + d]);
    }
    for (int i = tid; i < 1024; i += 256) {
        const int kr = i >> 3;
        const int dc = (i & 7) ^ (kr & 7);
        int j = base + kr; if (j > S_TOT - 1) j = S_TOT - 1;
        gll16(qkv + (size_t)j * QKV_LD + EMBED + h * HD + dc * 8, Kl + i * 8);
    }
    __syncthreads();

    {
        const int jj = tid & 127;
        const int qp = (tid >> 7) * 2;
        const int j = base + jj;
        float s0 = -INFINITY, s1 = -INFINITY;
        if (j < S_TOT) {
            float a0 = 0.f, a1 = 0.f;
#pragma unroll
            for (int cch = 0; cch < 8; ++cch) {
                const int slot = cch ^ (jj & 7);
                const bf16x8 kv8 = *(const bf16x8*)(Kl + jj * 64 + slot * 8);
#pragma unroll
                for (int u = 0; u < 8; ++u) {
                    const float kf = bf2f((unsigned short)kv8[u]);
                    a0 += qs[qp + 0][cch * 8 + u] * kf;
                    a1 += qs[qp + 1][cch * 8 + u] * kf;
                }
            }
            s0 = a0 * 0.125f; s1 = a1 * 0.125f;
        }
        sc[qp + 0][jj] = s0;
        sc[qp + 1][jj] = s1;
    }
    __syncthreads();

    const int w = tid >> 6, lane = tid & 63;
    {
        float m = fmaxf(sc[w][lane], sc[w][lane + 64]);
#pragma unroll
        for (int off = 32; off > 0; off >>= 1) m = fmaxf(m, __shfl_xor(m, off, 64));
        const float e0 = expf(sc[w][lane] - m);
        const float e1 = expf(sc[w][lane + 64] - m);
        sc[w][lane] = e0; sc[w][lane + 64] = e1;
        float lsum = e0 + e1;
#pragma unroll
        for (int off = 32; off > 0; off >>= 1) lsum += __shfl_xor(lsum, off, 64);
        if (lane == 0) { ml[w][0] = m; ml[w][1] = lsum; }
    }
    __syncthreads();

    {
        const int g = w, d = lane;
        float a0 = 0.f, a1 = 0.f, a2 = 0.f, a3 = 0.f;
        for (int jj = g; jj < CCH; jj += 4) {
            const int j = base + jj;
            if (j >= S_TOT) break;
            const float vv = bf2f(qkv[(size_t)j * QKV_LD + 2 * EMBED + h * HD + d]);
            a0 += sc[0][jj] * vv; a1 += sc[1][jj] * vv;
            a2 += sc[2][jj] * vv; a3 += sc[3][jj] * vv;
        }
        ored[g][0][d] = a0; ored[g][1][d] = a1; ored[g][2][d] = a2; ored[g][3][d] = a3;
    }
    __syncthreads();

    {
        const int qi = tid >> 6, d = tid & 63;
        const float o = ored[0][qi][d] + ored[1][qi][d] + ored[2][qi][d] + ored[3][qi][d];
        float* pb = part + ((size_t)(h * NCHUNK + c) * 4 + qi) * PSTRIDE;
        pb[d] = o;
        if (d == 0) { pb[64] = ml[qi][0]; pb[65] = ml[qi][1]; }
    }
}

__global__ __launch_bounds__(256) void cls_attn_combine(const float* __restrict__ part,
                                                        unsigned short* __restrict__ attn)
{
    const int h = blockIdx.x;
    const int qi = threadIdx.x >> 6, d = threadIdx.x & 63;
    float M = -INFINITY;
    for (int c = 0; c < NCHUNK; ++c)
        M = fmaxf(M, part[((size_t)(h * NCHUNK + c) * 4 + qi) * PSTRIDE + 64]);
    float acc = 0.f, L = 0.f;
    for (int c = 0; c < NCHUNK; ++c) {
        const float* pb = part + ((size_t)(h * NCHUNK + c) * 4 + qi) * PSTRIDE;
        const float s = expf(pb[64] - M);
        acc += s * pb[d];
        L   += s * pb[65];
    }
    attn[(size_t)qi * EMBED + h * HD + d] = f2bf(acc / L);
}

// ---------------- patch attention, MFMA (dense 32x112 band) ----------------
#define SW 116   // S stride (fp32)
#define PW 136   // P stride (bf16)

__global__ __launch_bounds__(256) void patch_attn_mfma(
    const unsigned short* __restrict__ qkv,   // [8196][1536] bf16, rope applied
    const unsigned short* __restrict__ vT,    // [512][VT_LD] v^T bf16
    unsigned short* __restrict__ attnb)       // [8196][512] bf16
{
    const int l0 = blockIdx.x * 32;
    const int h = blockIdx.y;
    const int tid = threadIdx.x;
    const int lane = tid & 63, w = tid >> 6;

    __shared__ __align__(16) unsigned short Qs[32 * 64];
    __shared__ __align__(16) unsigned short Ks[112 * 64];
    __shared__ __align__(16) unsigned short Vt[64 * 128];
    __shared__ __align__(16) float Sm[32 * SW];   // P (bf16 [32][PW]) aliases this

    {
        const int i = tid;
        const int t = i >> 3;
        const int dcl = (i & 7) ^ (t & 7);
        gll16(qkv + (size_t)(NUM_CLS + l0 + t) * QKV_LD + h * HD + dcl * 8, Qs + i * 8);
    }
    for (int i = tid; i < 896; i += 256) {
        const int c = i >> 3;
        const int dcl = (i & 7) ^ (c & 7);
        int tok = (c >= 104 && c < 108) ? (c - 104) : (l0 - 32 + c);
        tok = tok < 0 ? 0 : (tok > S_TOT - 1 ? S_TOT - 1 : tok);
        gll16(qkv + (size_t)tok * QKV_LD + EMBED + h * HD + dcl * 8, Ks + i * 8);
    }
    for (int i = tid; i < 1024; i += 256) {
        const int d = i >> 4;
        const int kcl = (i & 15) ^ (d & 15);
        const int c0 = kcl * 8;
        int tokb = (c0 == 104) ? 0 : (l0 - 32 + c0);
        tokb = tokb < 0 ? 0 : (tokb > 8192 ? 8192 : tokb);
        gll16(vT + (size_t)(h * HD + d) * VT_LD + tokb, Vt + i * 8);
    }
    __syncthreads();

    bf16x8 qf[2][2];
#pragma unroll
    for (int mt = 0; mt < 2; ++mt)
#pragma unroll
        for (int ks = 0; ks < 2; ++ks) {
            const int row = mt * 16 + (lane & 15);
            const int dc = (ks * 4 + (lane >> 4)) ^ (row & 7);
            qf[mt][ks] = *(const bf16x8*)(Qs + row * 64 + dc * 8);
        }
    for (int idx = w; idx < 14; idx += 4) {
        const int mt = idx & 1, nt = idx >> 1;
        f32x4 acc = (f32x4)0.f;
#pragma unroll
        for (int ks = 0; ks < 2; ++ks) {
            const int kr = nt * 16 + (lane & 15);
            const int dc = (ks * 4 + (lane >> 4)) ^ (kr & 7);
            const bf16x8 kf = *(const bf16x8*)(Ks + kr * 64 + dc * 8);
            acc = __builtin_amdgcn_mfma_f32_16x16x32_bf16(qf[mt][ks], kf, acc, 0, 0, 0);
        }
        const int col = nt * 16 + (lane & 15);
        const int r0 = mt * 16 + (lane >> 4) * 4;
#pragma unroll
        for (int r = 0; r < 4; ++r) Sm[(r0 + r) * SW + col] = acc[r];
    }
    __syncthreads();

    {
        const int t = tid >> 3, lq = tid & 7;
        float e[14];
        float m = -INFINITY;
#pragma unroll
        for (int j = 0; j < 14; ++j) {
            const int c = lq + 8 * j;
            bool valid;
            if (c >= 104) valid = (c < 108);
            else {
                const int r = c - 4;
                const int pos = l0 - 32 + r;
                valid = (c >= 4) && (c < 100) && (r >= t) && (r <= t + 64) &&
                        (pos >= 0) && (pos < PATCH_LEN);
            }
            e[j] = valid ? Sm[t * SW + c] * 0.125f : -INFINITY;
            m = fmaxf(m, e[j]);
        }
#pragma unroll
        for (int off = 1; off < 8; off <<= 1) m = fmaxf(m, __shfl_xor(m, off, 64));
        float sum = 0.f;
#pragma unroll
        for (int j = 0; j < 14; ++j) { e[j] = expf(e[j] - m); sum += e[j]; }
#pragma unroll
        for (int off = 1; off < 8; off <<= 1) sum += __shfl_xor(sum, off, 64);
        const float inv = 1.f / sum;
        __syncthreads();
        unsigned short* P = (unsigned short*)Sm;
#pragma unroll
        for (int j = 0; j < 14; ++j) P[t * PW + lq + 8 * j] = f2bf(e[j] * inv);
        ushort2 z; z.x = 0; z.y = 0;
        *(ushort2*)(P + (tid >> 3) * PW + 112 + (tid & 7) * 2) = z;
    }
    __syncthreads();

    {
        const unsigned short* P = (const unsigned short*)Sm;
        const int mt = w & 1;
        bf16x8 pf[4];
#pragma unroll
        for (int ks = 0; ks < 4; ++ks) {
            const int row = mt * 16 + (lane & 15);
            pf[ks] = *(const bf16x8*)(P + row * PW + ks * 32 + (lane >> 4) * 8);
        }
#pragma unroll
        for (int nn = 0; nn < 2; ++nn) {
            const int nt = (w >> 1) + nn * 2;
            f32x4 acc = (f32x4)0.f;
#pragma unroll
            for (int ks = 0; ks < 4; ++ks) {
                const int d = nt * 16 + (lane & 15);
                const int kc = (ks * 4 + (lane >> 4)) ^ (d & 15);
                const bf16x8 vf = *(const bf16x8*)(Vt + d * 128 + kc * 8);
                acc = __builtin_amdgcn_mfma_f32_16x16x32_bf16(pf[ks], vf, acc, 0, 0, 0);
            }
            const int dcol = nt * 16 + (lane & 15);
            const int r0 = mt * 16 + (lane >> 4) * 4;
#pragma unroll
            for (int r = 0; r < 4; ++r)
                attnb[(size_t)(NUM_CLS + l0 + r0 + r) * EMBED + h * HD + dcol] = f2bf(acc[r]);
        }
    }
}

extern "C" void kernel_launch(void* const* d_in, const int* in_sizes, int n_in,
                              void* d_out, int out_size, void* d_ws, size_t ws_size,
                              hipStream_t stream)
{
    const float* x      = (const float*)d_in[0];
    const float* coords = (const float*)d_in[1];
    const float* w_qkv  = (const float*)d_in[2];
    const float* b_qkv  = (const float*)d_in[3];
    const float* w_out  = (const float*)d_in[4];
    const float* b_out  = (const float*)d_in[5];
    float* out = (float*)d_out;

    // ---- ws layout: fully disjoint regions (~53 MB) ----
    char* p = (char*)d_ws;
    unsigned short* qkv   = (unsigned short*)p;  p += (size_t)S_TOT * QKV_LD * 2;
    unsigned short* vT    = (unsigned short*)p;  p += (size_t)EMBED * VT_LD * 2;
    unsigned short* attnb = (unsigned short*)p;  p += (size_t)S_TOT * EMBED * 2;
    float*          part  = (float*)p;           p += (size_t)NHEAD * NCHUNK * 4 * PSTRIDE * 4;
    unsigned short* wob   = (unsigned short*)p;  p += (size_t)EMBED * EMBED * 2;
    unsigned short* xb    = (unsigned short*)p;  p += (size_t)S_TOT * EMBED * 2;
    unsigned short* wqb   = (unsigned short*)p;

    // d_out is written ONLY by the final GEMM. Output = pure function of d_in.

    {
        const int total = S_TOT * EMBED + 3 * EMBED * EMBED + EMBED * EMBED;
        cast_all<<<(total / 4 + 255) / 256, 256, 0, stream>>>(x, w_qkv, w_out, xb, wqb, wob);
    }

    // 1) qkv(bf16, rope fused, vT fused) = x @ w_qkv^T + b_qkv
    gemm_qkv<<<dim3(12, 65), 256, 0, stream>>>(xb, wqb, b_qkv, qkv, coords, vT);

    // 2) cls attention (split-K over 65 chunks, 520 blocks)
    cls_attn_partial<<<dim3(NHEAD, NCHUNK), 256, 0, stream>>>(qkv, part);
    cls_attn_combine<<<NHEAD, 256, 0, stream>>>(part, attnb);

    // 3) patch attention via MFMA
    patch_attn_mfma<<<dim3(PATCH_LEN / 32, NHEAD), 256, 0, stream>>>(qkv, vT, attnb);

    // 4) out = attn @ w_out^T + b_out (fp32), 64x128 tiles -> 516 blocks
    gemm_out<<<dim3(4, 129), 256, 0, stream>>>(attnb, wob, b_out, out);
}

// Round 11
// 184.975 us; speedup vs baseline: 5.6036x; 1.0488x over previous
//
#include <hip/hip_runtime.h>
#include <math.h>

#define EMBED 512
#define NHEAD 8
#define HD 64
#define NUM_CLS 4
#define WIN 32
#define WLEN 65          // 2*WIN+1
#define PATCH_LEN 8192
#define S_TOT 8196       // NUM_CLS + PATCH_LEN
#define QKV_LD 1536
#define VT_LD 8200       // padded, multiple of 8 -> 16B-aligned rows

typedef short bf16x8 __attribute__((ext_vector_type(8)));
typedef float f32x4 __attribute__((ext_vector_type(4)));

__device__ __forceinline__ unsigned short f2bf(float f) {
    unsigned u = __float_as_uint(f);
    return (unsigned short)((u + 0x7fffu + ((u >> 16) & 1u)) >> 16);
}
__device__ __forceinline__ float bf2f(unsigned short v) {
    return __uint_as_float((unsigned)v << 16);
}
__device__ __forceinline__ void gll16(const unsigned short* g, unsigned short* l) {
    __builtin_amdgcn_global_load_lds((const __attribute__((address_space(1))) void*)g,
                                     (__attribute__((address_space(3))) void*)l, 16, 0, 0);
}

// ---------------- fused fp32 -> bf16 cast of x | w_qkv | w_out ----------------
__global__ __launch_bounds__(256) void cast_all(const float* __restrict__ x,
                                                const float* __restrict__ wq,
                                                const float* __restrict__ wo,
                                                unsigned short* __restrict__ xb,
                                                unsigned short* __restrict__ wqb,
                                                unsigned short* __restrict__ wob)
{
    const int n1 = S_TOT * EMBED;
    const int n2 = 3 * EMBED * EMBED;
    const int n3 = EMBED * EMBED;
    const int i = (blockIdx.x * 256 + threadIdx.x) * 4;
    const float* src;
    unsigned short* dst;
    int j;
    if (i < n1)           { src = x;  dst = xb;  j = i; }
    else if (i < n1 + n2) { src = wq; dst = wqb; j = i - n1; }
    else if (i < n1 + n2 + n3) { src = wo; dst = wob; j = i - n1 - n2; }
    else return;
    const float4 v = *(const float4*)(src + j);
    ushort4 o;
    o.x = f2bf(v.x); o.y = f2bf(v.y); o.z = f2bf(v.z); o.w = f2bf(v.w);
    *(ushort4*)(dst + j) = o;
}

// ---------------- QKV GEMM: qkv = x @ w_qkv^T + b, rope + vT fused ----------------
// 128x128 tile, BK=32, double-buffered LDS staging (32 KB) with the 17.4 KB
// epilogue buffer UNIONED on top (dead during K-loop) -> 5 blocks/CU.
// XCD swizzle: grid 864 = 8 x 108; xcd = id&7 owns bm = xcd + 8k -> each
// A-stripe is fetched into exactly one XCD L2.
#define EXW 136   // EX row stride (ushorts); 272B, 16B-aligned
__global__ __launch_bounds__(256) void gemm_qkv(const unsigned short* __restrict__ A,
                                                const unsigned short* __restrict__ B,
                                                const float* __restrict__ bias,
                                                unsigned short* __restrict__ C,
                                                const float* __restrict__ coords,
                                                unsigned short* __restrict__ vT)
{
    const int M = S_TOT, N = 3 * EMBED, K = EMBED;
    __shared__ __align__(16) unsigned short SMEM[16384];   // 32 KB: staging dbuf / EX
    unsigned short* EX = SMEM;                              // epilogue overlay (8704 ushorts)

    const int tid = threadIdx.x;
    const int lane = tid & 63, w = tid >> 6;
    const int xcd = blockIdx.x & 7;
    const int s = blockIdx.x >> 3;          // 0..107
    const int bm = xcd + 8 * (s / 12);      // stride-8 interleave per XCD
    const int bn = s % 12;
    if (bm >= 65) return;                   // 84 filler blocks exit

    const int ar0 = tid >> 2;
    const int col8 = (tid & 3) * 8;
    int gm0 = bm * 128 + ar0;       if (gm0 >= M) gm0 = M - 1;
    int gm1 = bm * 128 + ar0 + 64;  if (gm1 >= M) gm1 = M - 1;
    const unsigned short* pa0 = A + (size_t)gm0 * K + col8;
    const unsigned short* pa1 = A + (size_t)gm1 * K + col8;
    const unsigned short* pb0 = B + (size_t)(bn * 128 + ar0) * K + col8;
    const unsigned short* pb1 = B + (size_t)(bn * 128 + ar0 + 64) * K + col8;

    const int wr = (w & 1) * 64;
    const int wc = (w >> 1) * 64;
    const int fr = lane & 15;
    const int fk = (lane >> 4) * 8;

    f32x4 acc[4][4];
#pragma unroll
    for (int mi = 0; mi < 4; ++mi)
#pragma unroll
        for (int ni = 0; ni < 4; ++ni) acc[mi][ni] = (f32x4)0.f;

    // prefetch iter 0 (As[b] = SMEM + b*4096, Bs[b] = SMEM + 8192 + b*4096)
    gll16(pa0, SMEM + tid * 8);
    gll16(pa1, SMEM + (tid + 256) * 8);
    gll16(pb0, SMEM + 8192 + tid * 8);
    gll16(pb1, SMEM + 8192 + (tid + 256) * 8);

    for (int it = 0; it < 16; ++it) {
        __syncthreads();            // drains prefetch issued one iteration ago
        if (it + 1 < 16) {
            const int k0 = (it + 1) * 32;
            const int off = ((it + 1) & 1) * 4096;
            gll16(pa0 + k0, SMEM + off + tid * 8);
            gll16(pa1 + k0, SMEM + off + (tid + 256) * 8);
            gll16(pb0 + k0, SMEM + 8192 + off + tid * 8);
            gll16(pb1 + k0, SMEM + 8192 + off + (tid + 256) * 8);
        }
        const unsigned short* Asb = SMEM + (it & 1) * 4096;
        const unsigned short* Bsb = SMEM + 8192 + (it & 1) * 4096;
        bf16x8 af[4], bf[4];
#pragma unroll
        for (int mi = 0; mi < 4; ++mi)
            af[mi] = *(const bf16x8*)(Asb + (wr + mi * 16 + fr) * 32 + fk);
#pragma unroll
        for (int ni = 0; ni < 4; ++ni)
            bf[ni] = *(const bf16x8*)(Bsb + (wc + ni * 16 + fr) * 32 + fk);
#pragma unroll
        for (int mi = 0; mi < 4; ++mi)
#pragma unroll
            for (int ni = 0; ni < 4; ++ni)
                acc[mi][ni] = __builtin_amdgcn_mfma_f32_16x16x32_bf16(af[mi], bf[ni], acc[mi][ni], 0, 0, 0);
    }
    __syncthreads();   // staging dead; EX overlay becomes safe

    const int ccol = bn * 128 + wc + fr;

    if (bn < 8) {
        // ---- q/k sections: rope table in EX, pack to regs, coalesced stores ----
        ushort2* rt = (ushort2*)EX;
        for (int idx = tid; idx < 4096; idx += 256) {
            const int rr = idx >> 5, pr = idx & 31;
            int l = bm * 128 + rr - NUM_CLS;
            l = l < 0 ? 0 : (l > PATCH_LEN - 1 ? PATCH_LEN - 1 : l);
            const float cxy = coords[l * 2 + (pr >> 4)] * 1e-5f;
            const float f = cxy * __expf(-(float)(pr & 15) * 0.5756462732485114f);
            float sn, cs;
            __sincosf(f, &sn, &cs);
            ushort2 e; e.x = f2bf(cs); e.y = f2bf(sn);
            rt[idx] = e;
        }
        __syncthreads();

        unsigned pv[4][4][2];   // packed bf16 pairs (r0r1, r2r3)
#pragma unroll
        for (int mi = 0; mi < 4; ++mi) {
#pragma unroll
            for (int r = 0; r < 4; ++r) {
                const int rloc = wr + mi * 16 + (lane >> 4) * 4 + r;
                const int row = bm * 128 + rloc;
                const bool patch = (row >= NUM_CLS) && (row < M);
#pragma unroll
                for (int ni = 0; ni < 4; ++ni) {
                    const int col = ccol + ni * 16;
                    const float biased = acc[mi][ni][r] + bias[col];
                    const float prt = __shfl_xor(biased, 1);   // uniform flow
                    float outv = biased;
                    if (patch) {
                        const ushort2 e = rt[rloc * 32 + ((col & 63) >> 1)];
                        const float cs = bf2f(e.x), sn = bf2f(e.y);
                        outv = (col & 1) ? (biased * cs + prt * sn)
                                         : (biased * cs - prt * sn);
                    }
                    const unsigned us = f2bf(outv);
                    if (r & 1) pv[mi][ni][r >> 1] |= us << 16;
                    else       pv[mi][ni][r >> 1] = us;
                }
            }
        }
        // two passes of 64 rows: half-waves stage into EX, all store coalesced
        for (int p = 0; p < 2; ++p) {
            __syncthreads();
            if ((w & 1) == p) {
#pragma unroll
                for (int mi = 0; mi < 4; ++mi) {
#pragma unroll
                    for (int r = 0; r < 4; ++r) {
                        const int rl = mi * 16 + (lane >> 4) * 4 + r;   // 0..63
#pragma unroll
                        for (int ni = 0; ni < 4; ++ni) {
                            const unsigned pw = pv[mi][ni][r >> 1];
                            EX[rl * EXW + wc + fr + ni * 16] =
                                (unsigned short)((r & 1) ? (pw >> 16) : (pw & 0xffff));
                        }
                    }
                }
            }
            __syncthreads();
#pragma unroll
            for (int i = 0; i < 4; ++i) {
                const int idx = tid + 256 * i;
                const int rowl = idx >> 4, ch = idx & 15;
                const int grow = bm * 128 + p * 64 + rowl;
                if (grow < M)
                    *(bf16x8*)(C + (size_t)grow * N + bn * 128 + ch * 8) =
                        *(const bf16x8*)(EX + rowl * EXW + ch * 8);
            }
        }
    } else {
        const int dbase = (bn - 8) * 128;
        // row-major qkv v store (read by cls PV only)
#pragma unroll
        for (int mi = 0; mi < 4; ++mi) {
            const int rbase = bm * 128 + wr + mi * 16 + (lane >> 4) * 4;
#pragma unroll
            for (int ni = 0; ni < 4; ++ni) {
                const int col = ccol + ni * 16;
#pragma unroll
                for (int r = 0; r < 4; ++r) {
                    const int row = rbase + r;
                    if (row < M)
                        C[(size_t)row * N + col] = f2bf(acc[mi][ni][r] + bias[col]);
                }
            }
        }
        // transposed vT store via EX, 2 passes of 64 dims -> coalesced rows
        for (int p = 0; p < 2; ++p) {
            __syncthreads();
            if ((w >> 1) == p) {   // waves whose wc == p*64 own these dims
#pragma unroll
                for (int mi = 0; mi < 4; ++mi) {
                    const int tok0 = wr + mi * 16 + (lane >> 4) * 4;
                    const int rw = bm * 128 + tok0;
#pragma unroll
                    for (int ni = 0; ni < 4; ++ni) {
                        const int col = ccol + ni * 16;
                        const int dloc = fr + 16 * ni;
                        ushort4 o;
                        o.x = (rw + 0 < M) ? f2bf(acc[mi][ni][0] + bias[col]) : (unsigned short)0;
                        o.y = (rw + 1 < M) ? f2bf(acc[mi][ni][1] + bias[col]) : (unsigned short)0;
                        o.z = (rw + 2 < M) ? f2bf(acc[mi][ni][2] + bias[col]) : (unsigned short)0;
                        o.w = (rw + 3 < M) ? f2bf(acc[mi][ni][3] + bias[col]) : (unsigned short)0;
                        *(ushort4*)(EX + dloc * EXW + tok0) = o;
                    }
                }
            }
            __syncthreads();
            const int d = tid >> 2;
            const int tch = (tid & 3) * 32;
            const int gtok = bm * 128 + tch;
            unsigned short* dst = vT + (size_t)(dbase + p * 64 + d) * VT_LD + gtok;
            const unsigned short* srcl = EX + d * EXW + tch;
            if (gtok + 32 <= VT_LD) {
#pragma unroll
                for (int c2 = 0; c2 < 32; c2 += 8)
                    *(bf16x8*)(dst + c2) = *(const bf16x8*)(srcl + c2);
            } else {
                for (int c2 = 0; c2 < 32; ++c2)
                    if (gtok + c2 < VT_LD) dst[c2] = srcl[c2];
            }
        }
    }
}

// ---------------- out GEMM: out = attn @ w_out^T + b (fp32) ----------------
// 64x128 tile (M x N), BK=32, double-buffered, grid (4, 129) = 516 blocks.
__global__ __launch_bounds__(256) void gemm_out(const unsigned short* __restrict__ A,
                                                const unsigned short* __restrict__ B,
                                                const float* __restrict__ bias,
                                                float* __restrict__ C)
{
    const int M = S_TOT, N = EMBED, K = EMBED;
    __shared__ __align__(16) unsigned short As[2][64 * 32];
    __shared__ __align__(16) unsigned short Bs[2][128 * 32];
    const int tid = threadIdx.x;
    const int lane = tid & 63, w = tid >> 6;
    const int bn = blockIdx.x, bm = blockIdx.y;

    const int ar0 = tid >> 2;
    const int col8 = (tid & 3) * 8;
    int gm0 = bm * 64 + ar0;  if (gm0 >= M) gm0 = M - 1;
    const unsigned short* pa0 = A + (size_t)gm0 * K + col8;
    const unsigned short* pb0 = B + (size_t)(bn * 128 + ar0) * K + col8;
    const unsigned short* pb1 = B + (size_t)(bn * 128 + ar0 + 64) * K + col8;

    const int wr = (w & 1) * 32;
    const int wc = (w >> 1) * 64;
    const int fr = lane & 15;
    const int fk = (lane >> 4) * 8;

    f32x4 acc[2][4];
#pragma unroll
    for (int mi = 0; mi < 2; ++mi)
#pragma unroll
        for (int ni = 0; ni < 4; ++ni) acc[mi][ni] = (f32x4)0.f;

    gll16(pa0, As[0] + tid * 8);
    gll16(pb0, Bs[0] + tid * 8);
    gll16(pb1, Bs[0] + (tid + 256) * 8);

    for (int it = 0; it < 16; ++it) {
        __syncthreads();
        if (it + 1 < 16) {
            const int k0 = (it + 1) * 32;
            const int nb = (it + 1) & 1;
            gll16(pa0 + k0, As[nb] + tid * 8);
            gll16(pb0 + k0, Bs[nb] + tid * 8);
            gll16(pb1 + k0, Bs[nb] + (tid + 256) * 8);
        }
        const int cb = it & 1;
        bf16x8 af[2], bf[4];
#pragma unroll
        for (int mi = 0; mi < 2; ++mi)
            af[mi] = *(const bf16x8*)(As[cb] + (wr + mi * 16 + fr) * 32 + fk);
#pragma unroll
        for (int ni = 0; ni < 4; ++ni)
            bf[ni] = *(const bf16x8*)(Bs[cb] + (wc + ni * 16 + fr) * 32 + fk);
#pragma unroll
        for (int mi = 0; mi < 2; ++mi)
#pragma unroll
            for (int ni = 0; ni < 4; ++ni)
                acc[mi][ni] = __builtin_amdgcn_mfma_f32_16x16x32_bf16(af[mi], bf[ni], acc[mi][ni], 0, 0, 0);
    }

    const int ccol = bn * 128 + wc + fr;
#pragma unroll
    for (int mi = 0; mi < 2; ++mi) {
        const int rbase = bm * 64 + wr + mi * 16 + (lane >> 4) * 4;
#pragma unroll
        for (int r = 0; r < 4; ++r) {
            const int row = rbase + r;
            if (row < M) {
#pragma unroll
                for (int ni = 0; ni < 4; ++ni)
                    C[(size_t)row * N + ccol + ni * 16] = acc[mi][ni][r] + bias[ccol + ni * 16];
            }
        }
    }
}

// ---------------- cls attention, flash-decode split-K (bf16 K/V) ----------------
#define CCH 128
#define NCHUNK ((S_TOT + CCH - 1) / CCH)   // 65
#define PSTRIDE 68

__global__ __launch_bounds__(256) void cls_attn_partial(const unsigned short* __restrict__ qkv,
                                                        float* __restrict__ part)
{
    const int h = blockIdx.x;
    const int c = blockIdx.y;
    const int tid = threadIdx.x;
    const int base = c * CCH;

    __shared__ float qs[4][64];
    __shared__ __align__(16) unsigned short Kl[128 * 64];   // staged K chunk, swizzled
    __shared__ float sc[4][CCH];
    __shared__ float ored[4][4][64];
    __shared__ float ml[4][2];

    {
        const int qi = tid >> 6, d = tid & 63;
        qs[qi][d] = bf2f(qkv[(size_t)qi * QKV_LD + h * HD + d]);
    }
    for (int i = tid; i < 1024; i += 256) {
        const int kr = i >> 3;
        const int dc = (i & 7) ^ (kr & 7);
        int j = base + kr; if (j > S_TOT - 1) j = S_TOT - 1;
        gll16(qkv + (size_t)j * QKV_LD + EMBED + h * HD + dc * 8, Kl + i * 8);
    }
    __syncthreads();

    {
        const int jj = tid & 127;
        const int qp = (tid >> 7) * 2;
        const int j = base + jj;
        float s0 = -INFINITY, s1 = -INFINITY;
        if (j < S_TOT) {
            float a0 = 0.f, a1 = 0.f;
#pragma unroll
            for (int cch = 0; cch < 8; ++cch) {
                const int slot = cch ^ (jj & 7);
                const bf16x8 kv8 = *(const bf16x8*)(Kl + jj * 64 + slot * 8);
#pragma unroll
                for (int u = 0; u < 8; ++u) {
                    const float kf = bf2f((unsigned short)kv8[u]);
                    a0 += qs[qp + 0][cch * 8 + u] * kf;
                    a1 += qs[qp + 1][cch * 8 + u] * kf;
                }
            }
            s0 = a0 * 0.125f; s1 = a1 * 0.125f;
        }
        sc[qp + 0][jj] = s0;
        sc[qp + 1][jj] = s1;
    }
    __syncthreads();

    const int w = tid >> 6, lane = tid & 63;
    {
        float m = fmaxf(sc[w][lane], sc[w][lane + 64]);
#pragma unroll
        for (int off = 32; off > 0; off >>= 1) m = fmaxf(m, __shfl_xor(m, off, 64));
        const float e0 = expf(sc[w][lane] - m);
        const float e1 = expf(sc[w][lane + 64] - m);
        sc[w][lane] = e0; sc[w][lane + 64] = e1;
        float lsum = e0 + e1;
#pragma unroll
        for (int off = 32; off > 0; off >>= 1) lsum += __shfl_xor(lsum, off, 64);
        if (lane == 0) { ml[w][0] = m; ml[w][1] = lsum; }
    }
    __syncthreads();

    {
        const int g = w, d = lane;
        float a0 = 0.f, a1 = 0.f, a2 = 0.f, a3 = 0.f;
        for (int jj = g; jj < CCH; jj += 4) {
            const int j = base + jj;
            if (j >= S_TOT) break;
            const float vv = bf2f(qkv[(size_t)j * QKV_LD + 2 * EMBED + h * HD + d]);
            a0 += sc[0][jj] * vv; a1 += sc[1][jj] * vv;
            a2 += sc[2][jj] * vv; a3 += sc[3][jj] * vv;
        }
        ored[g][0][d] = a0; ored[g][1][d] = a1; ored[g][2][d] = a2; ored[g][3][d] = a3;
    }
    __syncthreads();

    {
        const int qi = tid >> 6, d = tid & 63;
        const float o = ored[0][qi][d] + ored[1][qi][d] + ored[2][qi][d] + ored[3][qi][d];
        float* pb = part + ((size_t)(h * NCHUNK + c) * 4 + qi) * PSTRIDE;
        pb[d] = o;
        if (d == 0) { pb[64] = ml[qi][0]; pb[65] = ml[qi][1]; }
    }
}

__global__ __launch_bounds__(256) void cls_attn_combine(const float* __restrict__ part,
                                                        unsigned short* __restrict__ attn)
{
    const int h = blockIdx.x;
    const int qi = threadIdx.x >> 6, d = threadIdx.x & 63;
    float M = -INFINITY;
    for (int c = 0; c < NCHUNK; ++c)
        M = fmaxf(M, part[((size_t)(h * NCHUNK + c) * 4 + qi) * PSTRIDE + 64]);
    float acc = 0.f, L = 0.f;
    for (int c = 0; c < NCHUNK; ++c) {
        const float* pb = part + ((size_t)(h * NCHUNK + c) * 4 + qi) * PSTRIDE;
        const float s = expf(pb[64] - M);
        acc += s * pb[d];
        L   += s * pb[65];
    }
    attn[(size_t)qi * EMBED + h * HD + d] = f2bf(acc / L);
}

// ---------------- patch attention, MFMA (dense 32x112 band) ----------------
#define SW 116   // S stride (fp32)
#define PW 136   // P stride (bf16)

__global__ __launch_bounds__(256) void patch_attn_mfma(
    const unsigned short* __restrict__ qkv,   // [8196][1536] bf16, rope applied
    const unsigned short* __restrict__ vT,    // [512][VT_LD] v^T bf16
    unsigned short* __restrict__ attnb)       // [8196][512] bf16
{
    const int l0 = blockIdx.x * 32;
    const int h = blockIdx.y;
    const int tid = threadIdx.x;
    const int lane = tid & 63, w = tid >> 6;

    __shared__ __align__(16) unsigned short Qs[32 * 64];
    __shared__ __align__(16) unsigned short Ks[112 * 64];
    __shared__ __align__(16) unsigned short Vt[64 * 128];
    __shared__ __align__(16) float Sm[32 * SW];   // P (bf16 [32][PW]) aliases this

    {
        const int i = tid;
        const int t = i >> 3;
        const int dcl = (i & 7) ^ (t & 7);
        gll16(qkv + (size_t)(NUM_CLS + l0 + t) * QKV_LD + h * HD + dcl * 8, Qs + i * 8);
    }
    for (int i = tid; i < 896; i += 256) {
        const int c = i >> 3;
        const int dcl = (i & 7) ^ (c & 7);
        int tok = (c >= 104 && c < 108) ? (c - 104) : (l0 - 32 + c);
        tok = tok < 0 ? 0 : (tok > S_TOT - 1 ? S_TOT - 1 : tok);
        gll16(qkv + (size_t)tok * QKV_LD + EMBED + h * HD + dcl * 8, Ks + i * 8);
    }
    for (int i = tid; i < 1024; i += 256) {
        const int d = i >> 4;
        const int kcl = (i & 15) ^ (d & 15);
        const int c0 = kcl * 8;
        int tokb = (c0 == 104) ? 0 : (l0 - 32 + c0);
        tokb = tokb < 0 ? 0 : (tokb > 8192 ? 8192 : tokb);
        gll16(vT + (size_t)(h * HD + d) * VT_LD + tokb, Vt + i * 8);
    }
    __syncthreads();

    bf16x8 qf[2][2];
#pragma unroll
    for (int mt = 0; mt < 2; ++mt)
#pragma unroll
        for (int ks = 0; ks < 2; ++ks) {
            const int row = mt * 16 + (lane & 15);
            const int dc = (ks * 4 + (lane >> 4)) ^ (row & 7);
            qf[mt][ks] = *(const bf16x8*)(Qs + row * 64 + dc * 8);
        }
    for (int idx = w; idx < 14; idx += 4) {
        const int mt = idx & 1, nt = idx >> 1;
        f32x4 acc = (f32x4)0.f;
#pragma unroll
        for (int ks = 0; ks < 2; ++ks) {
            const int kr = nt * 16 + (lane & 15);
            const int dc = (ks * 4 + (lane >> 4)) ^ (kr & 7);
            const bf16x8 kf = *(const bf16x8*)(Ks + kr * 64 + dc * 8);
            acc = __builtin_amdgcn_mfma_f32_16x16x32_bf16(qf[mt][ks], kf, acc, 0, 0, 0);
        }
        const int col = nt * 16 + (lane & 15);
        const int r0 = mt * 16 + (lane >> 4) * 4;
#pragma unroll
        for (int r = 0; r < 4; ++r) Sm[(r0 + r) * SW + col] = acc[r];
    }
    __syncthreads();

    {
        const int t = tid >> 3, lq = tid & 7;
        float e[14];
        float m = -INFINITY;
#pragma unroll
        for (int j = 0; j < 14; ++j) {
            const int c = lq + 8 * j;
            bool valid;
            if (c >= 104) valid = (c < 108);
            else {
                const int r = c - 4;
                const int pos = l0 - 32 + r;
                valid = (c >= 4) && (c < 100) && (r >= t) && (r <= t + 64) &&
                        (pos >= 0) && (pos < PATCH_LEN);
            }
            e[j] = valid ? Sm[t * SW + c] * 0.125f : -INFINITY;
            m = fmaxf(m, e[j]);
        }
#pragma unroll
        for (int off = 1; off < 8; off <<= 1) m = fmaxf(m, __shfl_xor(m, off, 64));
        float sum = 0.f;
#pragma unroll
        for (int j = 0; j < 14; ++j) { e[j] = expf(e[j] - m); sum += e[j]; }
#pragma unroll
        for (int off = 1; off < 8; off <<= 1) sum += __shfl_xor(sum, off, 64);
        const float inv = 1.f / sum;
        __syncthreads();
        unsigned short* P = (unsigned short*)Sm;
#pragma unroll
        for (int j = 0; j < 14; ++j) P[t * PW + lq + 8 * j] = f2bf(e[j] * inv);
        ushort2 z; z.x = 0; z.y = 0;
        *(ushort2*)(P + (tid >> 3) * PW + 112 + (tid & 7) * 2) = z;
    }
    __syncthreads();

    {
        const unsigned short* P = (const unsigned short*)Sm;
        const int mt = w & 1;
        bf16x8 pf[4];
#pragma unroll
        for (int ks = 0; ks < 4; ++ks) {
            const int row = mt * 16 + (lane & 15);
            pf[ks] = *(const bf16x8*)(P + row * PW + ks * 32 + (lane >> 4) * 8);
        }
#pragma unroll
        for (int nn = 0; nn < 2; ++nn) {
            const int nt = (w >> 1) + nn * 2;
            f32x4 acc = (f32x4)0.f;
#pragma unroll
            for (int ks = 0; ks < 4; ++ks) {
                const int d = nt * 16 + (lane & 15);
                const int kc = (ks * 4 + (lane >> 4)) ^ (d & 15);
                const bf16x8 vf = *(const bf16x8*)(Vt + d * 128 + kc * 8);
                acc = __builtin_amdgcn_mfma_f32_16x16x32_bf16(pf[ks], vf, acc, 0, 0, 0);
            }
            const int dcol = nt * 16 + (lane & 15);
            const int r0 = mt * 16 + (lane >> 4) * 4;
#pragma unroll
            for (int r = 0; r < 4; ++r)
                attnb[(size_t)(NUM_CLS + l0 + r0 + r) * EMBED + h * HD + dcol] = f2bf(acc[r]);
        }
    }
}

extern "C" void kernel_launch(void* const* d_in, const int* in_sizes, int n_in,
                              void* d_out, int out_size, void* d_ws, size_t ws_size,
                              hipStream_t stream)
{
    const float* x      = (const float*)d_in[0];
    const float* coords = (const float*)d_in[1];
    const float* w_qkv  = (const float*)d_in[2];
    const float* b_qkv  = (const float*)d_in[3];
    const float* w_out  = (const float*)d_in[4];
    const float* b_out  = (const float*)d_in[5];
    float* out = (float*)d_out;

    // ---- ws layout: fully disjoint regions (~53 MB) ----
    char* p = (char*)d_ws;
    unsigned short* qkv   = (unsigned short*)p;  p += (size_t)S_TOT * QKV_LD * 2;
    unsigned short* vT    = (unsigned short*)p;  p += (size_t)EMBED * VT_LD * 2;
    unsigned short* attnb = (unsigned short*)p;  p += (size_t)S_TOT * EMBED * 2;
    float*          part  = (float*)p;           p += (size_t)NHEAD * NCHUNK * 4 * PSTRIDE * 4;
    unsigned short* wob   = (unsigned short*)p;  p += (size_t)EMBED * EMBED * 2;
    unsigned short* xb    = (unsigned short*)p;  p += (size_t)S_TOT * EMBED * 2;
    unsigned short* wqb   = (unsigned short*)p;

    // d_out is written ONLY by the final GEMM. Output = pure function of d_in.

    {
        const int total = S_TOT * EMBED + 3 * EMBED * EMBED + EMBED * EMBED;
        cast_all<<<(total / 4 + 255) / 256, 256, 0, stream>>>(x, w_qkv, w_out, xb, wqb, wob);
    }

    // 1) qkv(bf16, rope fused, vT fused) = x @ w_qkv^T + b_qkv  [XCD-swizzled 1D grid]
    gemm_qkv<<<864, 256, 0, stream>>>(xb, wqb, b_qkv, qkv, coords, vT);

    // 2) cls attention (split-K over 65 chunks, 520 blocks)
    cls_attn_partial<<<dim3(NHEAD, NCHUNK), 256, 0, stream>>>(qkv, part);
    cls_attn_combine<<<NHEAD, 256, 0, stream>>>(part, attnb);

    // 3) patch attention via MFMA
    patch_attn_mfma<<<dim3(PATCH_LEN / 32, NHEAD), 256, 0, stream>>>(qkv, vT, attnb);

    // 4) out = attn @ w_out^T + b_out (fp32), 64x128 tiles -> 516 blocks
    gemm_out<<<dim3(4, 129), 256, 0, stream>>>(attnb, wob, b_out, out);
}

// Round 12
// 180.476 us; speedup vs baseline: 5.7433x; 1.0249x over previous
//
#include <hip/hip_runtime.h>
#include <math.h>

#define EMBED 512
#define NHEAD 8
#define HD 64
#define NUM_CLS 4
#define WIN 32
#define WLEN 65          // 2*WIN+1
#define PATCH_LEN 8192
#define S_TOT 8196       // NUM_CLS + PATCH_LEN
#define QKV_LD 1536
#define VT_LD 8200       // padded, multiple of 8 -> 16B-aligned rows

typedef short bf16x8 __attribute__((ext_vector_type(8)));
typedef float f32x4 __attribute__((ext_vector_type(4)));

__device__ __forceinline__ unsigned short f2bf(float f) {
    unsigned u = __float_as_uint(f);
    return (unsigned short)((u + 0x7fffu + ((u >> 16) & 1u)) >> 16);
}
__device__ __forceinline__ float bf2f(unsigned short v) {
    return __uint_as_float((unsigned)v << 16);
}
__device__ __forceinline__ void gll16(const unsigned short* g, unsigned short* l) {
    __builtin_amdgcn_global_load_lds((const __attribute__((address_space(1))) void*)g,
                                     (__attribute__((address_space(3))) void*)l, 16, 0, 0);
}
__device__ __forceinline__ bf16x8 pack8(float4 lo, float4 hi) {
    bf16x8 r;
    r[0] = (short)f2bf(lo.x); r[1] = (short)f2bf(lo.y);
    r[2] = (short)f2bf(lo.z); r[3] = (short)f2bf(lo.w);
    r[4] = (short)f2bf(hi.x); r[5] = (short)f2bf(hi.y);
    r[6] = (short)f2bf(hi.z); r[7] = (short)f2bf(hi.w);
    return r;
}

// ---------------- fp32 -> bf16 cast of w_qkv | w_out (weights only) ----------------
__global__ __launch_bounds__(256) void cast_w(const float* __restrict__ wq,
                                              const float* __restrict__ wo,
                                              unsigned short* __restrict__ wqb,
                                              unsigned short* __restrict__ wob)
{
    const int n2 = 3 * EMBED * EMBED;
    const int n3 = EMBED * EMBED;
    const int i = (blockIdx.x * 256 + threadIdx.x) * 4;
    const float* src;
    unsigned short* dst;
    int j;
    if (i < n2)           { src = wq; dst = wqb; j = i; }
    else if (i < n2 + n3) { src = wo; dst = wob; j = i - n2; }
    else return;
    const float4 v = *(const float4*)(src + j);
    ushort4 o;
    o.x = f2bf(v.x); o.y = f2bf(v.y); o.z = f2bf(v.z); o.w = f2bf(v.w);
    *(ushort4*)(dst + j) = o;
}

// ---------------- QKV GEMM: qkv = x(fp32) @ w_qkv^T + b, rope + vT fused ----------------
// A read as fp32, converted in-register, staged via ds_write (fused cast).
// 128x128 tile, BK=32, dbuf LDS (32 KB) with 17.4 KB epilogue overlay -> 5 blocks/CU.
// XCD swizzle: grid 864 = 8 x 108; xcd = id&7 owns bm = xcd + 8k.
#define EXW 136   // EX row stride (ushorts); 272B, 16B-aligned
__global__ __launch_bounds__(256) void gemm_qkv(const float* __restrict__ X,
                                                const unsigned short* __restrict__ B,
                                                const float* __restrict__ bias,
                                                unsigned short* __restrict__ C,
                                                const float* __restrict__ coords,
                                                unsigned short* __restrict__ vT)
{
    const int M = S_TOT, N = 3 * EMBED, K = EMBED;
    __shared__ __align__(16) unsigned short SMEM[16384];   // As dbuf | Bs dbuf; EX overlay
    unsigned short* EX = SMEM;

    const int tid = threadIdx.x;
    const int lane = tid & 63, w = tid >> 6;
    const int xcd = blockIdx.x & 7;
    const int s = blockIdx.x >> 3;          // 0..107
    const int bm = xcd + 8 * (s / 12);
    const int bn = s % 12;
    if (bm >= 65) return;

    const int ar0 = tid >> 2;
    const int col8 = (tid & 3) * 8;
    int gm0 = bm * 128 + ar0;       if (gm0 >= M) gm0 = M - 1;
    int gm1 = bm * 128 + ar0 + 64;  if (gm1 >= M) gm1 = M - 1;
    const float* Xp0 = X + (size_t)gm0 * K + col8;
    const float* Xp1 = X + (size_t)gm1 * K + col8;
    const unsigned short* pb0 = B + (size_t)(bn * 128 + ar0) * K + col8;
    const unsigned short* pb1 = B + (size_t)(bn * 128 + ar0 + 64) * K + col8;

    const int wr = (w & 1) * 64;
    const int wc = (w >> 1) * 64;
    const int fr = lane & 15;
    const int fk = (lane >> 4) * 8;

    f32x4 acc[4][4];
#pragma unroll
    for (int mi = 0; mi < 4; ++mi)
#pragma unroll
        for (int ni = 0; ni < 4; ++ni) acc[mi][ni] = (f32x4)0.f;

    // prologue: stage A(0) via regs+ds_write, prefetch B(0) via gll16
    {
        const float4 a00 = *(const float4*)(Xp0);
        const float4 a01 = *(const float4*)(Xp0 + 4);
        const float4 a10 = *(const float4*)(Xp1);
        const float4 a11 = *(const float4*)(Xp1 + 4);
        gll16(pb0, SMEM + 8192 + tid * 8);
        gll16(pb1, SMEM + 8192 + (tid + 256) * 8);
        *(bf16x8*)(SMEM + tid * 8) = pack8(a00, a01);
        *(bf16x8*)(SMEM + (tid + 256) * 8) = pack8(a10, a11);
    }

    for (int it = 0; it < 16; ++it) {
        __syncthreads();            // As[cb]/Bs[cb] ready
        float4 n00, n01, n10, n11;
        const bool more = (it + 1 < 16);
        if (more) {
            const int kf = (it + 1) * 32;
            n00 = *(const float4*)(Xp0 + kf);
            n01 = *(const float4*)(Xp0 + kf + 4);
            n10 = *(const float4*)(Xp1 + kf);
            n11 = *(const float4*)(Xp1 + kf + 4);
            const int off = ((it + 1) & 1) * 4096;
            gll16(pb0 + kf, SMEM + 8192 + off + tid * 8);
            gll16(pb1 + kf, SMEM + 8192 + off + (tid + 256) * 8);
        }
        const unsigned short* Asb = SMEM + (it & 1) * 4096;
        const unsigned short* Bsb = SMEM + 8192 + (it & 1) * 4096;
        bf16x8 af[4], bf[4];
#pragma unroll
        for (int mi = 0; mi < 4; ++mi)
            af[mi] = *(const bf16x8*)(Asb + (wr + mi * 16 + fr) * 32 + fk);
#pragma unroll
        for (int ni = 0; ni < 4; ++ni)
            bf[ni] = *(const bf16x8*)(Bsb + (wc + ni * 16 + fr) * 32 + fk);
#pragma unroll
        for (int mi = 0; mi < 4; ++mi)
#pragma unroll
            for (int ni = 0; ni < 4; ++ni)
                acc[mi][ni] = __builtin_amdgcn_mfma_f32_16x16x32_bf16(af[mi], bf[ni], acc[mi][ni], 0, 0, 0);
        if (more) {   // cvt+write AFTER compute: A-load latency hidden by MFMAs
            const int off = ((it + 1) & 1) * 4096;
            *(bf16x8*)(SMEM + off + tid * 8) = pack8(n00, n01);
            *(bf16x8*)(SMEM + off + (tid + 256) * 8) = pack8(n10, n11);
        }
    }
    __syncthreads();   // staging dead; EX overlay safe

    const int ccol = bn * 128 + wc + fr;

    if (bn < 8) {
        // ---- q/k sections: rope table in EX, pack to regs, coalesced stores ----
        ushort2* rt = (ushort2*)EX;
        for (int idx = tid; idx < 4096; idx += 256) {
            const int rr = idx >> 5, pr = idx & 31;
            int l = bm * 128 + rr - NUM_CLS;
            l = l < 0 ? 0 : (l > PATCH_LEN - 1 ? PATCH_LEN - 1 : l);
            const float cxy = coords[l * 2 + (pr >> 4)] * 1e-5f;
            const float f = cxy * __expf(-(float)(pr & 15) * 0.5756462732485114f);
            float sn, cs;
            __sincosf(f, &sn, &cs);
            ushort2 e; e.x = f2bf(cs); e.y = f2bf(sn);
            rt[idx] = e;
        }
        __syncthreads();

        unsigned pv[4][4][2];
#pragma unroll
        for (int mi = 0; mi < 4; ++mi) {
#pragma unroll
            for (int r = 0; r < 4; ++r) {
                const int rloc = wr + mi * 16 + (lane >> 4) * 4 + r;
                const int row = bm * 128 + rloc;
                const bool patch = (row >= NUM_CLS) && (row < M);
#pragma unroll
                for (int ni = 0; ni < 4; ++ni) {
                    const int col = ccol + ni * 16;
                    const float biased = acc[mi][ni][r] + bias[col];
                    const float prt = __shfl_xor(biased, 1);
                    float outv = biased;
                    if (patch) {
                        const ushort2 e = rt[rloc * 32 + ((col & 63) >> 1)];
                        const float cs = bf2f(e.x), sn = bf2f(e.y);
                        outv = (col & 1) ? (biased * cs + prt * sn)
                                         : (biased * cs - prt * sn);
                    }
                    const unsigned us = f2bf(outv);
                    if (r & 1) pv[mi][ni][r >> 1] |= us << 16;
                    else       pv[mi][ni][r >> 1] = us;
                }
            }
        }
        for (int p = 0; p < 2; ++p) {
            __syncthreads();
            if ((w & 1) == p) {
#pragma unroll
                for (int mi = 0; mi < 4; ++mi) {
#pragma unroll
                    for (int r = 0; r < 4; ++r) {
                        const int rl = mi * 16 + (lane >> 4) * 4 + r;
#pragma unroll
                        for (int ni = 0; ni < 4; ++ni) {
                            const unsigned pw = pv[mi][ni][r >> 1];
                            EX[rl * EXW + wc + fr + ni * 16] =
                                (unsigned short)((r & 1) ? (pw >> 16) : (pw & 0xffff));
                        }
                    }
                }
            }
            __syncthreads();
#pragma unroll
            for (int i = 0; i < 4; ++i) {
                const int idx = tid + 256 * i;
                const int rowl = idx >> 4, ch = idx & 15;
                const int grow = bm * 128 + p * 64 + rowl;
                if (grow < M)
                    *(bf16x8*)(C + (size_t)grow * N + bn * 128 + ch * 8) =
                        *(const bf16x8*)(EX + rowl * EXW + ch * 8);
            }
        }
    } else {
        const int dbase = (bn - 8) * 128;
#pragma unroll
        for (int mi = 0; mi < 4; ++mi) {
            const int rbase = bm * 128 + wr + mi * 16 + (lane >> 4) * 4;
#pragma unroll
            for (int ni = 0; ni < 4; ++ni) {
                const int col = ccol + ni * 16;
#pragma unroll
                for (int r = 0; r < 4; ++r) {
                    const int row = rbase + r;
                    if (row < M)
                        C[(size_t)row * N + col] = f2bf(acc[mi][ni][r] + bias[col]);
                }
            }
        }
        for (int p = 0; p < 2; ++p) {
            __syncthreads();
            if ((w >> 1) == p) {
#pragma unroll
                for (int mi = 0; mi < 4; ++mi) {
                    const int tok0 = wr + mi * 16 + (lane >> 4) * 4;
                    const int rw = bm * 128 + tok0;
#pragma unroll
                    for (int ni = 0; ni < 4; ++ni) {
                        const int col = ccol + ni * 16;
                        const int dloc = fr + 16 * ni;
                        ushort4 o;
                        o.x = (rw + 0 < M) ? f2bf(acc[mi][ni][0] + bias[col]) : (unsigned short)0;
                        o.y = (rw + 1 < M) ? f2bf(acc[mi][ni][1] + bias[col]) : (unsigned short)0;
                        o.z = (rw + 2 < M) ? f2bf(acc[mi][ni][2] + bias[col]) : (unsigned short)0;
                        o.w = (rw + 3 < M) ? f2bf(acc[mi][ni][3] + bias[col]) : (unsigned short)0;
                        *(ushort4*)(EX + dloc * EXW + tok0) = o;
                    }
                }
            }
            __syncthreads();
            const int d = tid >> 2;
            const int tch = (tid & 3) * 32;
            const int gtok = bm * 128 + tch;
            unsigned short* dst = vT + (size_t)(dbase + p * 64 + d) * VT_LD + gtok;
            const unsigned short* srcl = EX + d * EXW + tch;
            if (gtok + 32 <= VT_LD) {
#pragma unroll
                for (int c2 = 0; c2 < 32; c2 += 8)
                    *(bf16x8*)(dst + c2) = *(const bf16x8*)(srcl + c2);
            } else {
                for (int c2 = 0; c2 < 32; ++c2)
                    if (gtok + c2 < VT_LD) dst[c2] = srcl[c2];
            }
        }
    }
}

// ---------------- out GEMM: out = attn @ w_out^T + b (fp32) ----------------
__global__ __launch_bounds__(256) void gemm_out(const unsigned short* __restrict__ A,
                                                const unsigned short* __restrict__ B,
                                                const float* __restrict__ bias,
                                                float* __restrict__ C)
{
    const int M = S_TOT, N = EMBED, K = EMBED;
    __shared__ __align__(16) unsigned short As[2][64 * 32];
    __shared__ __align__(16) unsigned short Bs[2][128 * 32];
    const int tid = threadIdx.x;
    const int lane = tid & 63, w = tid >> 6;
    const int bn = blockIdx.x, bm = blockIdx.y;

    const int ar0 = tid >> 2;
    const int col8 = (tid & 3) * 8;
    int gm0 = bm * 64 + ar0;  if (gm0 >= M) gm0 = M - 1;
    const unsigned short* pa0 = A + (size_t)gm0 * K + col8;
    const unsigned short* pb0 = B + (size_t)(bn * 128 + ar0) * K + col8;
    const unsigned short* pb1 = B + (size_t)(bn * 128 + ar0 + 64) * K + col8;

    const int wr = (w & 1) * 32;
    const int wc = (w >> 1) * 64;
    const int fr = lane & 15;
    const int fk = (lane >> 4) * 8;

    f32x4 acc[2][4];
#pragma unroll
    for (int mi = 0; mi < 2; ++mi)
#pragma unroll
        for (int ni = 0; ni < 4; ++ni) acc[mi][ni] = (f32x4)0.f;

    gll16(pa0, As[0] + tid * 8);
    gll16(pb0, Bs[0] + tid * 8);
    gll16(pb1, Bs[0] + (tid + 256) * 8);

    for (int it = 0; it < 16; ++it) {
        __syncthreads();
        if (it + 1 < 16) {
            const int k0 = (it + 1) * 32;
            const int nb = (it + 1) & 1;
            gll16(pa0 + k0, As[nb] + tid * 8);
            gll16(pb0 + k0, Bs[nb] + tid * 8);
            gll16(pb1 + k0, Bs[nb] + (tid + 256) * 8);
        }
        const int cb = it & 1;
        bf16x8 af[2], bf[4];
#pragma unroll
        for (int mi = 0; mi < 2; ++mi)
            af[mi] = *(const bf16x8*)(As[cb] + (wr + mi * 16 + fr) * 32 + fk);
#pragma unroll
        for (int ni = 0; ni < 4; ++ni)
            bf[ni] = *(const bf16x8*)(Bs[cb] + (wc + ni * 16 + fr) * 32 + fk);
#pragma unroll
        for (int mi = 0; mi < 2; ++mi)
#pragma unroll
            for (int ni = 0; ni < 4; ++ni)
                acc[mi][ni] = __builtin_amdgcn_mfma_f32_16x16x32_bf16(af[mi], bf[ni], acc[mi][ni], 0, 0, 0);
    }

    const int ccol = bn * 128 + wc + fr;
#pragma unroll
    for (int mi = 0; mi < 2; ++mi) {
        const int rbase = bm * 64 + wr + mi * 16 + (lane >> 4) * 4;
#pragma unroll
        for (int r = 0; r < 4; ++r) {
            const int row = rbase + r;
            if (row < M) {
#pragma unroll
                for (int ni = 0; ni < 4; ++ni)
                    C[(size_t)row * N + ccol + ni * 16] = acc[mi][ni][r] + bias[ccol + ni * 16];
            }
        }
    }
}

// ---------------- fused attention: 2048 patch blocks + 520 cls blocks ----------------
#define CCH 128
#define NCHUNK ((S_TOT + CCH - 1) / CCH)   // 65
#define PSTRIDE 68
#define SW 116   // patch S stride (fp32)
#define PW 136   // patch P stride (bf16)

__global__ __launch_bounds__(256) void attn_fused(
    const unsigned short* __restrict__ qkv,   // [8196][1536] bf16, rope applied
    const unsigned short* __restrict__ vT,    // [512][VT_LD] v^T bf16
    float* __restrict__ part,
    unsigned short* __restrict__ attnb)       // [8196][512] bf16
{
    __shared__ __align__(16) char SM[49664];
    const int tid = threadIdx.x;
    const int lane = tid & 63, w = tid >> 6;

    if (blockIdx.x < 2048) {
        // ================= patch path =================
        const int l0 = (blockIdx.x >> 3) * 32;
        const int h = blockIdx.x & 7;
        unsigned short* Qs = (unsigned short*)SM;             //  4,096 B
        unsigned short* Ks = (unsigned short*)(SM + 4096);    // 14,336 B
        unsigned short* Vt = (unsigned short*)(SM + 18432);   // 16,384 B
        float* Sm = (float*)(SM + 34816);                     // 14,848 B

        {
            const int i = tid;
            const int t = i >> 3;
            const int dcl = (i & 7) ^ (t & 7);
            gll16(qkv + (size_t)(NUM_CLS + l0 + t) * QKV_LD + h * HD + dcl * 8, Qs + i * 8);
        }
        for (int i = tid; i < 896; i += 256) {
            const int c = i >> 3;
            const int dcl = (i & 7) ^ (c & 7);
            int tok = (c >= 104 && c < 108) ? (c - 104) : (l0 - 32 + c);
            tok = tok < 0 ? 0 : (tok > S_TOT - 1 ? S_TOT - 1 : tok);
            gll16(qkv + (size_t)tok * QKV_LD + EMBED + h * HD + dcl * 8, Ks + i * 8);
        }
        for (int i = tid; i < 1024; i += 256) {
            const int d = i >> 4;
            const int kcl = (i & 15) ^ (d & 15);
            const int c0 = kcl * 8;
            int tokb = (c0 == 104) ? 0 : (l0 - 32 + c0);
            tokb = tokb < 0 ? 0 : (tokb > 8192 ? 8192 : tokb);
            gll16(vT + (size_t)(h * HD + d) * VT_LD + tokb, Vt + i * 8);
        }
        __syncthreads();

        bf16x8 qf[2][2];
#pragma unroll
        for (int mt = 0; mt < 2; ++mt)
#pragma unroll
            for (int ks = 0; ks < 2; ++ks) {
                const int row = mt * 16 + (lane & 15);
                const int dc = (ks * 4 + (lane >> 4)) ^ (row & 7);
                qf[mt][ks] = *(const bf16x8*)(Qs + row * 64 + dc * 8);
            }
        for (int idx = w; idx < 14; idx += 4) {
            const int mt = idx & 1, nt = idx >> 1;
            f32x4 acc = (f32x4)0.f;
#pragma unroll
            for (int ks = 0; ks < 2; ++ks) {
                const int kr = nt * 16 + (lane & 15);
                const int dc = (ks * 4 + (lane >> 4)) ^ (kr & 7);
                const bf16x8 kf = *(const bf16x8*)(Ks + kr * 64 + dc * 8);
                acc = __builtin_amdgcn_mfma_f32_16x16x32_bf16(qf[mt][ks], kf, acc, 0, 0, 0);
            }
            const int col = nt * 16 + (lane & 15);
            const int r0 = mt * 16 + (lane >> 4) * 4;
#pragma unroll
            for (int r = 0; r < 4; ++r) Sm[(r0 + r) * SW + col] = acc[r];
        }
        __syncthreads();

        {
            const int t = tid >> 3, lq = tid & 7;
            float e[14];
            float m = -INFINITY;
#pragma unroll
            for (int j = 0; j < 14; ++j) {
                const int c = lq + 8 * j;
                bool valid;
                if (c >= 104) valid = (c < 108);
                else {
                    const int r = c - 4;
                    const int pos = l0 - 32 + r;
                    valid = (c >= 4) && (c < 100) && (r >= t) && (r <= t + 64) &&
                            (pos >= 0) && (pos < PATCH_LEN);
                }
                e[j] = valid ? Sm[t * SW + c] * 0.125f : -INFINITY;
                m = fmaxf(m, e[j]);
            }
#pragma unroll
            for (int off = 1; off < 8; off <<= 1) m = fmaxf(m, __shfl_xor(m, off, 64));
            float sum = 0.f;
#pragma unroll
            for (int j = 0; j < 14; ++j) { e[j] = expf(e[j] - m); sum += e[j]; }
#pragma unroll
            for (int off = 1; off < 8; off <<= 1) sum += __shfl_xor(sum, off, 64);
            const float inv = 1.f / sum;
            __syncthreads();
            unsigned short* P = (unsigned short*)Sm;
#pragma unroll
            for (int j = 0; j < 14; ++j) P[t * PW + lq + 8 * j] = f2bf(e[j] * inv);
            ushort2 z; z.x = 0; z.y = 0;
            *(ushort2*)(P + (tid >> 3) * PW + 112 + (tid & 7) * 2) = z;
        }
        __syncthreads();

        {
            const unsigned short* P = (const unsigned short*)Sm;
            const int mt = w & 1;
            bf16x8 pf[4];
#pragma unroll
            for (int ks = 0; ks < 4; ++ks) {
                const int row = mt * 16 + (lane & 15);
                pf[ks] = *(const bf16x8*)(P + row * PW + ks * 32 + (lane >> 4) * 8);
            }
#pragma unroll
            for (int nn = 0; nn < 2; ++nn) {
                const int nt = (w >> 1) + nn * 2;
                f32x4 acc = (f32x4)0.f;
#pragma unroll
                for (int ks = 0; ks < 4; ++ks) {
                    const int d = nt * 16 + (lane & 15);
                    const int kc = (ks * 4 + (lane >> 4)) ^ (d & 15);
                    const bf16x8 vf = *(const bf16x8*)(Vt + d * 128 + kc * 8);
                    acc = __builtin_amdgcn_mfma_f32_16x16x32_bf16(pf[ks], vf, acc, 0, 0, 0);
                }
                const int dcol = nt * 16 + (lane & 15);
                const int r0 = mt * 16 + (lane >> 4) * 4;
#pragma unroll
                for (int r = 0; r < 4; ++r)
                    attnb[(size_t)(NUM_CLS + l0 + r0 + r) * EMBED + h * HD + dcol] = f2bf(acc[r]);
            }
        }
    } else {
        // ================= cls split-K path =================
        const int cid = blockIdx.x - 2048;
        const int h = cid & 7;
        const int c = cid >> 3;
        const int base = c * CCH;
        float* qs = (float*)SM;                               // [4][64]  1,024 B
        unsigned short* Kl = (unsigned short*)(SM + 1024);    // 16,384 B
        float* sc = (float*)(SM + 17408);                     // [4][128] 2,048 B
        float* ored = (float*)(SM + 19456);                   // [4][4][64] 4,096 B
        float* ml = (float*)(SM + 23552);                     // [4][2] 32 B

        {
            const int qi = tid >> 6, d = tid & 63;
            qs[qi * 64 + d] = bf2f(qkv[(size_t)qi * QKV_LD + h * HD + d]);
        }
        for (int i = tid; i < 1024; i += 256) {
            const int kr = i >> 3;
            const int dc = (i & 7) ^ (kr & 7);
            int j = base + kr; if (j > S_TOT - 1) j = S_TOT - 1;
            gll16(qkv + (size_t)j * QKV_LD + EMBED + h * HD + dc * 8, Kl + i * 8);
        }
        __syncthreads();

        {
            const int jj = tid & 127;
            const int qp = (tid >> 7) * 2;
            const int j = base + jj;
            float s0 = -INFINITY, s1 = -INFINITY;
            if (j < S_TOT) {
                float a0 = 0.f, a1 = 0.f;
#pragma unroll
                for (int cch = 0; cch < 8; ++cch) {
                    const int slot = cch ^ (jj & 7);
                    const bf16x8 kv8 = *(const bf16x8*)(Kl + jj * 64 + slot * 8);
#pragma unroll
                    for (int u = 0; u < 8; ++u) {
                        const float kf = bf2f((unsigned short)kv8[u]);
                        a0 += qs[(qp + 0) * 64 + cch * 8 + u] * kf;
                        a1 += qs[(qp + 1) * 64 + cch * 8 + u] * kf;
                    }
                }
                s0 = a0 * 0.125f; s1 = a1 * 0.125f;
            }
            sc[(qp + 0) * CCH + jj] = s0;
            sc[(qp + 1) * CCH + jj] = s1;
        }
        __syncthreads();

        {
            float m = fmaxf(sc[w * CCH + lane], sc[w * CCH + lane + 64]);
#pragma unroll
            for (int off = 32; off > 0; off >>= 1) m = fmaxf(m, __shfl_xor(m, off, 64));
            const float e0 = expf(sc[w * CCH + lane] - m);
            const float e1 = expf(sc[w * CCH + lane + 64] - m);
            sc[w * CCH + lane] = e0; sc[w * CCH + lane + 64] = e1;
            float lsum = e0 + e1;
#pragma unroll
            for (int off = 32; off > 0; off >>= 1) lsum += __shfl_xor(lsum, off, 64);
            if (lane == 0) { ml[w * 2 + 0] = m; ml[w * 2 + 1] = lsum; }
        }
        __syncthreads();

        {
            const int g = w, d = lane;
            float a0 = 0.f, a1 = 0.f, a2 = 0.f, a3 = 0.f;
            for (int jj = g; jj < CCH; jj += 4) {
                const int j = base + jj;
                if (j >= S_TOT) break;
                const float vv = bf2f(qkv[(size_t)j * QKV_LD + 2 * EMBED + h * HD + d]);
                a0 += sc[0 * CCH + jj] * vv; a1 += sc[1 * CCH + jj] * vv;
                a2 += sc[2 * CCH + jj] * vv; a3 += sc[3 * CCH + jj] * vv;
            }
            ored[(g * 4 + 0) * 64 + d] = a0; ored[(g * 4 + 1) * 64 + d] = a1;
            ored[(g * 4 + 2) * 64 + d] = a2; ored[(g * 4 + 3) * 64 + d] = a3;
        }
        __syncthreads();

        {
            const int qi = tid >> 6, d = tid & 63;
            const float o = ored[(0 * 4 + qi) * 64 + d] + ored[(1 * 4 + qi) * 64 + d] +
                            ored[(2 * 4 + qi) * 64 + d] + ored[(3 * 4 + qi) * 64 + d];
            float* pb = part + ((size_t)(h * NCHUNK + c) * 4 + qi) * PSTRIDE;
            pb[d] = o;
            if (d == 0) { pb[64] = ml[qi * 2 + 0]; pb[65] = ml[qi * 2 + 1]; }
        }
    }
}

__global__ __launch_bounds__(256) void cls_attn_combine(const float* __restrict__ part,
                                                        unsigned short* __restrict__ attn)
{
    const int h = blockIdx.x;
    const int qi = threadIdx.x >> 6, d = threadIdx.x & 63;
    float M = -INFINITY;
    for (int c = 0; c < NCHUNK; ++c)
        M = fmaxf(M, part[((size_t)(h * NCHUNK + c) * 4 + qi) * PSTRIDE + 64]);
    float acc = 0.f, L = 0.f;
    for (int c = 0; c < NCHUNK; ++c) {
        const float* pb = part + ((size_t)(h * NCHUNK + c) * 4 + qi) * PSTRIDE;
        const float s = expf(pb[64] - M);
        acc += s * pb[d];
        L   += s * pb[65];
    }
    attn[(size_t)qi * EMBED + h * HD + d] = f2bf(acc / L);
}

extern "C" void kernel_launch(void* const* d_in, const int* in_sizes, int n_in,
                              void* d_out, int out_size, void* d_ws, size_t ws_size,
                              hipStream_t stream)
{
    const float* x      = (const float*)d_in[0];
    const float* coords = (const float*)d_in[1];
    const float* w_qkv  = (const float*)d_in[2];
    const float* b_qkv  = (const float*)d_in[3];
    const float* w_out  = (const float*)d_in[4];
    const float* b_out  = (const float*)d_in[5];
    float* out = (float*)d_out;

    // ---- ws layout: fully disjoint regions (~44.6 MB) ----
    char* p = (char*)d_ws;
    unsigned short* qkv   = (unsigned short*)p;  p += (size_t)S_TOT * QKV_LD * 2;
    unsigned short* vT    = (unsigned short*)p;  p += (size_t)EMBED * VT_LD * 2;
    unsigned short* attnb = (unsigned short*)p;  p += (size_t)S_TOT * EMBED * 2;
    float*          part  = (float*)p;           p += (size_t)NHEAD * NCHUNK * 4 * PSTRIDE * 4;
    unsigned short* wob   = (unsigned short*)p;  p += (size_t)EMBED * EMBED * 2;
    unsigned short* wqb   = (unsigned short*)p;

    // d_out is written ONLY by the final GEMM. Output = pure function of d_in.

    // 1) weight casts (x cast is fused into gemm_qkv)
    cast_w<<<1024, 256, 0, stream>>>(w_qkv, w_out, wqb, wob);

    // 2) qkv(bf16, rope fused, vT fused) = x(fp32) @ w_qkv^T + b_qkv
    gemm_qkv<<<864, 256, 0, stream>>>(x, wqb, b_qkv, qkv, coords, vT);

    // 3) fused attention: 2048 patch-MFMA blocks + 520 cls split-K blocks
    attn_fused<<<2048 + NHEAD * NCHUNK, 256, 0, stream>>>(qkv, vT, part, attnb);

    // 4) cls combine (8 blocks)
    cls_attn_combine<<<NHEAD, 256, 0, stream>>>(part, attnb);

    // 5) out = attn @ w_out^T + b_out (fp32)
    gemm_out<<<dim3(4, 129), 256, 0, stream>>>(attnb, wob, b_out, out);
}